// Round 3
// baseline (1714.770 us; speedup 1.0000x reference)
//
#include <hip/hip_runtime.h>
#include <hip/hip_bf16.h>
#include <cmath>

typedef __attribute__((ext_vector_type(8))) short bf16x8;
typedef __attribute__((ext_vector_type(4))) float f32x4;

__device__ inline ushort f2bf(float f) {
  __hip_bfloat16 h = __float2bfloat16(f);
  return *reinterpret_cast<ushort*>(&h);
}

// ---------------------------------------------------------------------------
// conv1x1: out[b,oc,n] = bias[oc] + sum_c w[oc,c] * x[b,c,n]
// ---------------------------------------------------------------------------
__global__ __launch_bounds__(256) void conv1x1_kernel(
    const float* __restrict__ x, const float* __restrict__ w,
    const float* __restrict__ bias, float* __restrict__ out,
    int C, int N, int OC) {
  __shared__ float As[64][17];
  __shared__ float Bs[16][64];
  const int b = blockIdx.z;
  const int m0 = blockIdx.y * 64, n0 = blockIdx.x * 64;
  const float* xb = x + (size_t)b * C * N;
  const int tid = threadIdx.x;
  const int tr = tid >> 4, tc = tid & 15;
  float acc[4][4] = {};
  for (int k0 = 0; k0 < C; k0 += 16) {
    for (int i = tid; i < 64 * 16; i += 256) {
      int m = i >> 4, kk = i & 15;
      int gm = m0 + m;
      As[m][kk] = (gm < OC) ? w[(size_t)gm * C + k0 + kk] : 0.f;
    }
    for (int i = tid; i < 16 * 64; i += 256) {
      int kk = i >> 6, n = i & 63;
      int gn = n0 + n;
      Bs[kk][n] = (gn < N) ? xb[(size_t)(k0 + kk) * N + gn] : 0.f;
    }
    __syncthreads();
#pragma unroll
    for (int kk = 0; kk < 16; ++kk) {
      float a[4], bb[4];
#pragma unroll
      for (int i = 0; i < 4; i++) a[i] = As[tr * 4 + i][kk];
#pragma unroll
      for (int j = 0; j < 4; j++) bb[j] = Bs[kk][tc * 4 + j];
#pragma unroll
      for (int i = 0; i < 4; i++)
#pragma unroll
        for (int j = 0; j < 4; j++) acc[i][j] += a[i] * bb[j];
    }
    __syncthreads();
  }
  for (int i = 0; i < 4; i++) {
    int gm = m0 + tr * 4 + i;
    if (gm >= OC) continue;
    float bv = bias[gm];
    for (int j = 0; j < 4; j++) {
      int gn = n0 + tc * 4 + j;
      if (gn < N) out[((size_t)b * OC + gm) * N + gn] = acc[i][j] + bv;
    }
  }
}

// ---------------------------------------------------------------------------
// energy[b,n,m] = sum_q q[b,q,n] * k[b,q,m]
// ---------------------------------------------------------------------------
__global__ __launch_bounds__(256) void energy_kernel(
    const float* __restrict__ qg, const float* __restrict__ kg,
    float* __restrict__ e, int QKd, int N) {
  __shared__ float As[16][64];
  __shared__ float Bs[16][64];
  const int b = blockIdx.z;
  const int n0 = blockIdx.y * 64, m0 = blockIdx.x * 64;
  const float* qb = qg + (size_t)b * QKd * N;
  const float* kb = kg + (size_t)b * QKd * N;
  const int tid = threadIdx.x, tr = tid >> 4, tc = tid & 15;
  float acc[4][4] = {};
  for (int k0 = 0; k0 < QKd; k0 += 16) {
    for (int i = tid; i < 16 * 64; i += 256) {
      int kk = i >> 6, n = i & 63;
      int gn = n0 + n;
      As[kk][n] = (gn < N) ? qb[(size_t)(k0 + kk) * N + gn] : 0.f;
    }
    for (int i = tid; i < 16 * 64; i += 256) {
      int kk = i >> 6, m = i & 63;
      int gm = m0 + m;
      Bs[kk][m] = (gm < N) ? kb[(size_t)(k0 + kk) * N + gm] : 0.f;
    }
    __syncthreads();
#pragma unroll
    for (int kk = 0; kk < 16; ++kk) {
      float a[4], bb[4];
#pragma unroll
      for (int i = 0; i < 4; i++) a[i] = As[kk][tr * 4 + i];
#pragma unroll
      for (int j = 0; j < 4; j++) bb[j] = Bs[kk][tc * 4 + j];
#pragma unroll
      for (int i = 0; i < 4; i++)
#pragma unroll
        for (int j = 0; j < 4; j++) acc[i][j] += a[i] * bb[j];
    }
    __syncthreads();
  }
  for (int i = 0; i < 4; i++) {
    int gn = n0 + tr * 4 + i;
    if (gn >= N) continue;
    for (int j = 0; j < 4; j++) {
      int gm = m0 + tc * 4 + j;
      if (gm < N) e[((size_t)b * N + gn) * N + gm] = acc[i][j];
    }
  }
}

// ---------------------------------------------------------------------------
// in-place row softmax of sign*r over last dim
// ---------------------------------------------------------------------------
__global__ __launch_bounds__(256) void softmax_rows_kernel(
    float* __restrict__ e, int N, float sign) {
  const size_t row = blockIdx.x;
  float* r = e + row * (size_t)N;
  const int tid = threadIdx.x;
  __shared__ float red[4];
  float mx = -1e30f;
  for (int i = tid; i < N; i += 256) mx = fmaxf(mx, sign * r[i]);
#pragma unroll
  for (int off = 32; off; off >>= 1) mx = fmaxf(mx, __shfl_xor(mx, off, 64));
  if ((tid & 63) == 0) red[tid >> 6] = mx;
  __syncthreads();
  if (tid == 0) {
    float m2 = red[0];
    for (int i = 1; i < 4; i++) m2 = fmaxf(m2, red[i]);
    red[0] = m2;
  }
  __syncthreads();
  mx = red[0];
  __syncthreads();
  float s = 0.f;
  for (int i = tid; i < N; i += 256) {
    float v = __expf(sign * r[i] - mx);
    r[i] = v;
    s += v;
  }
#pragma unroll
  for (int off = 32; off; off >>= 1) s += __shfl_xor(s, off, 64);
  if ((tid & 63) == 0) red[tid >> 6] = s;
  __syncthreads();
  if (tid == 0) {
    float t = 0.f;
    for (int i = 0; i < 4; i++) t += red[i];
    red[0] = t;
  }
  __syncthreads();
  const float inv = 1.f / red[0];
  for (int i = tid; i < N; i += 256) r[i] *= inv;
}

// ---------------------------------------------------------------------------
// PV via MFMA: xsum[b,c,n] = x[b,c,n] + g * sum_m v[b,c,m]*Att[b,n,m]
// M=256 (c, full), N-tile 64, K=N(spatial), BK=32. 4 waves, 64x64 each.
// grid (ceil(N/64), 1, B)
// ---------------------------------------------------------------------------
__global__ __launch_bounds__(256) void pv_mfma_kernel(
    const float* __restrict__ v, const float* __restrict__ Att,
    const float* __restrict__ x, const float* __restrict__ gp,
    float* __restrict__ xsum, int N) {
  constexpr int C = 256;
  __shared__ ushort Asm[256][40];
  __shared__ ushort Bsm[64][40];
  const int b = blockIdx.z;
  const int n0 = blockIdx.x * 64;
  const float* vb = v + (size_t)b * C * N;
  const float* Ab = Att + (size_t)b * N * N;
  const int tid = threadIdx.x, lane = tid & 63, w = tid >> 6;
  f32x4 acc[4][4];
#pragma unroll
  for (int i = 0; i < 4; i++)
#pragma unroll
    for (int j = 0; j < 4; j++) acc[i][j] = (f32x4){0.f, 0.f, 0.f, 0.f};
  const int nsteps = (N + 31) / 32;
  for (int s = 0; s < nsteps; ++s) {
    const int k0 = s * 32;
    // stage A: Asm[c][kk] = bf16(v[c][k0+kk])
    for (int u = tid; u < 256 * 4; u += 256) {
      const int row = u >> 2, seg = u & 3;
      const int gk = k0 + seg * 8;
      const float* src = vb + (size_t)row * N + gk;
      uint4 pk;
      uint pw[4];
#pragma unroll
      for (int h = 0; h < 4; h++) {
        const float e0 = (gk + 2 * h < N) ? src[2 * h] : 0.f;
        const float e1 = (gk + 2 * h + 1 < N) ? src[2 * h + 1] : 0.f;
        pw[h] = (uint)f2bf(e0) | ((uint)f2bf(e1) << 16);
      }
      pk.x = pw[0]; pk.y = pw[1]; pk.z = pw[2]; pk.w = pw[3];
      *reinterpret_cast<uint4*>(&Asm[row][seg * 8]) = pk;
    }
    // stage B: Bsm[n][kk] = bf16(Att[n0+n][k0+kk])
    for (int u = tid; u < 64 * 4; u += 256) {
      const int n = u >> 2, seg = u & 3;
      const int gn = n0 + n, gk = k0 + seg * 8;
      const float* src = Ab + (size_t)gn * N + gk;
      uint4 pk;
      uint pw[4];
#pragma unroll
      for (int h = 0; h < 4; h++) {
        const bool v0 = (gn < N) && (gk + 2 * h < N);
        const bool v1 = (gn < N) && (gk + 2 * h + 1 < N);
        const float e0 = v0 ? src[2 * h] : 0.f;
        const float e1 = v1 ? src[2 * h + 1] : 0.f;
        pw[h] = (uint)f2bf(e0) | ((uint)f2bf(e1) << 16);
      }
      pk.x = pw[0]; pk.y = pw[1]; pk.z = pw[2]; pk.w = pw[3];
      *reinterpret_cast<uint4*>(&Bsm[n][seg * 8]) = pk;
    }
    __syncthreads();
    const int koff = (lane >> 4) * 8;
    bf16x8 af[4], bfr[4];
#pragma unroll
    for (int mf = 0; mf < 4; mf++)
      af[mf] = *reinterpret_cast<const bf16x8*>(&Asm[w * 64 + mf * 16 + (lane & 15)][koff]);
#pragma unroll
    for (int nf = 0; nf < 4; nf++)
      bfr[nf] = *reinterpret_cast<const bf16x8*>(&Bsm[nf * 16 + (lane & 15)][koff]);
#pragma unroll
    for (int mf = 0; mf < 4; mf++)
#pragma unroll
      for (int nf = 0; nf < 4; nf++)
        acc[mf][nf] = __builtin_amdgcn_mfma_f32_16x16x32_bf16(af[mf], bfr[nf], acc[mf][nf], 0, 0, 0);
    __syncthreads();
  }
  const float g = *gp;
#pragma unroll
  for (int mf = 0; mf < 4; mf++) {
    const int mbase = w * 64 + mf * 16 + (lane >> 4) * 4;
#pragma unroll
    for (int nf = 0; nf < 4; nf++) {
      const int gn = n0 + nf * 16 + (lane & 15);
      if (gn < N) {
#pragma unroll
        for (int r = 0; r < 4; r++) {
          const size_t idx = ((size_t)b * C + mbase + r) * N + gn;
          xsum[idx] = x[idx] + g * acc[mf][nf][r];
        }
      }
    }
  }
}

// ---------------------------------------------------------------------------
// gram with split-K: e[b,c,d] += sum_{k} x[b,c,k]*x[b,d,k]  (e pre-zeroed)
// ---------------------------------------------------------------------------
template <int KS>
__global__ __launch_bounds__(256) void gram_split_kernel(
    const float* __restrict__ x, float* __restrict__ e, int C, int N) {
  __shared__ float Xs[64][17];
  __shared__ float Ys[64][17];
  const int b = blockIdx.z / KS;
  const int ks = blockIdx.z % KS;
  const int kper = ((N + KS * 16 - 1) / (KS * 16)) * 16;
  const int kstart = ks * kper;
  const int kend = min(N, kstart + kper);
  const int c0 = blockIdx.y * 64, d0 = blockIdx.x * 64;
  const float* xb = x + (size_t)b * C * N;
  const int tid = threadIdx.x, tr = tid >> 4, tc = tid & 15;
  float acc[4][4] = {};
  for (int k0 = kstart; k0 < kend; k0 += 16) {
    for (int i = tid; i < 1024; i += 256) {
      int rr = i >> 4, kk = i & 15;
      int gk = k0 + kk;
      Xs[rr][kk] = (gk < N) ? xb[(size_t)(c0 + rr) * N + gk] : 0.f;
    }
    for (int i = tid; i < 1024; i += 256) {
      int rr = i >> 4, kk = i & 15;
      int gk = k0 + kk;
      Ys[rr][kk] = (gk < N) ? xb[(size_t)(d0 + rr) * N + gk] : 0.f;
    }
    __syncthreads();
#pragma unroll
    for (int kk = 0; kk < 16; ++kk) {
      float a[4], bb[4];
#pragma unroll
      for (int i = 0; i < 4; i++) a[i] = Xs[tr * 4 + i][kk];
#pragma unroll
      for (int j = 0; j < 4; j++) bb[j] = Ys[tc * 4 + j][kk];
#pragma unroll
      for (int i = 0; i < 4; i++)
#pragma unroll
        for (int j = 0; j < 4; j++) acc[i][j] += a[i] * bb[j];
    }
    __syncthreads();
  }
  for (int i = 0; i < 4; i++)
    for (int j = 0; j < 4; j++)
      atomicAdd(&e[((size_t)b * C + c0 + tr * 4 + i) * C + d0 + tc * 4 + j],
                acc[i][j]);
}

// ---------------------------------------------------------------------------
// xsum[b,c,n] += sum_d (w1*Aown[b,c,d] + w2*Aoth[b,c,d]) * x[b,d,n]
// ---------------------------------------------------------------------------
__global__ __launch_bounds__(256) void chan_use_kernel(
    const float* __restrict__ Aown, const float* __restrict__ Aoth,
    const float* __restrict__ w1p, const float* __restrict__ w2p,
    const float* __restrict__ x, float* __restrict__ xsum, int C, int N) {
  __shared__ float Ms[64][17];
  __shared__ float Bs[16][64];
  const int b = blockIdx.z;
  const int c0 = blockIdx.y * 64, n0 = blockIdx.x * 64;
  const float w1 = *w1p, w2 = *w2p;
  const float* Ao = Aown + (size_t)b * C * C;
  const float* Ax = Aoth + (size_t)b * C * C;
  const float* xb = x + (size_t)b * C * N;
  const int tid = threadIdx.x, tr = tid >> 4, tc = tid & 15;
  float acc[4][4] = {};
  for (int k0 = 0; k0 < C; k0 += 16) {
    for (int i = tid; i < 1024; i += 256) {
      int rr = i >> 4, kk = i & 15;
      size_t ii = (size_t)(c0 + rr) * C + k0 + kk;
      Ms[rr][kk] = w1 * Ao[ii] + w2 * Ax[ii];
    }
    for (int i = tid; i < 1024; i += 256) {
      int kk = i >> 6, n = i & 63;
      int gn = n0 + n;
      Bs[kk][n] = (gn < N) ? xb[(size_t)(k0 + kk) * N + gn] : 0.f;
    }
    __syncthreads();
#pragma unroll
    for (int kk = 0; kk < 16; ++kk) {
      float a[4], bb[4];
#pragma unroll
      for (int i = 0; i < 4; i++) a[i] = Ms[tr * 4 + i][kk];
#pragma unroll
      for (int j = 0; j < 4; j++) bb[j] = Bs[kk][tc * 4 + j];
#pragma unroll
      for (int i = 0; i < 4; i++)
#pragma unroll
        for (int j = 0; j < 4; j++) acc[i][j] += a[i] * bb[j];
    }
    __syncthreads();
  }
  for (int i = 0; i < 4; i++) {
    int gc = c0 + tr * 4 + i;
    for (int j = 0; j < 4; j++) {
      int gn = n0 + tc * 4 + j;
      if (gn < N) xsum[((size_t)b * C + gc) * N + gn] += acc[i][j];
    }
  }
}

// ---------------------------------------------------------------------------
// bias fill: buf[b][o][p] = bias[o]
// ---------------------------------------------------------------------------
__global__ __launch_bounds__(256) void bias_fill_kernel(
    float* __restrict__ buf, const float* __restrict__ bias, int OC, int N,
    int total) {
  const int i = blockIdx.x * 256 + threadIdx.x;
  if (i >= total) return;
  buf[i] = bias[(i / N) % OC];
}

// ---------------------------------------------------------------------------
// offset conv as tiled GEMM (split-K, om pre-filled with bias)
// ---------------------------------------------------------------------------
template <int KS>
__global__ __launch_bounds__(256) void offconv_gemm_kernel(
    const float* __restrict__ xsum, const float* __restrict__ ow,
    float* __restrict__ om, int H, int Wd) {
  constexpr int C = 256, KTOT = C * 9;
  constexpr int KPER = KTOT / KS;
  __shared__ float As[16][33];
  __shared__ float Bs[16][64];
  const int N = H * Wd;
  const int p0 = blockIdx.x * 64;
  const int b = blockIdx.y / KS;
  const int ks = blockIdx.y % KS;
  const int tid = threadIdx.x;
  const int to = tid & 31, tp = tid >> 5;
  const float* xb = xsum + (size_t)b * C * N;
  float acc[8] = {};
  const int kstart = ks * KPER;
  for (int k0 = kstart; k0 < kstart + KPER; k0 += 16) {
    for (int i = tid; i < 512; i += 256) {
      int kk = i >> 5, o = i & 31;
      As[kk][o] = (o < 27) ? ow[(size_t)o * KTOT + k0 + kk] : 0.f;
    }
    for (int i = tid; i < 1024; i += 256) {
      int kk = i >> 6, n = i & 63;
      int K = k0 + kk;
      int c = K / 9, tap = K - c * 9;
      int dy = tap / 3 - 1, dx = tap - (tap / 3) * 3 - 1;
      int p = p0 + n;
      float v = 0.f;
      if (p < N) {
        int h = p / Wd, w = p - (p / Wd) * Wd;
        int hh = h + dy, ww = w + dx;
        if (hh >= 0 && hh < H && ww >= 0 && ww < Wd)
          v = xb[(size_t)c * N + hh * Wd + ww];
      }
      Bs[kk][n] = v;
    }
    __syncthreads();
#pragma unroll
    for (int kk = 0; kk < 16; ++kk) {
      float a = As[kk][to];
#pragma unroll
      for (int j = 0; j < 8; j++) acc[j] += a * Bs[kk][tp * 8 + j];
    }
    __syncthreads();
  }
  if (to < 27) {
    for (int j = 0; j < 8; j++) {
      int p = p0 + tp * 8 + j;
      if (p < N) atomicAdd(&om[((size_t)b * 27 + to) * N + p], acc[j]);
    }
  }
}

// ---------------------------------------------------------------------------
// reorder+convert DCN weights (O,C,3,3) fp32 -> Awb[o][k=tap*256+c] bf16
// ---------------------------------------------------------------------------
__global__ __launch_bounds__(256) void dcnw_prep_kernel(
    const float* __restrict__ W, ushort* __restrict__ Awb) {
  const int i = blockIdx.x * 256 + threadIdx.x;
  if (i >= 256 * 2304) return;
  const int o = i / 2304, k = i % 2304;
  const int tap = k >> 8, c = k & 255;
  Awb[i] = f2bf(W[(size_t)o * 2304 + c * 9 + tap]);
}

// ---------------------------------------------------------------------------
// precompute bilinear gather indices & weights per (b, kpos, p)
// ---------------------------------------------------------------------------
__global__ __launch_bounds__(256) void prep_offsets_kernel(
    const float* __restrict__ om, int4* __restrict__ idx4,
    float4* __restrict__ wgt4, int B, int H, int Wd) {
  const int N = H * Wd;
  const int i = blockIdx.x * 256 + threadIdx.x;
  if (i >= B * 9 * N) return;
  const int p = i % N;
  const int k = (i / N) % 9;
  const int b = i / (9 * N);
  const float* omb = om + (size_t)b * 27 * N;
  const float offy = omb[(size_t)k * N + p];
  const float offx = omb[(size_t)(9 + k) * N + p];
  const float mraw = omb[(size_t)(18 + k) * N + p];
  const float mval = 1.f / (1.f + __expf(-mraw));
  const int ky = k / 3, kx = k - (k / 3) * 3;
  const int h = p / Wd, w = p - (p / Wd) * Wd;
  const float py = offy + (float)(h + ky - 1);
  const float px = offx + (float)(w + kx - 1);
  const float y0f = floorf(py), x0f = floorf(px);
  const float wy = py - y0f, wx = px - x0f;
  const int y0 = (int)y0f, x0 = (int)x0f;
  int idxs[4];
  float wts[4];
  const int ys[2] = {y0, y0 + 1};
  const int xs2[2] = {x0, x0 + 1};
  const float wyv[2] = {1.f - wy, wy};
  const float wxv[2] = {1.f - wx, wx};
#pragma unroll
  for (int a = 0; a < 2; a++)
#pragma unroll
    for (int bb = 0; bb < 2; bb++) {
      const int yi = ys[a], xi = xs2[bb];
      const bool valid = (yi >= 0) && (yi < H) && (xi >= 0) && (xi < Wd);
      const int yc = min(max(yi, 0), H - 1);
      const int xc = min(max(xi, 0), Wd - 1);
      idxs[a * 2 + bb] = yc * Wd + xc;
      wts[a * 2 + bb] = valid ? wyv[a] * wxv[bb] * mval : 0.f;
    }
  idx4[i] = make_int4(idxs[0], idxs[1], idxs[2], idxs[3]);
  wgt4[i] = make_float4(wts[0], wts[1], wts[2], wts[3]);
}

// ---------------------------------------------------------------------------
// DCN via MFMA: out[b,o,p] = bias[o] + sum_{K=kpos*256+c} Awb[o][K]*gather(K,p)
// M=256 full, N-tile 64, K=2304, BK=32. Gather fused into B-stage.
// grid (ceil(N/64), 1, B)
// ---------------------------------------------------------------------------
__global__ __launch_bounds__(256) void dcn_mfma_kernel(
    const float* __restrict__ xsum, const int4* __restrict__ idx4,
    const float4* __restrict__ wgt4, const ushort* __restrict__ Awb,
    const float* __restrict__ bias, float* __restrict__ out, int N) {
  constexpr int C = 256, KTOT = 2304;
  __shared__ ushort Asm[256][40];
  __shared__ ushort Bsm[64][40];
  __shared__ int si[4][64];
  __shared__ float sw[4][64];
  const int b = blockIdx.z;
  const int n0 = blockIdx.x * 64;
  const int tid = threadIdx.x, lane = tid & 63, w = tid >> 6;
  const float* xb = xsum + (size_t)b * C * N;
  f32x4 acc[4][4];
#pragma unroll
  for (int i = 0; i < 4; i++)
#pragma unroll
    for (int j = 0; j < 4; j++) acc[i][j] = (f32x4){0.f, 0.f, 0.f, 0.f};
  for (int s = 0; s < KTOT / 32; ++s) {
    const int k0 = s * 32;
    const int kpos = k0 >> 8, c0 = k0 & 255;
    if (c0 == 0) {
      if (tid < 64) {
        const int p = n0 + tid;
        if (p < N) {
          const size_t base = ((size_t)b * 9 + kpos) * N + p;
          const int4 iv = idx4[base];
          const float4 wv = wgt4[base];
          si[0][tid] = iv.x; si[1][tid] = iv.y; si[2][tid] = iv.z; si[3][tid] = iv.w;
          sw[0][tid] = wv.x; sw[1][tid] = wv.y; sw[2][tid] = wv.z; sw[3][tid] = wv.w;
        } else {
          si[0][tid] = si[1][tid] = si[2][tid] = si[3][tid] = 0;
          sw[0][tid] = sw[1][tid] = sw[2][tid] = sw[3][tid] = 0.f;
        }
      }
      __syncthreads();
    }
    // stage A: bf16 weight tile copy (16B chunks)
    for (int u = tid; u < 256 * 4; u += 256) {
      const int row = u >> 2, seg = u & 3;
      *reinterpret_cast<uint4*>(&Asm[row][seg * 8]) =
          *reinterpret_cast<const uint4*>(&Awb[(size_t)row * KTOT + k0 + seg * 8]);
    }
    // stage B: gather 2 channels per unit, pack bf16 pair
    for (int u = tid; u < 64 * 16; u += 256) {
      const int n = u & 63, pr = u >> 6;
      const int kk = pr * 2;
      const float* r0 = xb + (size_t)(c0 + kk) * N;
      const float* r1 = r0 + N;
      const int i0 = si[0][n], i1 = si[1][n], i2 = si[2][n], i3 = si[3][n];
      const float w0 = sw[0][n], w1 = sw[1][n], w2 = sw[2][n], w3 = sw[3][n];
      const float v0 = w0 * r0[i0] + w1 * r0[i1] + w2 * r0[i2] + w3 * r0[i3];
      const float v1 = w0 * r1[i0] + w1 * r1[i1] + w2 * r1[i2] + w3 * r1[i3];
      *reinterpret_cast<uint*>(&Bsm[n][kk]) =
          (uint)f2bf(v0) | ((uint)f2bf(v1) << 16);
    }
    __syncthreads();
    const int koff = (lane >> 4) * 8;
    bf16x8 af[4], bfr[4];
#pragma unroll
    for (int mf = 0; mf < 4; mf++)
      af[mf] = *reinterpret_cast<const bf16x8*>(&Asm[w * 64 + mf * 16 + (lane & 15)][koff]);
#pragma unroll
    for (int nf = 0; nf < 4; nf++)
      bfr[nf] = *reinterpret_cast<const bf16x8*>(&Bsm[nf * 16 + (lane & 15)][koff]);
#pragma unroll
    for (int mf = 0; mf < 4; mf++)
#pragma unroll
      for (int nf = 0; nf < 4; nf++)
        acc[mf][nf] = __builtin_amdgcn_mfma_f32_16x16x32_bf16(af[mf], bfr[nf], acc[mf][nf], 0, 0, 0);
    __syncthreads();
  }
#pragma unroll
  for (int mf = 0; mf < 4; mf++) {
    const int mbase = w * 64 + mf * 16 + (lane >> 4) * 4;
#pragma unroll
    for (int nf = 0; nf < 4; nf++) {
      const int gn = n0 + nf * 16 + (lane & 15);
      if (gn < N) {
#pragma unroll
        for (int r = 0; r < 4; r++) {
          out[((size_t)b * C + mbase + r) * N + gn] = acc[mf][nf][r] + bias[mbase + r];
        }
      }
    }
  }
}

// ---------------------------------------------------------------------------
extern "C" void kernel_launch(void* const* d_in, const int* in_sizes, int n_in,
                              void* d_out, int out_size, void* d_ws, size_t ws_size,
                              hipStream_t stream) {
  const float* t_in = (const float*)d_in[0];
  const float* s_in = (const float*)d_in[1];
  const float* t_qw = (const float*)d_in[2];
  const float* t_qb = (const float*)d_in[3];
  const float* t_kw = (const float*)d_in[4];
  const float* t_kb = (const float*)d_in[5];
  const float* t_vw = (const float*)d_in[6];
  const float* t_vb = (const float*)d_in[7];
  const float* t_g = (const float*)d_in[8];
  const float* s_qw = (const float*)d_in[9];
  const float* s_qb = (const float*)d_in[10];
  const float* s_kw = (const float*)d_in[11];
  const float* s_kb = (const float*)d_in[12];
  const float* s_vw = (const float*)d_in[13];
  const float* s_vb = (const float*)d_in[14];
  const float* s_g = (const float*)d_in[15];
  const float* w_t_ch = (const float*)d_in[16];
  const float* w_s_ch = (const float*)d_in[17];
  const float* w_s2t = (const float*)d_in[18];
  const float* w_t2s = (const float*)d_in[19];
  const float* t_off_w = (const float*)d_in[20];
  const float* t_off_b = (const float*)d_in[21];
  const float* t_dcn_w = (const float*)d_in[22];
  const float* t_dcn_b = (const float*)d_in[23];
  const float* s_off_w = (const float*)d_in[24];
  const float* s_off_b = (const float*)d_in[25];
  const float* s_dcn_w = (const float*)d_in[26];
  const float* s_dcn_b = (const float*)d_in[27];
  (void)in_sizes; (void)n_in; (void)out_size; (void)ws_size;

  constexpr int Bn = 16, C = 256, QKd = 32;
  constexpr int HT = 15, WT = 15, NT = HT * WT;    // 225
  constexpr int HS = 31, WS2 = 31, NS = HS * WS2;  // 961

  float* ws = (float*)d_ws;
  size_t off = 0;
  auto alloc = [&](size_t n) { float* p = ws + off; off += n; return p; };
  float* q_t = alloc((size_t)Bn * QKd * NT);
  float* k_t = alloc((size_t)Bn * QKd * NT);
  float* v_t = alloc((size_t)Bn * C * NT);
  float* q_s = alloc((size_t)Bn * QKd * NS);
  float* k_s = alloc((size_t)Bn * QKd * NS);
  float* v_s = alloc((size_t)Bn * C * NS);
  float* At = alloc((size_t)Bn * NT * NT);
  float* As = alloc((size_t)Bn * NS * NS);
  float* xt = alloc((size_t)Bn * C * NT);
  float* xs = alloc((size_t)Bn * C * NS);
  float* Atc = alloc((size_t)Bn * C * C);
  float* Asc = alloc((size_t)Bn * C * C);
  float* om_t = alloc((size_t)Bn * 27 * NT);
  float* om_s = alloc((size_t)Bn * 27 * NS);
  ushort* Awb_t = (ushort*)alloc((size_t)256 * 2304 / 2);
  ushort* Awb_s = (ushort*)alloc((size_t)256 * 2304 / 2);
  float* prep_t = alloc((size_t)Bn * 9 * NT * 8);
  float* prep_s = alloc((size_t)Bn * 9 * NS * 8);
  int4* idx_t = (int4*)prep_t;
  float4* wgt_t = (float4*)(prep_t + (size_t)Bn * 9 * NT * 4);
  int4* idx_s = (int4*)prep_s;
  float4* wgt_s = (float4*)(prep_s + (size_t)Bn * 9 * NS * 4);

  dim3 blk(256);

  // q, k, v (conv1x1)
  conv1x1_kernel<<<dim3(4, 1, Bn), blk, 0, stream>>>(t_in, t_qw, t_qb, q_t, C, NT, QKd);
  conv1x1_kernel<<<dim3(4, 1, Bn), blk, 0, stream>>>(t_in, t_kw, t_kb, k_t, C, NT, QKd);
  conv1x1_kernel<<<dim3(4, 4, Bn), blk, 0, stream>>>(t_in, t_vw, t_vb, v_t, C, NT, C);
  conv1x1_kernel<<<dim3(16, 1, Bn), blk, 0, stream>>>(s_in, s_qw, s_qb, q_s, C, NS, QKd);
  conv1x1_kernel<<<dim3(16, 1, Bn), blk, 0, stream>>>(s_in, s_kw, s_kb, k_s, C, NS, QKd);
  conv1x1_kernel<<<dim3(16, 4, Bn), blk, 0, stream>>>(s_in, s_vw, s_vb, v_s, C, NS, C);

  // spatial attention
  energy_kernel<<<dim3(4, 4, Bn), blk, 0, stream>>>(q_t, k_t, At, QKd, NT);
  energy_kernel<<<dim3(16, 16, Bn), blk, 0, stream>>>(q_s, k_s, As, QKd, NS);
  softmax_rows_kernel<<<dim3(Bn * NT), blk, 0, stream>>>(At, NT, 1.f);
  softmax_rows_kernel<<<dim3(Bn * NS), blk, 0, stream>>>(As, NS, 1.f);
  pv_mfma_kernel<<<dim3(4, 1, Bn), blk, 0, stream>>>(v_t, At, t_in, t_g, xt, NT);
  pv_mfma_kernel<<<dim3(16, 1, Bn), blk, 0, stream>>>(v_s, As, s_in, s_g, xs, NS);

  // channel attention (A = softmax(-gram)), split-K gram
  hipMemsetAsync(Atc, 0, (size_t)Bn * C * C * sizeof(float), stream);
  hipMemsetAsync(Asc, 0, (size_t)Bn * C * C * sizeof(float), stream);
  gram_split_kernel<2><<<dim3(4, 4, Bn * 2), blk, 0, stream>>>(t_in, Atc, C, NT);
  gram_split_kernel<4><<<dim3(4, 4, Bn * 4), blk, 0, stream>>>(s_in, Asc, C, NS);
  softmax_rows_kernel<<<dim3(Bn * C), blk, 0, stream>>>(Atc, C, -1.f);
  softmax_rows_kernel<<<dim3(Bn * C), blk, 0, stream>>>(Asc, C, -1.f);
  chan_use_kernel<<<dim3(4, 4, Bn), blk, 0, stream>>>(Atc, Asc, w_t_ch, w_s2t, t_in, xt, C, NT);
  chan_use_kernel<<<dim3(16, 4, Bn), blk, 0, stream>>>(Asc, Atc, w_s_ch, w_t2s, s_in, xs, C, NS);

  // offsets: om pre-filled with bias, split-K GEMM accumulates
  bias_fill_kernel<<<dim3((Bn * 27 * NT + 255) / 256), blk, 0, stream>>>(om_t, t_off_b, 27, NT, Bn * 27 * NT);
  bias_fill_kernel<<<dim3((Bn * 27 * NS + 255) / 256), blk, 0, stream>>>(om_s, s_off_b, 27, NS, Bn * 27 * NS);
  offconv_gemm_kernel<8><<<dim3(4, Bn * 8), blk, 0, stream>>>(xt, t_off_w, om_t, HT, WT);
  offconv_gemm_kernel<2><<<dim3(16, Bn * 2), blk, 0, stream>>>(xs, s_off_w, om_s, HS, WS2);

  // DCN prep
  dcnw_prep_kernel<<<dim3((256 * 2304 + 255) / 256), blk, 0, stream>>>(t_dcn_w, Awb_t);
  dcnw_prep_kernel<<<dim3((256 * 2304 + 255) / 256), blk, 0, stream>>>(s_dcn_w, Awb_s);
  prep_offsets_kernel<<<dim3((Bn * 9 * NT + 255) / 256), blk, 0, stream>>>(om_t, idx_t, wgt_t, Bn, HT, WT);
  prep_offsets_kernel<<<dim3((Bn * 9 * NS + 255) / 256), blk, 0, stream>>>(om_s, idx_s, wgt_s, Bn, HS, WS2);

  float* out_t = (float*)d_out;
  float* out_s = out_t + (size_t)Bn * C * NT;
  dcn_mfma_kernel<<<dim3(4, 1, Bn), blk, 0, stream>>>(xt, idx_t, wgt_t, Awb_t, t_dcn_b, out_t, NT);
  dcn_mfma_kernel<<<dim3(16, 1, Bn), blk, 0, stream>>>(xs, idx_s, wgt_s, Awb_s, s_dcn_b, out_s, NS);
}

// Round 4
// 1231.517 us; speedup vs baseline: 1.3924x; 1.3924x over previous
//
#include <hip/hip_runtime.h>
#include <hip/hip_bf16.h>
#include <cmath>

typedef __attribute__((ext_vector_type(8))) short bf16x8;
typedef __attribute__((ext_vector_type(4))) float f32x4;

__device__ inline ushort f2bf(float f) {
  __hip_bfloat16 h = __float2bfloat16(f);
  return *reinterpret_cast<ushort*>(&h);
}
__device__ inline float bf2f(ushort u) {
  return __uint_as_float((uint)u << 16);
}

// ---------------------------------------------------------------------------
// conv1x1 (fp32 out): out[b,oc,n] = bias[oc] + sum_c w[oc,c] * x[b,c,n]
// ---------------------------------------------------------------------------
__global__ __launch_bounds__(256) void conv1x1_kernel(
    const float* __restrict__ x, const float* __restrict__ w,
    const float* __restrict__ bias, float* __restrict__ out,
    int C, int N, int OC) {
  __shared__ float As[64][17];
  __shared__ float Bs[16][64];
  const int b = blockIdx.z;
  const int m0 = blockIdx.y * 64, n0 = blockIdx.x * 64;
  const float* xb = x + (size_t)b * C * N;
  const int tid = threadIdx.x;
  const int tr = tid >> 4, tc = tid & 15;
  float acc[4][4] = {};
  for (int k0 = 0; k0 < C; k0 += 16) {
    for (int i = tid; i < 64 * 16; i += 256) {
      int m = i >> 4, kk = i & 15;
      int gm = m0 + m;
      As[m][kk] = (gm < OC) ? w[(size_t)gm * C + k0 + kk] : 0.f;
    }
    for (int i = tid; i < 16 * 64; i += 256) {
      int kk = i >> 6, n = i & 63;
      int gn = n0 + n;
      Bs[kk][n] = (gn < N) ? xb[(size_t)(k0 + kk) * N + gn] : 0.f;
    }
    __syncthreads();
#pragma unroll
    for (int kk = 0; kk < 16; ++kk) {
      float a[4], bb[4];
#pragma unroll
      for (int i = 0; i < 4; i++) a[i] = As[tr * 4 + i][kk];
#pragma unroll
      for (int j = 0; j < 4; j++) bb[j] = Bs[kk][tc * 4 + j];
#pragma unroll
      for (int i = 0; i < 4; i++)
#pragma unroll
        for (int j = 0; j < 4; j++) acc[i][j] += a[i] * bb[j];
    }
    __syncthreads();
  }
  for (int i = 0; i < 4; i++) {
    int gm = m0 + tr * 4 + i;
    if (gm >= OC) continue;
    float bv = bias[gm];
    for (int j = 0; j < 4; j++) {
      int gn = n0 + tc * 4 + j;
      if (gn < N) out[((size_t)b * OC + gm) * N + gn] = acc[i][j] + bv;
    }
  }
}

// ---------------------------------------------------------------------------
// conv1x1 with bf16 output into padded [OC][Np] rows; pads zeroed.
// grid (ceil(Np/64), OC/64, B)
// ---------------------------------------------------------------------------
__global__ __launch_bounds__(256) void conv1x1_bf16_kernel(
    const float* __restrict__ x, const float* __restrict__ w,
    const float* __restrict__ bias, ushort* __restrict__ out,
    int C, int N, int Np, int OC) {
  __shared__ float As[64][17];
  __shared__ float Bs[16][64];
  const int b = blockIdx.z;
  const int m0 = blockIdx.y * 64, n0 = blockIdx.x * 64;
  const float* xb = x + (size_t)b * C * N;
  const int tid = threadIdx.x;
  const int tr = tid >> 4, tc = tid & 15;
  float acc[4][4] = {};
  for (int k0 = 0; k0 < C; k0 += 16) {
    for (int i = tid; i < 64 * 16; i += 256) {
      int m = i >> 4, kk = i & 15;
      As[m][kk] = w[(size_t)(m0 + m) * C + k0 + kk];
    }
    for (int i = tid; i < 16 * 64; i += 256) {
      int kk = i >> 6, n = i & 63;
      int gn = n0 + n;
      Bs[kk][n] = (gn < N) ? xb[(size_t)(k0 + kk) * N + gn] : 0.f;
    }
    __syncthreads();
#pragma unroll
    for (int kk = 0; kk < 16; ++kk) {
      float a[4], bb[4];
#pragma unroll
      for (int i = 0; i < 4; i++) a[i] = As[tr * 4 + i][kk];
#pragma unroll
      for (int j = 0; j < 4; j++) bb[j] = Bs[kk][tc * 4 + j];
#pragma unroll
      for (int i = 0; i < 4; i++)
#pragma unroll
        for (int j = 0; j < 4; j++) acc[i][j] += a[i] * bb[j];
    }
    __syncthreads();
  }
  for (int i = 0; i < 4; i++) {
    int gm = m0 + tr * 4 + i;
    float bv = bias[gm];
    for (int j = 0; j < 4; j++) {
      int gn = n0 + tc * 4 + j;
      if (gn >= Np) continue;
      size_t o = ((size_t)b * OC + gm) * Np + gn;
      out[o] = (gn < N) ? f2bf(acc[i][j] + bv) : (ushort)0;
    }
  }
}

// ---------------------------------------------------------------------------
// energy -> bf16 scores: S[b][n][m] = sum_q q[b,q,n]*k[b,q,m], padded cols
// grid (ceil(Np/64) [m], ceil(N/64) [n], B)
// ---------------------------------------------------------------------------
__global__ __launch_bounds__(256) void energy_bf16_kernel(
    const float* __restrict__ qg, const float* __restrict__ kg,
    ushort* __restrict__ Sbf, int QKd, int N, int Np) {
  __shared__ float As[16][64];
  __shared__ float Bs[16][64];
  const int b = blockIdx.z;
  const int n0 = blockIdx.y * 64, m0 = blockIdx.x * 64;
  const float* qb = qg + (size_t)b * QKd * N;
  const float* kb = kg + (size_t)b * QKd * N;
  const int tid = threadIdx.x, tr = tid >> 4, tc = tid & 15;
  float acc[4][4] = {};
  for (int k0 = 0; k0 < QKd; k0 += 16) {
    for (int i = tid; i < 16 * 64; i += 256) {
      int kk = i >> 6, n = i & 63;
      int gn = n0 + n;
      As[kk][n] = (gn < N) ? qb[(size_t)(k0 + kk) * N + gn] : 0.f;
    }
    for (int i = tid; i < 16 * 64; i += 256) {
      int kk = i >> 6, m = i & 63;
      int gm = m0 + m;
      Bs[kk][m] = (gm < N) ? kb[(size_t)(k0 + kk) * N + gm] : 0.f;
    }
    __syncthreads();
#pragma unroll
    for (int kk = 0; kk < 16; ++kk) {
      float a[4], bb[4];
#pragma unroll
      for (int i = 0; i < 4; i++) a[i] = As[kk][tr * 4 + i];
#pragma unroll
      for (int j = 0; j < 4; j++) bb[j] = Bs[kk][tc * 4 + j];
#pragma unroll
      for (int i = 0; i < 4; i++)
#pragma unroll
        for (int j = 0; j < 4; j++) acc[i][j] += a[i] * bb[j];
    }
    __syncthreads();
  }
  for (int i = 0; i < 4; i++) {
    int gn = n0 + tr * 4 + i;
    if (gn >= N) continue;
    ushort* rw = Sbf + ((size_t)b * N + gn) * Np;
    for (int j = 0; j < 4; j++) {
      int gm = m0 + tc * 4 + j;
      if (gm < N) rw[gm] = f2bf(acc[i][j]);
      else if (gm < Np) rw[gm] = 0;
    }
  }
}

// ---------------------------------------------------------------------------
// fp32 in-place row softmax of sign*r (used for channel attention)
// ---------------------------------------------------------------------------
__global__ __launch_bounds__(256) void softmax_rows_kernel(
    float* __restrict__ e, int N, float sign) {
  const size_t row = blockIdx.x;
  float* r = e + row * (size_t)N;
  const int tid = threadIdx.x;
  __shared__ float red[4];
  float mx = -1e30f;
  for (int i = tid; i < N; i += 256) mx = fmaxf(mx, sign * r[i]);
#pragma unroll
  for (int off = 32; off; off >>= 1) mx = fmaxf(mx, __shfl_xor(mx, off, 64));
  if ((tid & 63) == 0) red[tid >> 6] = mx;
  __syncthreads();
  if (tid == 0) {
    float m2 = red[0];
    for (int i = 1; i < 4; i++) m2 = fmaxf(m2, red[i]);
    red[0] = m2;
  }
  __syncthreads();
  mx = red[0];
  __syncthreads();
  float s = 0.f;
  for (int i = tid; i < N; i += 256) {
    float v = __expf(sign * r[i] - mx);
    r[i] = v;
    s += v;
  }
#pragma unroll
  for (int off = 32; off; off >>= 1) s += __shfl_xor(s, off, 64);
  if ((tid & 63) == 0) red[tid >> 6] = s;
  __syncthreads();
  if (tid == 0) {
    float t = 0.f;
    for (int i = 0; i < 4; i++) t += red[i];
    red[0] = t;
  }
  __syncthreads();
  const float inv = 1.f / red[0];
  for (int i = tid; i < N; i += 256) r[i] *= inv;
}

// ---------------------------------------------------------------------------
// bf16 in-place row softmax (spatial attention scores). Pads stay zero.
// grid = (#rows = B*N), block 256.
// ---------------------------------------------------------------------------
__global__ __launch_bounds__(256) void softmax_bf16_kernel(
    ushort* __restrict__ Sbf, int N, int Np) {
  __shared__ float buf[992];
  __shared__ float red[4];
  const size_t row = blockIdx.x;
  ushort* r = Sbf + row * (size_t)Np;
  const int tid = threadIdx.x;
  float mx = -1e30f;
  for (int i = tid; i < N; i += 256) {
    float f = bf2f(r[i]);
    buf[i] = f;
    mx = fmaxf(mx, f);
  }
#pragma unroll
  for (int off = 32; off; off >>= 1) mx = fmaxf(mx, __shfl_xor(mx, off, 64));
  if ((tid & 63) == 0) red[tid >> 6] = mx;
  __syncthreads();
  if (tid == 0) {
    float m2 = red[0];
    for (int i = 1; i < 4; i++) m2 = fmaxf(m2, red[i]);
    red[0] = m2;
  }
  __syncthreads();
  mx = red[0];
  __syncthreads();
  float s = 0.f;
  for (int i = tid; i < N; i += 256) {
    float v = __expf(buf[i] - mx);
    buf[i] = v;
    s += v;
  }
#pragma unroll
  for (int off = 32; off; off >>= 1) s += __shfl_xor(s, off, 64);
  if ((tid & 63) == 0) red[tid >> 6] = s;
  __syncthreads();
  if (tid == 0) {
    float t = 0.f;
    for (int i = 0; i < 4; i++) t += red[i];
    red[0] = t;
  }
  __syncthreads();
  const float inv = 1.f / red[0];
  for (int i = tid; i < N; i += 256) r[i] = f2bf(buf[i] * inv);
}

// ---------------------------------------------------------------------------
// PV via MFMA, all-bf16 staged inputs.
// xsum[b,c,n] = x[b,c,n] + g * sum_m vbf[b,c,m]*Abf[b,n,m]
// template: MS = M-split (BM = 256/MS), NW = waves/block.
// grid (ceil(N/64), MS, B), block NW*64
// ---------------------------------------------------------------------------
template <int MS, int NW>
__global__ __launch_bounds__(NW * 64) void pv_mfma_kernel(
    const ushort* __restrict__ vbf, const ushort* __restrict__ Abf,
    const float* __restrict__ x, const float* __restrict__ gp,
    float* __restrict__ xsum, int N, int Np) {
  constexpr int C = 256;
  constexpr int BM = C / MS;
  constexpr int WM = BM / 64;
  constexpr int WN = NW / WM;
  constexpr int NF = 4 / WN;
  __shared__ ushort Asm[BM][40];
  __shared__ ushort Bsm[64][40];
  const int b = blockIdx.z;
  const int n0 = blockIdx.x * 64;
  const int m0 = blockIdx.y * BM;
  const int tid = threadIdx.x, lane = tid & 63, w = tid >> 6;
  const int wr = w / WN, wc = w % WN;
  const ushort* vb = vbf + (size_t)b * C * Np;
  const ushort* Ab = Abf + (size_t)b * (size_t)N * Np;
  f32x4 acc[4][NF];
#pragma unroll
  for (int i = 0; i < 4; i++)
#pragma unroll
    for (int j = 0; j < NF; j++) acc[i][j] = (f32x4){0.f, 0.f, 0.f, 0.f};
  for (int k0 = 0; k0 < Np; k0 += 32) {
    for (int u = tid; u < BM * 4; u += NW * 64) {
      const int row = u >> 2, seg = u & 3;
      *reinterpret_cast<uint4*>(&Asm[row][seg * 8]) =
          *reinterpret_cast<const uint4*>(&vb[(size_t)(m0 + row) * Np + k0 + seg * 8]);
    }
    for (int u = tid; u < 64 * 4; u += NW * 64) {
      const int row = u >> 2, seg = u & 3;
      const int gn = n0 + row;
      uint4 val;
      if (gn < N)
        val = *reinterpret_cast<const uint4*>(&Ab[(size_t)gn * Np + k0 + seg * 8]);
      else
        val = make_uint4(0, 0, 0, 0);
      *reinterpret_cast<uint4*>(&Bsm[row][seg * 8]) = val;
    }
    __syncthreads();
    const int koff = (lane >> 4) * 8;
    bf16x8 af[4];
    bf16x8 bfr[NF];
#pragma unroll
    for (int mf = 0; mf < 4; mf++)
      af[mf] = *reinterpret_cast<const bf16x8*>(&Asm[wr * 64 + mf * 16 + (lane & 15)][koff]);
#pragma unroll
    for (int nf = 0; nf < NF; nf++)
      bfr[nf] = *reinterpret_cast<const bf16x8*>(&Bsm[wc * NF * 16 + nf * 16 + (lane & 15)][koff]);
#pragma unroll
    for (int mf = 0; mf < 4; mf++)
#pragma unroll
      for (int nf = 0; nf < NF; nf++)
        acc[mf][nf] = __builtin_amdgcn_mfma_f32_16x16x32_bf16(af[mf], bfr[nf], acc[mf][nf], 0, 0, 0);
    __syncthreads();
  }
  const float g = *gp;
#pragma unroll
  for (int mf = 0; mf < 4; mf++) {
    const int mbase = m0 + wr * 64 + mf * 16 + ((lane >> 4) * 4);
#pragma unroll
    for (int nf = 0; nf < NF; nf++) {
      const int gn = n0 + wc * NF * 16 + nf * 16 + (lane & 15);
      if (gn < N) {
#pragma unroll
        for (int rr = 0; rr < 4; rr++) {
          const size_t idx = ((size_t)b * C + mbase + rr) * N + gn;
          xsum[idx] = x[idx] + g * acc[mf][nf][rr];
        }
      }
    }
  }
}

// ---------------------------------------------------------------------------
// gram with split-K (e pre-zeroed, atomicAdd)
// ---------------------------------------------------------------------------
template <int KS>
__global__ __launch_bounds__(256) void gram_split_kernel(
    const float* __restrict__ x, float* __restrict__ e, int C, int N) {
  __shared__ float Xs[64][17];
  __shared__ float Ys[64][17];
  const int b = blockIdx.z / KS;
  const int ks = blockIdx.z % KS;
  const int kper = ((N + KS * 16 - 1) / (KS * 16)) * 16;
  const int kstart = ks * kper;
  const int kend = min(N, kstart + kper);
  const int c0 = blockIdx.y * 64, d0 = blockIdx.x * 64;
  const float* xb = x + (size_t)b * C * N;
  const int tid = threadIdx.x, tr = tid >> 4, tc = tid & 15;
  float acc[4][4] = {};
  for (int k0 = kstart; k0 < kend; k0 += 16) {
    for (int i = tid; i < 1024; i += 256) {
      int rr = i >> 4, kk = i & 15;
      int gk = k0 + kk;
      Xs[rr][kk] = (gk < N) ? xb[(size_t)(c0 + rr) * N + gk] : 0.f;
    }
    for (int i = tid; i < 1024; i += 256) {
      int rr = i >> 4, kk = i & 15;
      int gk = k0 + kk;
      Ys[rr][kk] = (gk < N) ? xb[(size_t)(d0 + rr) * N + gk] : 0.f;
    }
    __syncthreads();
#pragma unroll
    for (int kk = 0; kk < 16; ++kk) {
      float a[4], bb[4];
#pragma unroll
      for (int i = 0; i < 4; i++) a[i] = Xs[tr * 4 + i][kk];
#pragma unroll
      for (int j = 0; j < 4; j++) bb[j] = Ys[tc * 4 + j][kk];
#pragma unroll
      for (int i = 0; i < 4; i++)
#pragma unroll
        for (int j = 0; j < 4; j++) acc[i][j] += a[i] * bb[j];
    }
    __syncthreads();
  }
  for (int i = 0; i < 4; i++)
    for (int j = 0; j < 4; j++)
      atomicAdd(&e[((size_t)b * C + c0 + tr * 4 + i) * C + d0 + tc * 4 + j],
                acc[i][j]);
}

// ---------------------------------------------------------------------------
// xsum[b,c,n] += sum_d (w1*Aown[b,c,d] + w2*Aoth[b,c,d]) * x[b,d,n]
// ---------------------------------------------------------------------------
__global__ __launch_bounds__(256) void chan_use_kernel(
    const float* __restrict__ Aown, const float* __restrict__ Aoth,
    const float* __restrict__ w1p, const float* __restrict__ w2p,
    const float* __restrict__ x, float* __restrict__ xsum, int C, int N) {
  __shared__ float Ms[64][17];
  __shared__ float Bs[16][64];
  const int b = blockIdx.z;
  const int c0 = blockIdx.y * 64, n0 = blockIdx.x * 64;
  const float w1 = *w1p, w2 = *w2p;
  const float* Ao = Aown + (size_t)b * C * C;
  const float* Ax = Aoth + (size_t)b * C * C;
  const float* xb = x + (size_t)b * C * N;
  const int tid = threadIdx.x, tr = tid >> 4, tc = tid & 15;
  float acc[4][4] = {};
  for (int k0 = 0; k0 < C; k0 += 16) {
    for (int i = tid; i < 1024; i += 256) {
      int rr = i >> 4, kk = i & 15;
      size_t ii = (size_t)(c0 + rr) * C + k0 + kk;
      Ms[rr][kk] = w1 * Ao[ii] + w2 * Ax[ii];
    }
    for (int i = tid; i < 1024; i += 256) {
      int kk = i >> 6, n = i & 63;
      int gn = n0 + n;
      Bs[kk][n] = (gn < N) ? xb[(size_t)(k0 + kk) * N + gn] : 0.f;
    }
    __syncthreads();
#pragma unroll
    for (int kk = 0; kk < 16; ++kk) {
      float a[4], bb[4];
#pragma unroll
      for (int i = 0; i < 4; i++) a[i] = Ms[tr * 4 + i][kk];
#pragma unroll
      for (int j = 0; j < 4; j++) bb[j] = Bs[kk][tc * 4 + j];
#pragma unroll
      for (int i = 0; i < 4; i++)
#pragma unroll
        for (int j = 0; j < 4; j++) acc[i][j] += a[i] * bb[j];
    }
    __syncthreads();
  }
  for (int i = 0; i < 4; i++) {
    int gc = c0 + tr * 4 + i;
    for (int j = 0; j < 4; j++) {
      int gn = n0 + tc * 4 + j;
      if (gn < N) xsum[((size_t)b * C + gc) * N + gn] += acc[i][j];
    }
  }
}

// ---------------------------------------------------------------------------
// bias fill: buf[b][o][p] = bias[o]
// ---------------------------------------------------------------------------
__global__ __launch_bounds__(256) void bias_fill_kernel(
    float* __restrict__ buf, const float* __restrict__ bias, int OC, int N,
    int total) {
  const int i = blockIdx.x * 256 + threadIdx.x;
  if (i >= total) return;
  buf[i] = bias[(i / N) % OC];
}

// ---------------------------------------------------------------------------
// offset conv as tiled GEMM (split-K, om pre-filled with bias)
// ---------------------------------------------------------------------------
template <int KS>
__global__ __launch_bounds__(256) void offconv_gemm_kernel(
    const float* __restrict__ xsum, const float* __restrict__ ow,
    float* __restrict__ om, int H, int Wd) {
  constexpr int C = 256, KTOT = C * 9;
  constexpr int KPER = KTOT / KS;
  __shared__ float As[16][33];
  __shared__ float Bs[16][64];
  const int N = H * Wd;
  const int p0 = blockIdx.x * 64;
  const int b = blockIdx.y / KS;
  const int ks = blockIdx.y % KS;
  const int tid = threadIdx.x;
  const int to = tid & 31, tp = tid >> 5;
  const float* xb = xsum + (size_t)b * C * N;
  float acc[8] = {};
  const int kstart = ks * KPER;
  for (int k0 = kstart; k0 < kstart + KPER; k0 += 16) {
    for (int i = tid; i < 512; i += 256) {
      int kk = i >> 5, o = i & 31;
      As[kk][o] = (o < 27) ? ow[(size_t)o * KTOT + k0 + kk] : 0.f;
    }
    for (int i = tid; i < 1024; i += 256) {
      int kk = i >> 6, n = i & 63;
      int K = k0 + kk;
      int c = K / 9, tap = K - c * 9;
      int dy = tap / 3 - 1, dx = tap - (tap / 3) * 3 - 1;
      int p = p0 + n;
      float v = 0.f;
      if (p < N) {
        int h = p / Wd, w = p - (p / Wd) * Wd;
        int hh = h + dy, ww = w + dx;
        if (hh >= 0 && hh < H && ww >= 0 && ww < Wd)
          v = xb[(size_t)c * N + hh * Wd + ww];
      }
      Bs[kk][n] = v;
    }
    __syncthreads();
#pragma unroll
    for (int kk = 0; kk < 16; ++kk) {
      float a = As[kk][to];
#pragma unroll
      for (int j = 0; j < 8; j++) acc[j] += a * Bs[kk][tp * 8 + j];
    }
    __syncthreads();
  }
  if (to < 27) {
    for (int j = 0; j < 8; j++) {
      int p = p0 + tp * 8 + j;
      if (p < N) atomicAdd(&om[((size_t)b * 27 + to) * N + p], acc[j]);
    }
  }
}

// ---------------------------------------------------------------------------
// reorder+convert DCN weights (O,C,3,3) fp32 -> Awb[o][k=tap*256+c] bf16
// ---------------------------------------------------------------------------
__global__ __launch_bounds__(256) void dcnw_prep_kernel(
    const float* __restrict__ W, ushort* __restrict__ Awb) {
  const int i = blockIdx.x * 256 + threadIdx.x;
  if (i >= 256 * 2304) return;
  const int o = i / 2304, k = i % 2304;
  const int tap = k >> 8, c = k & 255;
  Awb[i] = f2bf(W[(size_t)o * 2304 + c * 9 + tap]);
}

// ---------------------------------------------------------------------------
// precompute bilinear gather indices & weights per (b, kpos, p)
// ---------------------------------------------------------------------------
__global__ __launch_bounds__(256) void prep_offsets_kernel(
    const float* __restrict__ om, int4* __restrict__ idx4,
    float4* __restrict__ wgt4, int B, int H, int Wd) {
  const int N = H * Wd;
  const int i = blockIdx.x * 256 + threadIdx.x;
  if (i >= B * 9 * N) return;
  const int p = i % N;
  const int k = (i / N) % 9;
  const int b = i / (9 * N);
  const float* omb = om + (size_t)b * 27 * N;
  const float offy = omb[(size_t)k * N + p];
  const float offx = omb[(size_t)(9 + k) * N + p];
  const float mraw = omb[(size_t)(18 + k) * N + p];
  const float mval = 1.f / (1.f + __expf(-mraw));
  const int ky = k / 3, kx = k - (k / 3) * 3;
  const int h = p / Wd, w = p - (p / Wd) * Wd;
  const float py = offy + (float)(h + ky - 1);
  const float px = offx + (float)(w + kx - 1);
  const float y0f = floorf(py), x0f = floorf(px);
  const float wy = py - y0f, wx = px - x0f;
  const int y0 = (int)y0f, x0 = (int)x0f;
  int idxs[4];
  float wts[4];
  const int ys[2] = {y0, y0 + 1};
  const int xs2[2] = {x0, x0 + 1};
  const float wyv[2] = {1.f - wy, wy};
  const float wxv[2] = {1.f - wx, wx};
#pragma unroll
  for (int a = 0; a < 2; a++)
#pragma unroll
    for (int bb = 0; bb < 2; bb++) {
      const int yi = ys[a], xi = xs2[bb];
      const bool valid = (yi >= 0) && (yi < H) && (xi >= 0) && (xi < Wd);
      const int yc = min(max(yi, 0), H - 1);
      const int xc = min(max(xi, 0), Wd - 1);
      idxs[a * 2 + bb] = yc * Wd + xc;
      wts[a * 2 + bb] = valid ? wyv[a] * wxv[bb] * mval : 0.f;
    }
  idx4[i] = make_int4(idxs[0], idxs[1], idxs[2], idxs[3]);
  wgt4[i] = make_float4(wts[0], wts[1], wts[2], wts[3]);
}

// ---------------------------------------------------------------------------
// DCN via MFMA with fused gather. template MS (BM=256/MS), NW waves.
// grid (ceil(N/64), MS, B), block NW*64
// ---------------------------------------------------------------------------
template <int MS, int NW>
__global__ __launch_bounds__(NW * 64) void dcn_mfma_kernel(
    const float* __restrict__ xsum, const int4* __restrict__ idx4,
    const float4* __restrict__ wgt4, const ushort* __restrict__ Awb,
    const float* __restrict__ bias, float* __restrict__ out, int N) {
  constexpr int C = 256, KTOT = 2304;
  constexpr int BM = C / MS;
  constexpr int WM = BM / 64;
  constexpr int WN = NW / WM;
  constexpr int NF = 4 / WN;
  __shared__ ushort Asm[BM][40];
  __shared__ ushort Bsm[64][40];
  __shared__ int si[4][64];
  __shared__ float sw[4][64];
  const int b = blockIdx.z;
  const int n0 = blockIdx.x * 64;
  const int m0 = blockIdx.y * BM;
  const int tid = threadIdx.x, lane = tid & 63, w = tid >> 6;
  const int wr = w / WN, wc = w % WN;
  const float* xb = xsum + (size_t)b * C * N;
  f32x4 acc[4][NF];
#pragma unroll
  for (int i = 0; i < 4; i++)
#pragma unroll
    for (int j = 0; j < NF; j++) acc[i][j] = (f32x4){0.f, 0.f, 0.f, 0.f};
  for (int k0 = 0; k0 < KTOT; k0 += 32) {
    const int kpos = k0 >> 8, c0 = k0 & 255;
    if (c0 == 0) {
      if (tid < 64) {
        const int p = n0 + tid;
        if (p < N) {
          const size_t base = ((size_t)b * 9 + kpos) * N + p;
          const int4 iv = idx4[base];
          const float4 wv = wgt4[base];
          si[0][tid] = iv.x; si[1][tid] = iv.y; si[2][tid] = iv.z; si[3][tid] = iv.w;
          sw[0][tid] = wv.x; sw[1][tid] = wv.y; sw[2][tid] = wv.z; sw[3][tid] = wv.w;
        } else {
          si[0][tid] = si[1][tid] = si[2][tid] = si[3][tid] = 0;
          sw[0][tid] = sw[1][tid] = sw[2][tid] = sw[3][tid] = 0.f;
        }
      }
      __syncthreads();
    }
    // stage A: bf16 weight tile copy
    for (int u = tid; u < BM * 4; u += NW * 64) {
      const int row = u >> 2, seg = u & 3;
      *reinterpret_cast<uint4*>(&Asm[row][seg * 8]) =
          *reinterpret_cast<const uint4*>(&Awb[(size_t)(m0 + row) * KTOT + k0 + seg * 8]);
    }
    // stage B: gather 2 channels per unit, pack bf16 pair
    for (int u = tid; u < 64 * 16; u += NW * 64) {
      const int n = u & 63, pr = u >> 6;
      const int kk = pr * 2;
      const float* r0 = xb + (size_t)(c0 + kk) * N;
      const float* r1 = r0 + N;
      const int i0 = si[0][n], i1 = si[1][n], i2 = si[2][n], i3 = si[3][n];
      const float w0 = sw[0][n], w1 = sw[1][n], w2 = sw[2][n], w3 = sw[3][n];
      const float v0 = w0 * r0[i0] + w1 * r0[i1] + w2 * r0[i2] + w3 * r0[i3];
      const float v1 = w0 * r1[i0] + w1 * r1[i1] + w2 * r1[i2] + w3 * r1[i3];
      *reinterpret_cast<uint*>(&Bsm[n][kk]) =
          (uint)f2bf(v0) | ((uint)f2bf(v1) << 16);
    }
    __syncthreads();
    const int koff = (lane >> 4) * 8;
    bf16x8 af[4];
    bf16x8 bfr[NF];
#pragma unroll
    for (int mf = 0; mf < 4; mf++)
      af[mf] = *reinterpret_cast<const bf16x8*>(&Asm[wr * 64 + mf * 16 + (lane & 15)][koff]);
#pragma unroll
    for (int nf = 0; nf < NF; nf++)
      bfr[nf] = *reinterpret_cast<const bf16x8*>(&Bsm[wc * NF * 16 + nf * 16 + (lane & 15)][koff]);
#pragma unroll
    for (int mf = 0; mf < 4; mf++)
#pragma unroll
      for (int nf = 0; nf < NF; nf++)
        acc[mf][nf] = __builtin_amdgcn_mfma_f32_16x16x32_bf16(af[mf], bfr[nf], acc[mf][nf], 0, 0, 0);
    __syncthreads();
  }
#pragma unroll
  for (int mf = 0; mf < 4; mf++) {
    const int mbase = m0 + wr * 64 + mf * 16 + ((lane >> 4) * 4);
#pragma unroll
    for (int nf = 0; nf < NF; nf++) {
      const int gn = n0 + wc * NF * 16 + nf * 16 + (lane & 15);
      if (gn < N) {
#pragma unroll
        for (int rr = 0; rr < 4; rr++)
          out[((size_t)b * C + mbase + rr) * N + gn] = acc[mf][nf][rr] + bias[mbase + rr];
      }
    }
  }
}

// ---------------------------------------------------------------------------
extern "C" void kernel_launch(void* const* d_in, const int* in_sizes, int n_in,
                              void* d_out, int out_size, void* d_ws, size_t ws_size,
                              hipStream_t stream) {
  const float* t_in = (const float*)d_in[0];
  const float* s_in = (const float*)d_in[1];
  const float* t_qw = (const float*)d_in[2];
  const float* t_qb = (const float*)d_in[3];
  const float* t_kw = (const float*)d_in[4];
  const float* t_kb = (const float*)d_in[5];
  const float* t_vw = (const float*)d_in[6];
  const float* t_vb = (const float*)d_in[7];
  const float* t_g = (const float*)d_in[8];
  const float* s_qw = (const float*)d_in[9];
  const float* s_qb = (const float*)d_in[10];
  const float* s_kw = (const float*)d_in[11];
  const float* s_kb = (const float*)d_in[12];
  const float* s_vw = (const float*)d_in[13];
  const float* s_vb = (const float*)d_in[14];
  const float* s_g = (const float*)d_in[15];
  const float* w_t_ch = (const float*)d_in[16];
  const float* w_s_ch = (const float*)d_in[17];
  const float* w_s2t = (const float*)d_in[18];
  const float* w_t2s = (const float*)d_in[19];
  const float* t_off_w = (const float*)d_in[20];
  const float* t_off_b = (const float*)d_in[21];
  const float* t_dcn_w = (const float*)d_in[22];
  const float* t_dcn_b = (const float*)d_in[23];
  const float* s_off_w = (const float*)d_in[24];
  const float* s_off_b = (const float*)d_in[25];
  const float* s_dcn_w = (const float*)d_in[26];
  const float* s_dcn_b = (const float*)d_in[27];
  (void)in_sizes; (void)n_in; (void)out_size; (void)ws_size;

  constexpr int Bn = 16, C = 256, QKd = 32;
  constexpr int HT = 15, WT = 15, NT = HT * WT;    // 225
  constexpr int HS = 31, WS2 = 31, NS = HS * WS2;  // 961
  constexpr int NpT = 256, NpS = 992;              // K/col pads (mult of 32)

  float* ws = (float*)d_ws;
  size_t off = 0;
  auto alloc = [&](size_t n) {
    n = (n + 3) & ~(size_t)3;
    float* p = ws + off; off += n; return p;
  };
  auto allocU = [&](size_t nu) { return (ushort*)alloc((nu + 1) / 2); };

  float* q_t = alloc((size_t)Bn * QKd * NT);
  float* k_t = alloc((size_t)Bn * QKd * NT);
  ushort* v_tbf = allocU((size_t)Bn * C * NpT);
  float* q_s = alloc((size_t)Bn * QKd * NS);
  float* k_s = alloc((size_t)Bn * QKd * NS);
  ushort* v_sbf = allocU((size_t)Bn * C * NpS);
  ushort* S_t = allocU((size_t)Bn * NT * NpT);
  ushort* S_s = allocU((size_t)Bn * NS * NpS);
  float* xt = alloc((size_t)Bn * C * NT);
  float* xs = alloc((size_t)Bn * C * NS);
  float* Atc = alloc((size_t)Bn * C * C);
  float* Asc = alloc((size_t)Bn * C * C);
  float* om_t = alloc((size_t)Bn * 27 * NT);
  float* om_s = alloc((size_t)Bn * 27 * NS);
  ushort* Awb_t = allocU((size_t)256 * 2304);
  ushort* Awb_s = allocU((size_t)256 * 2304);
  float* prep_t = alloc((size_t)Bn * 9 * NT * 8);
  float* prep_s = alloc((size_t)Bn * 9 * NS * 8);
  int4* idx_t = (int4*)prep_t;
  float4* wgt_t = (float4*)(prep_t + (size_t)Bn * 9 * NT * 4);
  int4* idx_s = (int4*)prep_s;
  float4* wgt_s = (float4*)(prep_s + (size_t)Bn * 9 * NS * 4);

  dim3 blk(256);

  // q, k (fp32), v (bf16, padded)
  conv1x1_kernel<<<dim3(4, 1, Bn), blk, 0, stream>>>(t_in, t_qw, t_qb, q_t, C, NT, QKd);
  conv1x1_kernel<<<dim3(4, 1, Bn), blk, 0, stream>>>(t_in, t_kw, t_kb, k_t, C, NT, QKd);
  conv1x1_bf16_kernel<<<dim3(NpT / 64, 4, Bn), blk, 0, stream>>>(t_in, t_vw, t_vb, v_tbf, C, NT, NpT, C);
  conv1x1_kernel<<<dim3(16, 1, Bn), blk, 0, stream>>>(s_in, s_qw, s_qb, q_s, C, NS, QKd);
  conv1x1_kernel<<<dim3(16, 1, Bn), blk, 0, stream>>>(s_in, s_kw, s_kb, k_s, C, NS, QKd);
  conv1x1_bf16_kernel<<<dim3((NpS + 63) / 64, 4, Bn), blk, 0, stream>>>(s_in, s_vw, s_vb, v_sbf, C, NS, NpS, C);

  // spatial attention: energy -> bf16 scores -> in-place softmax -> PV (MFMA)
  energy_bf16_kernel<<<dim3(NpT / 64, 4, Bn), blk, 0, stream>>>(q_t, k_t, S_t, QKd, NT, NpT);
  energy_bf16_kernel<<<dim3((NpS + 63) / 64, 16, Bn), blk, 0, stream>>>(q_s, k_s, S_s, QKd, NS, NpS);
  softmax_bf16_kernel<<<dim3(Bn * NT), blk, 0, stream>>>(S_t, NT, NpT);
  softmax_bf16_kernel<<<dim3(Bn * NS), blk, 0, stream>>>(S_s, NS, NpS);
  pv_mfma_kernel<4, 4><<<dim3(4, 4, Bn), blk, 0, stream>>>(v_tbf, S_t, t_in, t_g, xt, NT, NpT);
  pv_mfma_kernel<2, 4><<<dim3(16, 2, Bn), blk, 0, stream>>>(v_sbf, S_s, s_in, s_g, xs, NS, NpS);

  // channel attention (A = softmax(-gram)), split-K gram
  hipMemsetAsync(Atc, 0, (size_t)Bn * C * C * sizeof(float), stream);
  hipMemsetAsync(Asc, 0, (size_t)Bn * C * C * sizeof(float), stream);
  gram_split_kernel<2><<<dim3(4, 4, Bn * 2), blk, 0, stream>>>(t_in, Atc, C, NT);
  gram_split_kernel<4><<<dim3(4, 4, Bn * 4), blk, 0, stream>>>(s_in, Asc, C, NS);
  softmax_rows_kernel<<<dim3(Bn * C), blk, 0, stream>>>(Atc, C, -1.f);
  softmax_rows_kernel<<<dim3(Bn * C), blk, 0, stream>>>(Asc, C, -1.f);
  chan_use_kernel<<<dim3(4, 4, Bn), blk, 0, stream>>>(Atc, Asc, w_t_ch, w_s2t, t_in, xt, C, NT);
  chan_use_kernel<<<dim3(16, 4, Bn), blk, 0, stream>>>(Asc, Atc, w_s_ch, w_t2s, s_in, xs, C, NS);

  // offsets: om pre-filled with bias, split-K GEMM accumulates
  bias_fill_kernel<<<dim3((Bn * 27 * NT + 255) / 256), blk, 0, stream>>>(om_t, t_off_b, 27, NT, Bn * 27 * NT);
  bias_fill_kernel<<<dim3((Bn * 27 * NS + 255) / 256), blk, 0, stream>>>(om_s, s_off_b, 27, NS, Bn * 27 * NS);
  offconv_gemm_kernel<8><<<dim3(4, Bn * 8), blk, 0, stream>>>(xt, t_off_w, om_t, HT, WT);
  offconv_gemm_kernel<2><<<dim3(16, Bn * 2), blk, 0, stream>>>(xs, s_off_w, om_s, HS, WS2);

  // DCN prep
  dcnw_prep_kernel<<<dim3((256 * 2304 + 255) / 256), blk, 0, stream>>>(t_dcn_w, Awb_t);
  dcnw_prep_kernel<<<dim3((256 * 2304 + 255) / 256), blk, 0, stream>>>(s_dcn_w, Awb_s);
  prep_offsets_kernel<<<dim3((Bn * 9 * NT + 255) / 256), blk, 0, stream>>>(om_t, idx_t, wgt_t, Bn, HT, WT);
  prep_offsets_kernel<<<dim3((Bn * 9 * NS + 255) / 256), blk, 0, stream>>>(om_s, idx_s, wgt_s, Bn, HS, WS2);

  float* out_t = (float*)d_out;
  float* out_s = out_t + (size_t)Bn * C * NT;
  dcn_mfma_kernel<4, 4><<<dim3(4, 4, Bn), dim3(256), 0, stream>>>(xt, idx_t, wgt_t, Awb_t, t_dcn_b, out_t, NT);
  dcn_mfma_kernel<1, 8><<<dim3(16, 1, Bn), dim3(512), 0, stream>>>(xs, idx_s, wgt_s, Awb_s, s_dcn_b, out_s, NS);
}

// Round 5
// 976.048 us; speedup vs baseline: 1.7568x; 1.2617x over previous
//
#include <hip/hip_runtime.h>
#include <hip/hip_bf16.h>
#include <cmath>

typedef __attribute__((ext_vector_type(8))) short bf16x8;
typedef __attribute__((ext_vector_type(4))) float f32x4;

__device__ inline ushort f2bf(float f) {
  __hip_bfloat16 h = __float2bfloat16(f);
  return *reinterpret_cast<ushort*>(&h);
}
__device__ inline float bf2f(ushort u) {
  return __uint_as_float((uint)u << 16);
}

// XCD-aware bijective remap (requires grid total % 8 == 0): XCD r = id%8 gets
// a contiguous work chunk -> same-batch blocks cluster on one XCD's L2.
__device__ inline void xcd_remap(int& bx, int& by, int& bz) {
  const int gx = gridDim.x, gy = gridDim.y, gz = gridDim.z;
  const int total = gx * gy * gz;
  int id = blockIdx.x + gx * (blockIdx.y + gy * blockIdx.z);
  int wid = (id & 7) * (total >> 3) + (id >> 3);
  bx = wid % gx;
  wid /= gx;
  by = wid % gy;
  bz = wid / gy;
}

// ---------------------------------------------------------------------------
// conv1x1 (fp32): q/k projections only (OC=32)
// ---------------------------------------------------------------------------
__global__ __launch_bounds__(256) void conv1x1_kernel(
    const float* __restrict__ x, const float* __restrict__ w,
    const float* __restrict__ bias, float* __restrict__ out,
    int C, int N, int OC) {
  __shared__ float As[64][17];
  __shared__ float Bs[16][64];
  const int b = blockIdx.z;
  const int m0 = blockIdx.y * 64, n0 = blockIdx.x * 64;
  const float* xb = x + (size_t)b * C * N;
  const int tid = threadIdx.x;
  const int tr = tid >> 4, tc = tid & 15;
  float acc[4][4] = {};
  for (int k0 = 0; k0 < C; k0 += 16) {
    for (int i = tid; i < 64 * 16; i += 256) {
      int m = i >> 4, kk = i & 15;
      int gm = m0 + m;
      As[m][kk] = (gm < OC) ? w[(size_t)gm * C + k0 + kk] : 0.f;
    }
    for (int i = tid; i < 16 * 64; i += 256) {
      int kk = i >> 6, n = i & 63;
      int gn = n0 + n;
      Bs[kk][n] = (gn < N) ? xb[(size_t)(k0 + kk) * N + gn] : 0.f;
    }
    __syncthreads();
#pragma unroll
    for (int kk = 0; kk < 16; ++kk) {
      float a[4], bb[4];
#pragma unroll
      for (int i = 0; i < 4; i++) a[i] = As[tr * 4 + i][kk];
#pragma unroll
      for (int j = 0; j < 4; j++) bb[j] = Bs[kk][tc * 4 + j];
#pragma unroll
      for (int i = 0; i < 4; i++)
#pragma unroll
        for (int j = 0; j < 4; j++) acc[i][j] += a[i] * bb[j];
    }
    __syncthreads();
  }
  for (int i = 0; i < 4; i++) {
    int gm = m0 + tr * 4 + i;
    if (gm >= OC) continue;
    float bv = bias[gm];
    for (int j = 0; j < 4; j++) {
      int gn = n0 + tc * 4 + j;
      if (gn < N) out[((size_t)b * OC + gm) * N + gn] = acc[i][j] + bv;
    }
  }
}

// ---------------------------------------------------------------------------
// cast+transpose: x fp32 [C][N] -> xT bf16 [NR][C] (rows >= N zeroed)
// grid (NR/64, C/64, B)
// ---------------------------------------------------------------------------
__global__ __launch_bounds__(256) void cast_transpose_kernel(
    const float* __restrict__ x, ushort* __restrict__ xT, int C, int N,
    int NR) {
  __shared__ float T[64][65];
  const int b = blockIdx.z;
  const int n0 = blockIdx.x * 64, c0 = blockIdx.y * 64;
  const float* xb = x + (size_t)b * C * N;
  const int tid = threadIdx.x;
  for (int u = tid; u < 4096; u += 256) {
    const int cc = u >> 6, nn = u & 63;
    const int gn = n0 + nn;
    T[cc][nn] = (gn < N) ? xb[(size_t)(c0 + cc) * N + gn] : 0.f;
  }
  __syncthreads();
  ushort* ob = xT + (size_t)b * NR * C;
  for (int u = tid; u < 4096; u += 256) {
    const int nn = u >> 6, cc = u & 63;
    ob[(size_t)(n0 + nn) * C + c0 + cc] = f2bf(T[cc][nn]);
  }
}

// ---------------------------------------------------------------------------
// elementwise fp32 -> bf16 cast (weights)
// ---------------------------------------------------------------------------
__global__ __launch_bounds__(256) void castw_kernel(
    const float* __restrict__ W, ushort* __restrict__ out, int total) {
  const int i = blockIdx.x * 256 + threadIdx.x;
  if (i < total) out[i] = f2bf(W[i]);
}

// ---------------------------------------------------------------------------
// Mcomb = bf16(w1*Aown + w2*Aoth)  (channel-attention combined matrix)
// ---------------------------------------------------------------------------
__global__ __launch_bounds__(256) void mcomb_kernel(
    const float* __restrict__ Ao, const float* __restrict__ Ax,
    const float* __restrict__ w1p, const float* __restrict__ w2p,
    ushort* __restrict__ out, int total) {
  const int i = blockIdx.x * 256 + threadIdx.x;
  if (i < total) out[i] = f2bf((*w1p) * Ao[i] + (*w2p) * Ax[i]);
}

// ---------------------------------------------------------------------------
// generic bf16 GEMM: out[m][n] = sum_k A[m][k] * Bt[n][k], M=256.
// EPI 0: outBf[b][m][Np] = bf16(acc+bias[m]) (cols>=N zeroed)   [conv1x1-v]
// EPI 1: outF[b][m][N]  += acc                                  [chan_use]
// grid (NR/64, MS, B), block NW*64. XCD-swizzled.
// ---------------------------------------------------------------------------
template <int MS, int NW, int EPI>
__global__ __launch_bounds__(NW * 64) void gemm_abf_kernel(
    const ushort* __restrict__ A, int aPerBatch,
    const ushort* __restrict__ Bt, const float* __restrict__ bias,
    ushort* __restrict__ outBf, float* __restrict__ outF,
    int N, int Np, int NR, int Kp) {
  constexpr int CM = 256;
  constexpr int BM = CM / MS;
  constexpr int WM = BM / 64;
  constexpr int WN = NW / WM;
  constexpr int NF = 4 / WN;
  __shared__ ushort Asm[BM][40];
  __shared__ ushort Bsm[64][40];
  int bx, by, bz;
  xcd_remap(bx, by, bz);
  const int n0 = bx * 64, m0 = by * BM, b = bz;
  const ushort* Ab = A + (size_t)(aPerBatch ? b : 0) * CM * Kp;
  const ushort* Bb = Bt + (size_t)b * NR * Kp;
  const int tid = threadIdx.x, lane = tid & 63, w = tid >> 6;
  const int wr = w / WN, wc = w % WN;
  f32x4 acc[4][NF];
#pragma unroll
  for (int i = 0; i < 4; i++)
#pragma unroll
    for (int j = 0; j < NF; j++) acc[i][j] = (f32x4){0.f, 0.f, 0.f, 0.f};
  for (int k0 = 0; k0 < Kp; k0 += 32) {
    for (int u = tid; u < BM * 4; u += NW * 64) {
      const int row = u >> 2, seg = u & 3;
      *reinterpret_cast<uint4*>(&Asm[row][seg * 8]) =
          *reinterpret_cast<const uint4*>(&Ab[(size_t)(m0 + row) * Kp + k0 + seg * 8]);
    }
    for (int u = tid; u < 64 * 4; u += NW * 64) {
      const int row = u >> 2, seg = u & 3;
      *reinterpret_cast<uint4*>(&Bsm[row][seg * 8]) =
          *reinterpret_cast<const uint4*>(&Bb[(size_t)(n0 + row) * Kp + k0 + seg * 8]);
    }
    __syncthreads();
    const int koff = (lane >> 4) * 8;
    bf16x8 af[4], bfr[NF];
#pragma unroll
    for (int mf = 0; mf < 4; mf++)
      af[mf] = *reinterpret_cast<const bf16x8*>(&Asm[wr * 64 + mf * 16 + (lane & 15)][koff]);
#pragma unroll
    for (int nf = 0; nf < NF; nf++)
      bfr[nf] = *reinterpret_cast<const bf16x8*>(&Bsm[wc * NF * 16 + nf * 16 + (lane & 15)][koff]);
#pragma unroll
    for (int mf = 0; mf < 4; mf++)
#pragma unroll
      for (int nf = 0; nf < NF; nf++)
        acc[mf][nf] = __builtin_amdgcn_mfma_f32_16x16x32_bf16(af[mf], bfr[nf], acc[mf][nf], 0, 0, 0);
    __syncthreads();
  }
#pragma unroll
  for (int mf = 0; mf < 4; mf++) {
    const int mbase = m0 + wr * 64 + mf * 16 + ((lane >> 4) * 4);
#pragma unroll
    for (int nf = 0; nf < NF; nf++) {
      const int gn = n0 + wc * NF * 16 + nf * 16 + (lane & 15);
#pragma unroll
      for (int rr = 0; rr < 4; rr++) {
        const int m = mbase + rr;
        if (EPI == 0) {
          if (gn < Np) {
            ushort v = (gn < N) ? f2bf(acc[mf][nf][rr] + bias[m]) : (ushort)0;
            outBf[((size_t)b * CM + m) * Np + gn] = v;
          }
        } else {
          if (gn < N) outF[((size_t)b * CM + m) * N + gn] += acc[mf][nf][rr];
        }
      }
    }
  }
}

// ---------------------------------------------------------------------------
// energy via MFMA (K=32): S[b][n][m] = sum_q q[q][n]*k[q][m] -> bf16, padded
// grid (Np/64 [m], ceil(N/64) [n], B), 4 waves. XCD-swizzled.
// ---------------------------------------------------------------------------
__global__ __launch_bounds__(256) void energy_mfma_kernel(
    const float* __restrict__ qg, const float* __restrict__ kg,
    ushort* __restrict__ Sbf, int N, int Np) {
  __shared__ ushort Aq[64][40];
  __shared__ ushort Bk[64][40];
  int bx, by, bz;
  xcd_remap(bx, by, bz);
  const int m0 = bx * 64, n0 = by * 64, b = bz;
  const float* qb = qg + (size_t)b * 32 * N;
  const float* kb = kg + (size_t)b * 32 * N;
  const int tid = threadIdx.x, lane = tid & 63, w = tid >> 6;
  for (int u = tid; u < 2048; u += 256) {
    const int c = u >> 6, nn = u & 63;
    const int gn = n0 + nn, gm = m0 + nn;
    Aq[nn][c] = (gn < N) ? f2bf(qb[(size_t)c * N + gn]) : (ushort)0;
    Bk[nn][c] = (gm < N) ? f2bf(kb[(size_t)c * N + gm]) : (ushort)0;
  }
  __syncthreads();
  const int koff = (lane >> 4) * 8;
  const bf16x8 af = *reinterpret_cast<const bf16x8*>(&Aq[w * 16 + (lane & 15)][koff]);
  f32x4 acc[4];
#pragma unroll
  for (int j = 0; j < 4; j++) {
    const bf16x8 bf = *reinterpret_cast<const bf16x8*>(&Bk[j * 16 + (lane & 15)][koff]);
    acc[j] = __builtin_amdgcn_mfma_f32_16x16x32_bf16(af, bf, (f32x4){0.f, 0.f, 0.f, 0.f}, 0, 0, 0);
  }
#pragma unroll
  for (int j = 0; j < 4; j++) {
    const int m = m0 + j * 16 + (lane & 15);
    if (m >= Np) continue;
#pragma unroll
    for (int r = 0; r < 4; r++) {
      const int n = n0 + w * 16 + (lane >> 4) * 4 + r;
      if (n < N) Sbf[((size_t)b * N + n) * Np + m] = (m < N) ? f2bf(acc[j][r]) : (ushort)0;
    }
  }
}

// ---------------------------------------------------------------------------
// fp32 in-place row softmax of sign*r (channel attention)
// ---------------------------------------------------------------------------
__global__ __launch_bounds__(256) void softmax_rows_kernel(
    float* __restrict__ e, int N, float sign) {
  const size_t row = blockIdx.x;
  float* r = e + row * (size_t)N;
  const int tid = threadIdx.x;
  __shared__ float red[4];
  float mx = -1e30f;
  for (int i = tid; i < N; i += 256) mx = fmaxf(mx, sign * r[i]);
#pragma unroll
  for (int off = 32; off; off >>= 1) mx = fmaxf(mx, __shfl_xor(mx, off, 64));
  if ((tid & 63) == 0) red[tid >> 6] = mx;
  __syncthreads();
  if (tid == 0) {
    float m2 = red[0];
    for (int i = 1; i < 4; i++) m2 = fmaxf(m2, red[i]);
    red[0] = m2;
  }
  __syncthreads();
  mx = red[0];
  __syncthreads();
  float s = 0.f;
  for (int i = tid; i < N; i += 256) {
    float v = __expf(sign * r[i] - mx);
    r[i] = v;
    s += v;
  }
#pragma unroll
  for (int off = 32; off; off >>= 1) s += __shfl_xor(s, off, 64);
  if ((tid & 63) == 0) red[tid >> 6] = s;
  __syncthreads();
  if (tid == 0) {
    float t = 0.f;
    for (int i = 0; i < 4; i++) t += red[i];
    red[0] = t;
  }
  __syncthreads();
  const float inv = 1.f / red[0];
  for (int i = tid; i < N; i += 256) r[i] *= inv;
}

// ---------------------------------------------------------------------------
// bf16 in-place row softmax (spatial attention scores)
// ---------------------------------------------------------------------------
__global__ __launch_bounds__(256) void softmax_bf16_kernel(
    ushort* __restrict__ Sbf, int N, int Np) {
  __shared__ float buf[992];
  __shared__ float red[4];
  const size_t row = blockIdx.x;
  ushort* r = Sbf + row * (size_t)Np;
  const int tid = threadIdx.x;
  float mx = -1e30f;
  for (int i = tid; i < N; i += 256) {
    float f = bf2f(r[i]);
    buf[i] = f;
    mx = fmaxf(mx, f);
  }
#pragma unroll
  for (int off = 32; off; off >>= 1) mx = fmaxf(mx, __shfl_xor(mx, off, 64));
  if ((tid & 63) == 0) red[tid >> 6] = mx;
  __syncthreads();
  if (tid == 0) {
    float m2 = red[0];
    for (int i = 1; i < 4; i++) m2 = fmaxf(m2, red[i]);
    red[0] = m2;
  }
  __syncthreads();
  mx = red[0];
  __syncthreads();
  float s = 0.f;
  for (int i = tid; i < N; i += 256) {
    float v = __expf(buf[i] - mx);
    buf[i] = v;
    s += v;
  }
#pragma unroll
  for (int off = 32; off; off >>= 1) s += __shfl_xor(s, off, 64);
  if ((tid & 63) == 0) red[tid >> 6] = s;
  __syncthreads();
  if (tid == 0) {
    float t = 0.f;
    for (int i = 0; i < 4; i++) t += red[i];
    red[0] = t;
  }
  __syncthreads();
  const float inv = 1.f / red[0];
  for (int i = tid; i < N; i += 256) r[i] = f2bf(buf[i] * inv);
}

// ---------------------------------------------------------------------------
// PV via MFMA: xsum = x + g * v @ A^T   (all-bf16 staging), XCD-swizzled
// grid (ceil(NR_n/64), MS, B), block NW*64
// ---------------------------------------------------------------------------
template <int MS, int NW>
__global__ __launch_bounds__(NW * 64) void pv_mfma_kernel(
    const ushort* __restrict__ vbf, const ushort* __restrict__ Abf,
    const float* __restrict__ x, const float* __restrict__ gp,
    float* __restrict__ xsum, int N, int Np) {
  constexpr int C = 256;
  constexpr int BM = C / MS;
  constexpr int WM = BM / 64;
  constexpr int WN = NW / WM;
  constexpr int NF = 4 / WN;
  __shared__ ushort Asm[BM][40];
  __shared__ ushort Bsm[64][40];
  int bx, by, bz;
  xcd_remap(bx, by, bz);
  const int n0 = bx * 64, m0 = by * BM, b = bz;
  const int tid = threadIdx.x, lane = tid & 63, w = tid >> 6;
  const int wr = w / WN, wc = w % WN;
  const ushort* vb = vbf + (size_t)b * C * Np;
  const ushort* Ab = Abf + (size_t)b * (size_t)N * Np;
  f32x4 acc[4][NF];
#pragma unroll
  for (int i = 0; i < 4; i++)
#pragma unroll
    for (int j = 0; j < NF; j++) acc[i][j] = (f32x4){0.f, 0.f, 0.f, 0.f};
  for (int k0 = 0; k0 < Np; k0 += 32) {
    for (int u = tid; u < BM * 4; u += NW * 64) {
      const int row = u >> 2, seg = u & 3;
      *reinterpret_cast<uint4*>(&Asm[row][seg * 8]) =
          *reinterpret_cast<const uint4*>(&vb[(size_t)(m0 + row) * Np + k0 + seg * 8]);
    }
    for (int u = tid; u < 64 * 4; u += NW * 64) {
      const int row = u >> 2, seg = u & 3;
      const int gn = n0 + row;
      uint4 val;
      if (gn < N)
        val = *reinterpret_cast<const uint4*>(&Ab[(size_t)gn * Np + k0 + seg * 8]);
      else
        val = make_uint4(0, 0, 0, 0);
      *reinterpret_cast<uint4*>(&Bsm[row][seg * 8]) = val;
    }
    __syncthreads();
    const int koff = (lane >> 4) * 8;
    bf16x8 af[4], bfr[NF];
#pragma unroll
    for (int mf = 0; mf < 4; mf++)
      af[mf] = *reinterpret_cast<const bf16x8*>(&Asm[wr * 64 + mf * 16 + (lane & 15)][koff]);
#pragma unroll
    for (int nf = 0; nf < NF; nf++)
      bfr[nf] = *reinterpret_cast<const bf16x8*>(&Bsm[wc * NF * 16 + nf * 16 + (lane & 15)][koff]);
#pragma unroll
    for (int mf = 0; mf < 4; mf++)
#pragma unroll
      for (int nf = 0; nf < NF; nf++)
        acc[mf][nf] = __builtin_amdgcn_mfma_f32_16x16x32_bf16(af[mf], bfr[nf], acc[mf][nf], 0, 0, 0);
    __syncthreads();
  }
  const float g = *gp;
#pragma unroll
  for (int mf = 0; mf < 4; mf++) {
    const int mbase = m0 + wr * 64 + mf * 16 + ((lane >> 4) * 4);
#pragma unroll
    for (int nf = 0; nf < NF; nf++) {
      const int gn = n0 + wc * NF * 16 + nf * 16 + (lane & 15);
      if (gn < N) {
#pragma unroll
        for (int rr = 0; rr < 4; rr++) {
          const size_t idx = ((size_t)b * C + mbase + rr) * N + gn;
          xsum[idx] = x[idx] + g * acc[mf][nf][rr];
        }
      }
    }
  }
}

// ---------------------------------------------------------------------------
// gram with split-K (e pre-zeroed, atomicAdd), XCD-swizzled
// ---------------------------------------------------------------------------
template <int KS>
__global__ __launch_bounds__(256) void gram_split_kernel(
    const float* __restrict__ x, float* __restrict__ e, int C, int N) {
  __shared__ float Xs[64][17];
  __shared__ float Ys[64][17];
  int bx, by, bz;
  xcd_remap(bx, by, bz);
  const int b = bz / KS;
  const int ks = bz % KS;
  const int kper = ((N + KS * 16 - 1) / (KS * 16)) * 16;
  const int kstart = ks * kper;
  const int kend = min(N, kstart + kper);
  const int c0 = by * 64, d0 = bx * 64;
  const float* xb = x + (size_t)b * C * N;
  const int tid = threadIdx.x, tr = tid >> 4, tc = tid & 15;
  float acc[4][4] = {};
  for (int k0 = kstart; k0 < kend; k0 += 16) {
    for (int i = tid; i < 1024; i += 256) {
      int rr = i >> 4, kk = i & 15;
      int gk = k0 + kk;
      Xs[rr][kk] = (gk < N) ? xb[(size_t)(c0 + rr) * N + gk] : 0.f;
    }
    for (int i = tid; i < 1024; i += 256) {
      int rr = i >> 4, kk = i & 15;
      int gk = k0 + kk;
      Ys[rr][kk] = (gk < N) ? xb[(size_t)(d0 + rr) * N + gk] : 0.f;
    }
    __syncthreads();
#pragma unroll
    for (int kk = 0; kk < 16; ++kk) {
      float a[4], bb[4];
#pragma unroll
      for (int i = 0; i < 4; i++) a[i] = Xs[tr * 4 + i][kk];
#pragma unroll
      for (int j = 0; j < 4; j++) bb[j] = Ys[tc * 4 + j][kk];
#pragma unroll
      for (int i = 0; i < 4; i++)
#pragma unroll
        for (int j = 0; j < 4; j++) acc[i][j] += a[i] * bb[j];
    }
    __syncthreads();
  }
  for (int i = 0; i < 4; i++)
    for (int j = 0; j < 4; j++)
      atomicAdd(&e[((size_t)b * C + c0 + tr * 4 + i) * C + d0 + tc * 4 + j],
                acc[i][j]);
}

// ---------------------------------------------------------------------------
// bias fill: buf[b][o][p] = bias[o]
// ---------------------------------------------------------------------------
__global__ __launch_bounds__(256) void bias_fill_kernel(
    float* __restrict__ buf, const float* __restrict__ bias, int OC, int N,
    int total) {
  const int i = blockIdx.x * 256 + threadIdx.x;
  if (i >= total) return;
  buf[i] = bias[(i / N) % OC];
}

// ---------------------------------------------------------------------------
// offset conv tiled GEMM (split-K atomicAdd, om pre-biased), XCD-swizzled (2D)
// grid (ceil(N/64), B*KS)
// ---------------------------------------------------------------------------
template <int KS>
__global__ __launch_bounds__(256) void offconv_gemm_kernel(
    const float* __restrict__ xsum, const float* __restrict__ ow,
    float* __restrict__ om, int H, int Wd) {
  constexpr int C = 256, KTOT = C * 9;
  constexpr int KPER = KTOT / KS;
  __shared__ float As[16][33];
  __shared__ float Bs[16][64];
  const int N = H * Wd;
  int bx, by, bz;
  xcd_remap(bx, by, bz);
  const int p0 = bx * 64;
  const int b = by / KS;
  const int ks = by % KS;
  const int tid = threadIdx.x;
  const int to = tid & 31, tp = tid >> 5;
  const float* xb = xsum + (size_t)b * C * N;
  float acc[8] = {};
  const int kstart = ks * KPER;
  for (int k0 = kstart; k0 < kstart + KPER; k0 += 16) {
    for (int i = tid; i < 512; i += 256) {
      int kk = i >> 5, o = i & 31;
      As[kk][o] = (o < 27) ? ow[(size_t)o * KTOT + k0 + kk] : 0.f;
    }
    for (int i = tid; i < 1024; i += 256) {
      int kk = i >> 6, n = i & 63;
      int K = k0 + kk;
      int c = K / 9, tap = K - c * 9;
      int dy = tap / 3 - 1, dx = tap - (tap / 3) * 3 - 1;
      int p = p0 + n;
      float v = 0.f;
      if (p < N) {
        int h = p / Wd, w = p - (p / Wd) * Wd;
        int hh = h + dy, ww = w + dx;
        if (hh >= 0 && hh < H && ww >= 0 && ww < Wd)
          v = xb[(size_t)c * N + hh * Wd + ww];
      }
      Bs[kk][n] = v;
    }
    __syncthreads();
#pragma unroll
    for (int kk = 0; kk < 16; ++kk) {
      float a = As[kk][to];
#pragma unroll
      for (int j = 0; j < 8; j++) acc[j] += a * Bs[kk][tp * 8 + j];
    }
    __syncthreads();
  }
  if (to < 27) {
    for (int j = 0; j < 8; j++) {
      int p = p0 + tp * 8 + j;
      if (p < N) atomicAdd(&om[((size_t)b * 27 + to) * N + p], acc[j]);
    }
  }
}

// ---------------------------------------------------------------------------
// reorder+convert DCN weights (O,C,3,3) fp32 -> Awb[o][k=tap*256+c] bf16
// ---------------------------------------------------------------------------
__global__ __launch_bounds__(256) void dcnw_prep_kernel(
    const float* __restrict__ W, ushort* __restrict__ Awb) {
  const int i = blockIdx.x * 256 + threadIdx.x;
  if (i >= 256 * 2304) return;
  const int o = i / 2304, k = i % 2304;
  const int tap = k >> 8, c = k & 255;
  Awb[i] = f2bf(W[(size_t)o * 2304 + c * 9 + tap]);
}

// ---------------------------------------------------------------------------
// packed bilinear gather table: uint4 = {short4 idx, 4x bf16 weight}
// ---------------------------------------------------------------------------
__global__ __launch_bounds__(256) void prep_offsets_kernel(
    const float* __restrict__ om, uint4* __restrict__ prep, int B, int H,
    int Wd) {
  const int N = H * Wd;
  const int i = blockIdx.x * 256 + threadIdx.x;
  if (i >= B * 9 * N) return;
  const int p = i % N;
  const int k = (i / N) % 9;
  const int b = i / (9 * N);
  const float* omb = om + (size_t)b * 27 * N;
  const float offy = omb[(size_t)k * N + p];
  const float offx = omb[(size_t)(9 + k) * N + p];
  const float mraw = omb[(size_t)(18 + k) * N + p];
  const float mval = 1.f / (1.f + __expf(-mraw));
  const int ky = k / 3, kx = k - (k / 3) * 3;
  const int h = p / Wd, w = p - (p / Wd) * Wd;
  const float py = offy + (float)(h + ky - 1);
  const float px = offx + (float)(w + kx - 1);
  const float y0f = floorf(py), x0f = floorf(px);
  const float wy = py - y0f, wx = px - x0f;
  const int y0 = (int)y0f, x0 = (int)x0f;
  int idxs[4];
  float wts[4];
  const int ys[2] = {y0, y0 + 1};
  const int xs2[2] = {x0, x0 + 1};
  const float wyv[2] = {1.f - wy, wy};
  const float wxv[2] = {1.f - wx, wx};
#pragma unroll
  for (int a = 0; a < 2; a++)
#pragma unroll
    for (int bb = 0; bb < 2; bb++) {
      const int yi = ys[a], xi = xs2[bb];
      const bool valid = (yi >= 0) && (yi < H) && (xi >= 0) && (xi < Wd);
      const int yc = min(max(yi, 0), H - 1);
      const int xc = min(max(xi, 0), Wd - 1);
      idxs[a * 2 + bb] = yc * Wd + xc;
      wts[a * 2 + bb] = valid ? wyv[a] * wxv[bb] * mval : 0.f;
    }
  uint4 pk;
  pk.x = (uint)(ushort)idxs[0] | ((uint)(ushort)idxs[1] << 16);
  pk.y = (uint)(ushort)idxs[2] | ((uint)(ushort)idxs[3] << 16);
  pk.z = (uint)f2bf(wts[0]) | ((uint)f2bf(wts[1]) << 16);
  pk.w = (uint)f2bf(wts[2]) | ((uint)f2bf(wts[3]) << 16);
  prep[i] = pk;
}

// ---------------------------------------------------------------------------
// DCN via MFMA with fused gather, XCD-swizzled, packed prep table.
// grid (ceil(N/64), MS, B), block NW*64
// ---------------------------------------------------------------------------
template <int MS, int NW>
__global__ __launch_bounds__(NW * 64) void dcn_mfma_kernel(
    const float* __restrict__ xsum, const uint4* __restrict__ prep,
    const ushort* __restrict__ Awb, const float* __restrict__ bias,
    float* __restrict__ out, int N) {
  constexpr int C = 256, KTOT = 2304;
  constexpr int BM = C / MS;
  constexpr int WM = BM / 64;
  constexpr int WN = NW / WM;
  constexpr int NF = 4 / WN;
  __shared__ ushort Asm[BM][40];
  __shared__ ushort Bsm[64][40];
  __shared__ int si[4][64];
  __shared__ float sw[4][64];
  int bx, by, bz;
  xcd_remap(bx, by, bz);
  const int n0 = bx * 64, m0 = by * BM, b = bz;
  const int tid = threadIdx.x, lane = tid & 63, w = tid >> 6;
  const int wr = w / WN, wc = w % WN;
  const float* xb = xsum + (size_t)b * C * N;
  f32x4 acc[4][NF];
#pragma unroll
  for (int i = 0; i < 4; i++)
#pragma unroll
    for (int j = 0; j < NF; j++) acc[i][j] = (f32x4){0.f, 0.f, 0.f, 0.f};
  for (int k0 = 0; k0 < KTOT; k0 += 32) {
    const int kpos = k0 >> 8, c0 = k0 & 255;
    if (c0 == 0) {
      if (tid < 64) {
        const int p = n0 + tid;
        if (p < N) {
          const uint4 pk = prep[((size_t)b * 9 + kpos) * N + p];
          si[0][tid] = (int)(pk.x & 0xffff);
          si[1][tid] = (int)(pk.x >> 16);
          si[2][tid] = (int)(pk.y & 0xffff);
          si[3][tid] = (int)(pk.y >> 16);
          sw[0][tid] = bf2f((ushort)(pk.z & 0xffff));
          sw[1][tid] = bf2f((ushort)(pk.z >> 16));
          sw[2][tid] = bf2f((ushort)(pk.w & 0xffff));
          sw[3][tid] = bf2f((ushort)(pk.w >> 16));
        } else {
          si[0][tid] = si[1][tid] = si[2][tid] = si[3][tid] = 0;
          sw[0][tid] = sw[1][tid] = sw[2][tid] = sw[3][tid] = 0.f;
        }
      }
      __syncthreads();
    }
    for (int u = tid; u < BM * 4; u += NW * 64) {
      const int row = u >> 2, seg = u & 3;
      *reinterpret_cast<uint4*>(&Asm[row][seg * 8]) =
          *reinterpret_cast<const uint4*>(&Awb[(size_t)(m0 + row) * KTOT + k0 + seg * 8]);
    }
    for (int u = tid; u < 64 * 16; u += NW * 64) {
      const int n = u & 63, pr = u >> 6;
      const int kk = pr * 2;
      const float* r0 = xb + (size_t)(c0 + kk) * N;
      const float* r1 = r0 + N;
      const int i0 = si[0][n], i1 = si[1][n], i2 = si[2][n], i3 = si[3][n];
      const float w0 = sw[0][n], w1 = sw[1][n], w2 = sw[2][n], w3 = sw[3][n];
      const float v0 = w0 * r0[i0] + w1 * r0[i1] + w2 * r0[i2] + w3 * r0[i3];
      const float v1 = w0 * r1[i0] + w1 * r1[i1] + w2 * r1[i2] + w3 * r1[i3];
      *reinterpret_cast<uint*>(&Bsm[n][kk]) =
          (uint)f2bf(v0) | ((uint)f2bf(v1) << 16);
    }
    __syncthreads();
    const int koff = (lane >> 4) * 8;
    bf16x8 af[4], bfr[NF];
#pragma unroll
    for (int mf = 0; mf < 4; mf++)
      af[mf] = *reinterpret_cast<const bf16x8*>(&Asm[wr * 64 + mf * 16 + (lane & 15)][koff]);
#pragma unroll
    for (int nf = 0; nf < NF; nf++)
      bfr[nf] = *reinterpret_cast<const bf16x8*>(&Bsm[wc * NF * 16 + nf * 16 + (lane & 15)][koff]);
#pragma unroll
    for (int mf = 0; mf < 4; mf++)
#pragma unroll
      for (int nf = 0; nf < NF; nf++)
        acc[mf][nf] = __builtin_amdgcn_mfma_f32_16x16x32_bf16(af[mf], bfr[nf], acc[mf][nf], 0, 0, 0);
    __syncthreads();
  }
#pragma unroll
  for (int mf = 0; mf < 4; mf++) {
    const int mbase = m0 + wr * 64 + mf * 16 + ((lane >> 4) * 4);
#pragma unroll
    for (int nf = 0; nf < NF; nf++) {
      const int gn = n0 + wc * NF * 16 + nf * 16 + (lane & 15);
      if (gn < N) {
#pragma unroll
        for (int rr = 0; rr < 4; rr++)
          out[((size_t)b * C + mbase + rr) * N + gn] = acc[mf][nf][rr] + bias[mbase + rr];
      }
    }
  }
}

// ---------------------------------------------------------------------------
extern "C" void kernel_launch(void* const* d_in, const int* in_sizes, int n_in,
                              void* d_out, int out_size, void* d_ws, size_t ws_size,
                              hipStream_t stream) {
  const float* t_in = (const float*)d_in[0];
  const float* s_in = (const float*)d_in[1];
  const float* t_qw = (const float*)d_in[2];
  const float* t_qb = (const float*)d_in[3];
  const float* t_kw = (const float*)d_in[4];
  const float* t_kb = (const float*)d_in[5];
  const float* t_vw = (const float*)d_in[6];
  const float* t_vb = (const float*)d_in[7];
  const float* t_g = (const float*)d_in[8];
  const float* s_qw = (const float*)d_in[9];
  const float* s_qb = (const float*)d_in[10];
  const float* s_kw = (const float*)d_in[11];
  const float* s_kb = (const float*)d_in[12];
  const float* s_vw = (const float*)d_in[13];
  const float* s_vb = (const float*)d_in[14];
  const float* s_g = (const float*)d_in[15];
  const float* w_t_ch = (const float*)d_in[16];
  const float* w_s_ch = (const float*)d_in[17];
  const float* w_s2t = (const float*)d_in[18];
  const float* w_t2s = (const float*)d_in[19];
  const float* t_off_w = (const float*)d_in[20];
  const float* t_off_b = (const float*)d_in[21];
  const float* t_dcn_w = (const float*)d_in[22];
  const float* t_dcn_b = (const float*)d_in[23];
  const float* s_off_w = (const float*)d_in[24];
  const float* s_off_b = (const float*)d_in[25];
  const float* s_dcn_w = (const float*)d_in[26];
  const float* s_dcn_b = (const float*)d_in[27];
  (void)in_sizes; (void)n_in; (void)out_size; (void)ws_size;

  constexpr int Bn = 16, C = 256, QKd = 32;
  constexpr int HT = 15, WT = 15, NT = HT * WT;    // 225
  constexpr int HS = 31, WS2 = 31, NS = HS * WS2;  // 961
  constexpr int NpT = 256, NpS = 992;              // col pads (mult of 32)
  constexpr int NRT = 256, NRS = 1024;             // row pads (mult of 64)

  float* ws = (float*)d_ws;
  size_t off = 0;
  auto alloc = [&](size_t n) {
    n = (n + 3) & ~(size_t)3;
    float* p = ws + off; off += n; return p;
  };
  auto allocU = [&](size_t nu) { return (ushort*)alloc((nu + 1) / 2); };

  float* q_t = alloc((size_t)Bn * QKd * NT);
  float* k_t = alloc((size_t)Bn * QKd * NT);
  float* q_s = alloc((size_t)Bn * QKd * NS);
  float* k_s = alloc((size_t)Bn * QKd * NS);
  ushort* xT_t = allocU((size_t)Bn * NRT * C);
  ushort* xT_s = allocU((size_t)Bn * NRS * C);
  ushort* Wv_t = allocU((size_t)C * C);
  ushort* Wv_s = allocU((size_t)C * C);
  ushort* v_tbf = allocU((size_t)Bn * C * NpT);
  ushort* v_sbf = allocU((size_t)Bn * C * NpS);
  ushort* S_t = allocU((size_t)Bn * NT * NpT);
  ushort* S_s = allocU((size_t)Bn * NS * NpS);
  float* xt = alloc((size_t)Bn * C * NT);
  float* xs = alloc((size_t)Bn * C * NS);
  float* Atc = alloc((size_t)Bn * C * C);
  float* Asc = alloc((size_t)Bn * C * C);
  ushort* Mc_t = allocU((size_t)Bn * C * C);
  ushort* Mc_s = allocU((size_t)Bn * C * C);
  float* om_t = alloc((size_t)Bn * 27 * NT);
  float* om_s = alloc((size_t)Bn * 27 * NS);
  ushort* Awb_t = allocU((size_t)256 * 2304);
  ushort* Awb_s = allocU((size_t)256 * 2304);
  uint4* prep_t = (uint4*)alloc((size_t)Bn * 9 * NT * 4);
  uint4* prep_s = (uint4*)alloc((size_t)Bn * 9 * NS * 4);

  dim3 blk(256);

  // q, k projections (fp32)
  conv1x1_kernel<<<dim3(4, 1, Bn), blk, 0, stream>>>(t_in, t_qw, t_qb, q_t, C, NT, QKd);
  conv1x1_kernel<<<dim3(4, 1, Bn), blk, 0, stream>>>(t_in, t_kw, t_kb, k_t, C, NT, QKd);
  conv1x1_kernel<<<dim3(16, 1, Bn), blk, 0, stream>>>(s_in, s_qw, s_qb, q_s, C, NS, QKd);
  conv1x1_kernel<<<dim3(16, 1, Bn), blk, 0, stream>>>(s_in, s_kw, s_kb, k_s, C, NS, QKd);

  // bf16 transposed inputs + bf16 weights
  cast_transpose_kernel<<<dim3(NRT / 64, 4, Bn), blk, 0, stream>>>(t_in, xT_t, C, NT, NRT);
  cast_transpose_kernel<<<dim3(NRS / 64, 4, Bn), blk, 0, stream>>>(s_in, xT_s, C, NS, NRS);
  castw_kernel<<<dim3((C * C + 255) / 256), blk, 0, stream>>>(t_vw, Wv_t, C * C);
  castw_kernel<<<dim3((C * C + 255) / 256), blk, 0, stream>>>(s_vw, Wv_s, C * C);

  // v projection via MFMA -> bf16 padded
  gemm_abf_kernel<4, 4, 0><<<dim3(NRT / 64, 4, Bn), blk, 0, stream>>>(
      Wv_t, 0, xT_t, t_vb, v_tbf, nullptr, NT, NpT, NRT, C);
  gemm_abf_kernel<2, 4, 0><<<dim3(NRS / 64, 2, Bn), blk, 0, stream>>>(
      Wv_s, 0, xT_s, s_vb, v_sbf, nullptr, NS, NpS, NRS, C);

  // spatial attention: energy (MFMA) -> softmax -> PV (MFMA)
  energy_mfma_kernel<<<dim3(NpT / 64, 4, Bn), blk, 0, stream>>>(q_t, k_t, S_t, NT, NpT);
  energy_mfma_kernel<<<dim3((NpS + 63) / 64, 16, Bn), blk, 0, stream>>>(q_s, k_s, S_s, NS, NpS);
  softmax_bf16_kernel<<<dim3(Bn * NT), blk, 0, stream>>>(S_t, NT, NpT);
  softmax_bf16_kernel<<<dim3(Bn * NS), blk, 0, stream>>>(S_s, NS, NpS);
  pv_mfma_kernel<4, 4><<<dim3(4, 4, Bn), blk, 0, stream>>>(v_tbf, S_t, t_in, t_g, xt, NT, NpT);
  pv_mfma_kernel<2, 4><<<dim3(16, 2, Bn), blk, 0, stream>>>(v_sbf, S_s, s_in, s_g, xs, NS, NpS);

  // channel attention: gram (fp32 split-K) -> softmax -> combined-M GEMM
  hipMemsetAsync(Atc, 0, (size_t)Bn * C * C * sizeof(float), stream);
  hipMemsetAsync(Asc, 0, (size_t)Bn * C * C * sizeof(float), stream);
  gram_split_kernel<2><<<dim3(4, 4, Bn * 2), blk, 0, stream>>>(t_in, Atc, C, NT);
  gram_split_kernel<4><<<dim3(4, 4, Bn * 4), blk, 0, stream>>>(s_in, Asc, C, NS);
  softmax_rows_kernel<<<dim3(Bn * C), blk, 0, stream>>>(Atc, C, -1.f);
  softmax_rows_kernel<<<dim3(Bn * C), blk, 0, stream>>>(Asc, C, -1.f);
  mcomb_kernel<<<dim3((Bn * C * C + 255) / 256), blk, 0, stream>>>(Atc, Asc, w_t_ch, w_s2t, Mc_t, Bn * C * C);
  mcomb_kernel<<<dim3((Bn * C * C + 255) / 256), blk, 0, stream>>>(Asc, Atc, w_s_ch, w_t2s, Mc_s, Bn * C * C);
  gemm_abf_kernel<4, 4, 1><<<dim3(NRT / 64, 4, Bn), blk, 0, stream>>>(
      Mc_t, 1, xT_t, nullptr, nullptr, xt, NT, NpT, NRT, C);
  gemm_abf_kernel<2, 4, 1><<<dim3(NRS / 64, 2, Bn), blk, 0, stream>>>(
      Mc_s, 1, xT_s, nullptr, nullptr, xs, NS, NpS, NRS, C);

  // offsets: om pre-filled with bias, split-K GEMM accumulates
  bias_fill_kernel<<<dim3((Bn * 27 * NT + 255) / 256), blk, 0, stream>>>(om_t, t_off_b, 27, NT, Bn * 27 * NT);
  bias_fill_kernel<<<dim3((Bn * 27 * NS + 255) / 256), blk, 0, stream>>>(om_s, s_off_b, 27, NS, Bn * 27 * NS);
  offconv_gemm_kernel<8><<<dim3(4, Bn * 8), blk, 0, stream>>>(xt, t_off_w, om_t, HT, WT);
  offconv_gemm_kernel<2><<<dim3(16, Bn * 2), blk, 0, stream>>>(xs, s_off_w, om_s, HS, WS2);

  // DCN prep
  dcnw_prep_kernel<<<dim3((256 * 2304 + 255) / 256), blk, 0, stream>>>(t_dcn_w, Awb_t);
  dcnw_prep_kernel<<<dim3((256 * 2304 + 255) / 256), blk, 0, stream>>>(s_dcn_w, Awb_s);
  prep_offsets_kernel<<<dim3((Bn * 9 * NT + 255) / 256), blk, 0, stream>>>(om_t, prep_t, Bn, HT, WT);
  prep_offsets_kernel<<<dim3((Bn * 9 * NS + 255) / 256), blk, 0, stream>>>(om_s, prep_s, Bn, HS, WS2);

  float* out_t = (float*)d_out;
  float* out_s = out_t + (size_t)Bn * C * NT;
  dcn_mfma_kernel<4, 4><<<dim3(4, 4, Bn), dim3(256), 0, stream>>>(xt, prep_t, Awb_t, t_dcn_b, out_t, NT);
  dcn_mfma_kernel<1, 8><<<dim3(16, 1, Bn), dim3(512), 0, stream>>>(xs, prep_s, Awb_s, s_dcn_b, out_s, NS);
}

// Round 7
// 695.821 us; speedup vs baseline: 2.4644x; 1.4027x over previous
//
#include <hip/hip_runtime.h>
#include <hip/hip_bf16.h>
#include <cmath>

typedef __attribute__((ext_vector_type(8))) short bf16x8;
typedef __attribute__((ext_vector_type(4))) float f32x4;

__device__ inline ushort f2bf(float f) {
  __hip_bfloat16 h = __float2bfloat16(f);
  return *reinterpret_cast<ushort*>(&h);
}
__device__ inline float bf2f(ushort u) {
  return __uint_as_float((uint)u << 16);
}

// XCD-aware bijective remap (requires grid total % 8 == 0)
__device__ inline void xcd_remap(int& bx, int& by, int& bz) {
  const int gx = gridDim.x, gy = gridDim.y, gz = gridDim.z;
  const int total = gx * gy * gz;
  int id = blockIdx.x + gx * (blockIdx.y + gy * blockIdx.z);
  int wid = (id & 7) * (total >> 3) + (id >> 3);
  bx = wid % gx;
  wid /= gx;
  by = wid % gy;
  bz = wid / gy;
}

// ---------------------------------------------------------------------------
// conv1x1 (fp32): merged q|k projection (OC=64)
// ---------------------------------------------------------------------------
__global__ __launch_bounds__(256) void conv1x1_kernel(
    const float* __restrict__ x, const float* __restrict__ w,
    const float* __restrict__ bias, float* __restrict__ out,
    int C, int N, int OC) {
  __shared__ float As[64][17];
  __shared__ float Bs[16][64];
  const int b = blockIdx.z;
  const int m0 = blockIdx.y * 64, n0 = blockIdx.x * 64;
  const float* xb = x + (size_t)b * C * N;
  const int tid = threadIdx.x;
  const int tr = tid >> 4, tc = tid & 15;
  float acc[4][4] = {};
  for (int k0 = 0; k0 < C; k0 += 16) {
    for (int i = tid; i < 64 * 16; i += 256) {
      int m = i >> 4, kk = i & 15;
      int gm = m0 + m;
      As[m][kk] = (gm < OC) ? w[(size_t)gm * C + k0 + kk] : 0.f;
    }
    for (int i = tid; i < 16 * 64; i += 256) {
      int kk = i >> 6, n = i & 63;
      int gn = n0 + n;
      Bs[kk][n] = (gn < N) ? xb[(size_t)(k0 + kk) * N + gn] : 0.f;
    }
    __syncthreads();
#pragma unroll
    for (int kk = 0; kk < 16; ++kk) {
      float a[4], bb[4];
#pragma unroll
      for (int i = 0; i < 4; i++) a[i] = As[tr * 4 + i][kk];
#pragma unroll
      for (int j = 0; j < 4; j++) bb[j] = Bs[kk][tc * 4 + j];
#pragma unroll
      for (int i = 0; i < 4; i++)
#pragma unroll
        for (int j = 0; j < 4; j++) acc[i][j] += a[i] * bb[j];
    }
    __syncthreads();
  }
  for (int i = 0; i < 4; i++) {
    int gm = m0 + tr * 4 + i;
    if (gm >= OC) continue;
    float bv = bias[gm];
    for (int j = 0; j < 4; j++) {
      int gn = n0 + tc * 4 + j;
      if (gn < N) out[((size_t)b * OC + gm) * N + gn] = acc[i][j] + bv;
    }
  }
}

// ---------------------------------------------------------------------------
// concat q,k weights/biases -> [64][C] / [64]
// ---------------------------------------------------------------------------
__global__ __launch_bounds__(256) void qkcat_kernel(
    const float* __restrict__ qw, const float* __restrict__ qb,
    const float* __restrict__ kw, const float* __restrict__ kb,
    float* __restrict__ w, float* __restrict__ b, int C) {
  const int i = blockIdx.x * 256 + threadIdx.x;
  if (i < 32 * C) w[i] = qw[i];
  else if (i < 64 * C) w[i] = kw[i - 32 * C];
  if (i < 32) b[i] = qb[i];
  else if (i < 64) b[i] = kb[i - 32];
}

// ---------------------------------------------------------------------------
// cast+transpose: x fp32 [C][N] -> xT bf16 [NR][C] (rows >= N zeroed)
// ---------------------------------------------------------------------------
__global__ __launch_bounds__(256) void cast_transpose_kernel(
    const float* __restrict__ x, ushort* __restrict__ xT, int C, int N,
    int NR) {
  __shared__ float T[64][65];
  const int b = blockIdx.z;
  const int n0 = blockIdx.x * 64, c0 = blockIdx.y * 64;
  const float* xb = x + (size_t)b * C * N;
  const int tid = threadIdx.x;
  for (int u = tid; u < 4096; u += 256) {
    const int cc = u >> 6, nn = u & 63;
    const int gn = n0 + nn;
    T[cc][nn] = (gn < N) ? xb[(size_t)(c0 + cc) * N + gn] : 0.f;
  }
  __syncthreads();
  ushort* ob = xT + (size_t)b * NR * C;
  for (int u = tid; u < 4096; u += 256) {
    const int nn = u >> 6, cc = u & 63;
    ob[(size_t)(n0 + nn) * C + c0 + cc] = f2bf(T[cc][nn]);
  }
}

// ---------------------------------------------------------------------------
// elementwise fp32 -> bf16 cast (weights)
// ---------------------------------------------------------------------------
__global__ __launch_bounds__(256) void castw_kernel(
    const float* __restrict__ W, ushort* __restrict__ out, int total) {
  const int i = blockIdx.x * 256 + threadIdx.x;
  if (i < total) out[i] = f2bf(W[i]);
}

// ---------------------------------------------------------------------------
// cast with col pad: x fp32 [B][C][N] -> xbf bf16 [B][C][Np] (pads zero)
// ---------------------------------------------------------------------------
__global__ __launch_bounds__(256) void cast_pad_kernel(
    const float* __restrict__ x, ushort* __restrict__ xbf, int C, int N,
    int Np, int total) {
  const int i = blockIdx.x * 256 + threadIdx.x;
  if (i >= total) return;
  const int np = i % Np;
  const int c = (i / Np) % C;
  const int b = i / (Np * C);
  xbf[i] = (np < N) ? f2bf(x[((size_t)b * C + c) * N + np]) : (ushort)0;
}

// ---------------------------------------------------------------------------
// Mcomb = bf16(w1*Aown + w2*Aoth)
// ---------------------------------------------------------------------------
__global__ __launch_bounds__(256) void mcomb_kernel(
    const float* __restrict__ Ao, const float* __restrict__ Ax,
    const float* __restrict__ w1p, const float* __restrict__ w2p,
    ushort* __restrict__ out, int total) {
  const int i = blockIdx.x * 256 + threadIdx.x;
  if (i < total) out[i] = f2bf((*w1p) * Ao[i] + (*w2p) * Ax[i]);
}

// ---------------------------------------------------------------------------
// generic bf16 GEMM: out[m][n] = sum_k A[m][k] * Bt[n][k], M=256.
// EPI 0: outBf[b][m][Np] = bf16(acc+bias[m]) (cols>=N zeroed)  [conv1x1-v]
// EPI 1: outF[b][m][N] += acc; xsT[b][n][m] = bf16(sum)        [chan_use]
// EPI 2: outF[b][m][N] = acc                                   [gram]
// grid (gx, MS, B), block NW*64. XCD-swizzled.
// ---------------------------------------------------------------------------
template <int MS, int NW, int EPI>
__global__ __launch_bounds__(NW * 64) void gemm_abf_kernel(
    const ushort* __restrict__ A, int aPerBatch,
    const ushort* __restrict__ Bt, const float* __restrict__ bias,
    ushort* __restrict__ outBf, float* __restrict__ outF,
    ushort* __restrict__ xsT, int N, int Np, int NR, int Kp) {
  constexpr int CM = 256;
  constexpr int BM = CM / MS;
  constexpr int WM = BM / 64;
  constexpr int WN = NW / WM;
  constexpr int NF = 4 / WN;
  __shared__ ushort Asm[BM][40];
  __shared__ ushort Bsm[64][40];
  int bx, by, bz;
  xcd_remap(bx, by, bz);
  const int n0 = bx * 64, m0 = by * BM, b = bz;
  const ushort* Ab = A + (size_t)(aPerBatch ? b : 0) * CM * Kp;
  const ushort* Bb = Bt + (size_t)b * NR * Kp;
  const int tid = threadIdx.x, lane = tid & 63, w = tid >> 6;
  const int wr = w / WN, wc = w % WN;
  f32x4 acc[4][NF];
#pragma unroll
  for (int i = 0; i < 4; i++)
#pragma unroll
    for (int j = 0; j < NF; j++) acc[i][j] = (f32x4){0.f, 0.f, 0.f, 0.f};
  for (int k0 = 0; k0 < Kp; k0 += 32) {
    for (int u = tid; u < BM * 4; u += NW * 64) {
      const int row = u >> 2, seg = u & 3;
      *reinterpret_cast<uint4*>(&Asm[row][seg * 8]) =
          *reinterpret_cast<const uint4*>(&Ab[(size_t)(m0 + row) * Kp + k0 + seg * 8]);
    }
    for (int u = tid; u < 64 * 4; u += NW * 64) {
      const int row = u >> 2, seg = u & 3;
      *reinterpret_cast<uint4*>(&Bsm[row][seg * 8]) =
          *reinterpret_cast<const uint4*>(&Bb[(size_t)(n0 + row) * Kp + k0 + seg * 8]);
    }
    __syncthreads();
    const int koff = (lane >> 4) * 8;
    bf16x8 af[4], bfr[NF];
#pragma unroll
    for (int mf = 0; mf < 4; mf++)
      af[mf] = *reinterpret_cast<const bf16x8*>(&Asm[wr * 64 + mf * 16 + (lane & 15)][koff]);
#pragma unroll
    for (int nf = 0; nf < NF; nf++)
      bfr[nf] = *reinterpret_cast<const bf16x8*>(&Bsm[wc * NF * 16 + nf * 16 + (lane & 15)][koff]);
#pragma unroll
    for (int mf = 0; mf < 4; mf++)
#pragma unroll
      for (int nf = 0; nf < NF; nf++)
        acc[mf][nf] = __builtin_amdgcn_mfma_f32_16x16x32_bf16(af[mf], bfr[nf], acc[mf][nf], 0, 0, 0);
    __syncthreads();
  }
#pragma unroll
  for (int mf = 0; mf < 4; mf++) {
    const int mbase = m0 + wr * 64 + mf * 16 + ((lane >> 4) * 4);
#pragma unroll
    for (int nf = 0; nf < NF; nf++) {
      const int gn = n0 + wc * NF * 16 + nf * 16 + (lane & 15);
      if (EPI == 0) {
#pragma unroll
        for (int rr = 0; rr < 4; rr++) {
          const int m = mbase + rr;
          if (gn < Np) {
            ushort v = (gn < N) ? f2bf(acc[mf][nf][rr] + bias[m]) : (ushort)0;
            outBf[((size_t)b * CM + m) * Np + gn] = v;
          }
        }
      } else if (EPI == 1) {
        if (gn < N) {
          float s[4];
#pragma unroll
          for (int rr = 0; rr < 4; rr++) {
            const size_t idx = ((size_t)b * CM + mbase + rr) * N + gn;
            s[rr] = outF[idx] + acc[mf][nf][rr];
            outF[idx] = s[rr];
          }
          uint lo = (uint)f2bf(s[0]) | ((uint)f2bf(s[1]) << 16);
          uint hi = (uint)f2bf(s[2]) | ((uint)f2bf(s[3]) << 16);
          *reinterpret_cast<uint2*>(&xsT[((size_t)b * NR + gn) * CM + mbase]) =
              make_uint2(lo, hi);
        }
      } else {
#pragma unroll
        for (int rr = 0; rr < 4; rr++) {
          if (gn < N)
            outF[((size_t)b * CM + mbase + rr) * N + gn] = acc[mf][nf][rr];
        }
      }
    }
  }
}

// ---------------------------------------------------------------------------
// energy via MFMA (K=32): S[b][n][m] = sum_q q[q][n]*k[q][m] -> bf16, padded
// grid (ceil(Np/64) [m], ceil(N/64) [n], B), 4 waves. XCD-swizzled.
// ---------------------------------------------------------------------------
__global__ __launch_bounds__(256) void energy_mfma_kernel(
    const float* __restrict__ qg, const float* __restrict__ kg,
    ushort* __restrict__ Sbf, int N, int Np, int bstride) {
  __shared__ ushort Aq[64][40];
  __shared__ ushort Bk[64][40];
  int bx, by, bz;
  xcd_remap(bx, by, bz);
  const int m0 = bx * 64, n0 = by * 64, b = bz;
  const float* qb = qg + (size_t)b * bstride;
  const float* kb = kg + (size_t)b * bstride;
  const int tid = threadIdx.x, lane = tid & 63, w = tid >> 6;
  for (int u = tid; u < 2048; u += 256) {
    const int c = u >> 6, nn = u & 63;
    const int gn = n0 + nn, gm = m0 + nn;
    Aq[nn][c] = (gn < N) ? f2bf(qb[(size_t)c * N + gn]) : (ushort)0;
    Bk[nn][c] = (gm < N) ? f2bf(kb[(size_t)c * N + gm]) : (ushort)0;
  }
  __syncthreads();
  const int koff = (lane >> 4) * 8;
  const bf16x8 af = *reinterpret_cast<const bf16x8*>(&Aq[w * 16 + (lane & 15)][koff]);
  f32x4 acc[4];
#pragma unroll
  for (int j = 0; j < 4; j++) {
    const bf16x8 bf = *reinterpret_cast<const bf16x8*>(&Bk[j * 16 + (lane & 15)][koff]);
    acc[j] = __builtin_amdgcn_mfma_f32_16x16x32_bf16(af, bf, (f32x4){0.f, 0.f, 0.f, 0.f}, 0, 0, 0);
  }
#pragma unroll
  for (int j = 0; j < 4; j++) {
    const int m = m0 + j * 16 + (lane & 15);
    if (m >= Np) continue;
#pragma unroll
    for (int r = 0; r < 4; r++) {
      const int n = n0 + w * 16 + (lane >> 4) * 4 + r;
      if (n < N) Sbf[((size_t)b * N + n) * Np + m] = (m < N) ? f2bf(acc[j][r]) : (ushort)0;
    }
  }
}

// ---------------------------------------------------------------------------
// fp32 in-place row softmax of sign*r (channel attention)
// ---------------------------------------------------------------------------
__global__ __launch_bounds__(256) void softmax_rows_kernel(
    float* __restrict__ e, int N, float sign) {
  const size_t row = blockIdx.x;
  float* r = e + row * (size_t)N;
  const int tid = threadIdx.x;
  __shared__ float red[4];
  float mx = -1e30f;
  for (int i = tid; i < N; i += 256) mx = fmaxf(mx, sign * r[i]);
#pragma unroll
  for (int off = 32; off; off >>= 1) mx = fmaxf(mx, __shfl_xor(mx, off, 64));
  if ((tid & 63) == 0) red[tid >> 6] = mx;
  __syncthreads();
  if (tid == 0) {
    float m2 = red[0];
    for (int i = 1; i < 4; i++) m2 = fmaxf(m2, red[i]);
    red[0] = m2;
  }
  __syncthreads();
  mx = red[0];
  __syncthreads();
  float s = 0.f;
  for (int i = tid; i < N; i += 256) {
    float v = __expf(sign * r[i] - mx);
    r[i] = v;
    s += v;
  }
#pragma unroll
  for (int off = 32; off; off >>= 1) s += __shfl_xor(s, off, 64);
  if ((tid & 63) == 0) red[tid >> 6] = s;
  __syncthreads();
  if (tid == 0) {
    float t = 0.f;
    for (int i = 0; i < 4; i++) t += red[i];
    red[0] = t;
  }
  __syncthreads();
  const float inv = 1.f / red[0];
  for (int i = tid; i < N; i += 256) r[i] *= inv;
}

// ---------------------------------------------------------------------------
// bf16 in-place row softmax (spatial attention scores)
// ---------------------------------------------------------------------------
__global__ __launch_bounds__(256) void softmax_bf16_kernel(
    ushort* __restrict__ Sbf, int N, int Np) {
  __shared__ float buf[992];
  __shared__ float red[4];
  const size_t row = blockIdx.x;
  ushort* r = Sbf + row * (size_t)Np;
  const int tid = threadIdx.x;
  float mx = -1e30f;
  for (int i = tid; i < N; i += 256) {
    float f = bf2f(r[i]);
    buf[i] = f;
    mx = fmaxf(mx, f);
  }
#pragma unroll
  for (int off = 32; off; off >>= 1) mx = fmaxf(mx, __shfl_xor(mx, off, 64));
  if ((tid & 63) == 0) red[tid >> 6] = mx;
  __syncthreads();
  if (tid == 0) {
    float m2 = red[0];
    for (int i = 1; i < 4; i++) m2 = fmaxf(m2, red[i]);
    red[0] = m2;
  }
  __syncthreads();
  mx = red[0];
  __syncthreads();
  float s = 0.f;
  for (int i = tid; i < N; i += 256) {
    float v = __expf(buf[i] - mx);
    buf[i] = v;
    s += v;
  }
#pragma unroll
  for (int off = 32; off; off >>= 1) s += __shfl_xor(s, off, 64);
  if ((tid & 63) == 0) red[tid >> 6] = s;
  __syncthreads();
  if (tid == 0) {
    float t = 0.f;
    for (int i = 0; i < 4; i++) t += red[i];
    red[0] = t;
  }
  __syncthreads();
  const float inv = 1.f / red[0];
  for (int i = tid; i < N; i += 256) r[i] = f2bf(buf[i] * inv);
}

// ---------------------------------------------------------------------------
// PV via MFMA: xsum = x + g * v @ A^T, XCD-swizzled
// ---------------------------------------------------------------------------
template <int MS, int NW>
__global__ __launch_bounds__(NW * 64) void pv_mfma_kernel(
    const ushort* __restrict__ vbf, const ushort* __restrict__ Abf,
    const float* __restrict__ x, const float* __restrict__ gp,
    float* __restrict__ xsum, int N, int Np) {
  constexpr int C = 256;
  constexpr int BM = C / MS;
  constexpr int WM = BM / 64;
  constexpr int WN = NW / WM;
  constexpr int NF = 4 / WN;
  __shared__ ushort Asm[BM][40];
  __shared__ ushort Bsm[64][40];
  int bx, by, bz;
  xcd_remap(bx, by, bz);
  const int n0 = bx * 64, m0 = by * BM, b = bz;
  const int tid = threadIdx.x, lane = tid & 63, w = tid >> 6;
  const int wr = w / WN, wc = w % WN;
  const ushort* vb = vbf + (size_t)b * C * Np;
  const ushort* Ab = Abf + (size_t)b * (size_t)N * Np;
  f32x4 acc[4][NF];
#pragma unroll
  for (int i = 0; i < 4; i++)
#pragma unroll
    for (int j = 0; j < NF; j++) acc[i][j] = (f32x4){0.f, 0.f, 0.f, 0.f};
  for (int k0 = 0; k0 < Np; k0 += 32) {
    for (int u = tid; u < BM * 4; u += NW * 64) {
      const int row = u >> 2, seg = u & 3;
      *reinterpret_cast<uint4*>(&Asm[row][seg * 8]) =
          *reinterpret_cast<const uint4*>(&vb[(size_t)(m0 + row) * Np + k0 + seg * 8]);
    }
    for (int u = tid; u < 64 * 4; u += NW * 64) {
      const int row = u >> 2, seg = u & 3;
      const int gn = n0 + row;
      uint4 val;
      if (gn < N)
        val = *reinterpret_cast<const uint4*>(&Ab[(size_t)gn * Np + k0 + seg * 8]);
      else
        val = make_uint4(0, 0, 0, 0);
      *reinterpret_cast<uint4*>(&Bsm[row][seg * 8]) = val;
    }
    __syncthreads();
    const int koff = (lane >> 4) * 8;
    bf16x8 af[4], bfr[NF];
#pragma unroll
    for (int mf = 0; mf < 4; mf++)
      af[mf] = *reinterpret_cast<const bf16x8*>(&Asm[wr * 64 + mf * 16 + (lane & 15)][koff]);
#pragma unroll
    for (int nf = 0; nf < NF; nf++)
      bfr[nf] = *reinterpret_cast<const bf16x8*>(&Bsm[wc * NF * 16 + nf * 16 + (lane & 15)][koff]);
#pragma unroll
    for (int mf = 0; mf < 4; mf++)
#pragma unroll
      for (int nf = 0; nf < NF; nf++)
        acc[mf][nf] = __builtin_amdgcn_mfma_f32_16x16x32_bf16(af[mf], bfr[nf], acc[mf][nf], 0, 0, 0);
    __syncthreads();
  }
  const float g = *gp;
#pragma unroll
  for (int mf = 0; mf < 4; mf++) {
    const int mbase = m0 + wr * 64 + mf * 16 + ((lane >> 4) * 4);
#pragma unroll
    for (int nf = 0; nf < NF; nf++) {
      const int gn = n0 + wc * NF * 16 + nf * 16 + (lane & 15);
      if (gn < N) {
#pragma unroll
        for (int rr = 0; rr < 4; rr++) {
          const size_t idx = ((size_t)b * C + mbase + rr) * N + gn;
          xsum[idx] = x[idx] + g * acc[mf][nf][rr];
        }
      }
    }
  }
}

// ---------------------------------------------------------------------------
// offconv weight reorder: ow[27][C][9] -> owb[32][tap*256+c] bf16 (rows>=27 = 0)
// ---------------------------------------------------------------------------
__global__ __launch_bounds__(256) void offw_prep_kernel(
    const float* __restrict__ ow, ushort* __restrict__ owb) {
  const int i = blockIdx.x * 256 + threadIdx.x;
  if (i >= 32 * 2304) return;
  const int o = i / 2304, k = i % 2304;
  const int tap = k >> 8, c = k & 255;
  owb[i] = (o < 27) ? f2bf(ow[(size_t)o * 2304 + c * 9 + tap]) : (ushort)0;
}

// ---------------------------------------------------------------------------
// offconv via MFMA: om[b][o][p] = ob[o] + sum_{tap,c} owb[o][tap*256+c]
//                                  * xsT[b][p+shift(tap)][c]  (masked)
// grid (ceil(N/64), 1, B), 4 waves. XCD-swizzled.
// FIX r7: stage the FULL 64-element K-tile (seg = 0..7), not half of it.
// ---------------------------------------------------------------------------
__global__ __launch_bounds__(256) void offconv_mfma_kernel(
    const ushort* __restrict__ xsT, const ushort* __restrict__ owb,
    const float* __restrict__ ob, float* __restrict__ om,
    int H, int Wd, int N, int NR) {
  __shared__ ushort Asm[32][72];
  __shared__ ushort Bsm[64][72];
  __shared__ int qsrc[64];
  int bx, by, bz;
  xcd_remap(bx, by, bz);
  const int n0 = bx * 64, b = bz;
  const int tid = threadIdx.x, lane = tid & 63, w = tid >> 6;
  const ushort* xb = xsT + (size_t)b * NR * 256;
  f32x4 acc[2];
  acc[0] = (f32x4){0.f, 0.f, 0.f, 0.f};
  acc[1] = (f32x4){0.f, 0.f, 0.f, 0.f};
  for (int tap = 0; tap < 9; ++tap) {
    const int dy = tap / 3 - 1, dx = tap - (tap / 3) * 3 - 1;
    if (tid < 64) {
      const int p = n0 + tid;
      int q = -1;
      if (p < N) {
        const int h = p / Wd, ww = p - (p / Wd) * Wd;
        const int yy = h + dy, xx = ww + dx;
        if (yy >= 0 && yy < H && xx >= 0 && xx < Wd) q = yy * Wd + xx;
      }
      qsrc[tid] = q;
    }
    __syncthreads();
    for (int ks = 0; ks < 4; ++ks) {
      const int k0 = tap * 256 + ks * 64;
      {
        // A: 32 rows x 8 segs of 8 bf16 = full 64-wide tile (256 uint4s)
        const int row = tid >> 3, seg = tid & 7;
        *reinterpret_cast<uint4*>(&Asm[row][seg * 8]) =
            *reinterpret_cast<const uint4*>(&owb[(size_t)row * 2304 + k0 + seg * 8]);
      }
      // B: 64 rows x 8 segs (512 uint4s, 2 per thread)
      for (int u = tid; u < 512; u += 256) {
        const int row = u >> 3, seg = u & 7;
        const int q = qsrc[row];
        uint4 val = make_uint4(0, 0, 0, 0);
        if (q >= 0)
          val = *reinterpret_cast<const uint4*>(&xb[(size_t)q * 256 + ks * 64 + seg * 8]);
        *reinterpret_cast<uint4*>(&Bsm[row][seg * 8]) = val;
      }
      __syncthreads();
#pragma unroll
      for (int sub = 0; sub < 2; ++sub) {
        const int koff = sub * 32 + (lane >> 4) * 8;
        const bf16x8 b0 = *reinterpret_cast<const bf16x8*>(&Bsm[w * 16 + (lane & 15)][koff]);
#pragma unroll
        for (int mf = 0; mf < 2; ++mf) {
          const bf16x8 a0 = *reinterpret_cast<const bf16x8*>(&Asm[mf * 16 + (lane & 15)][koff]);
          acc[mf] = __builtin_amdgcn_mfma_f32_16x16x32_bf16(a0, b0, acc[mf], 0, 0, 0);
        }
      }
      __syncthreads();
    }
  }
#pragma unroll
  for (int mf = 0; mf < 2; ++mf) {
#pragma unroll
    for (int r = 0; r < 4; ++r) {
      const int o = mf * 16 + (lane >> 4) * 4 + r;
      const int n = n0 + w * 16 + (lane & 15);
      if (o < 27 && n < N)
        om[((size_t)b * 27 + o) * N + n] = acc[mf][r] + ob[o];
    }
  }
}

// ---------------------------------------------------------------------------
// reorder+convert DCN weights (O,C,3,3) fp32 -> Awb[o][k=tap*256+c] bf16
// ---------------------------------------------------------------------------
__global__ __launch_bounds__(256) void dcnw_prep_kernel(
    const float* __restrict__ W, ushort* __restrict__ Awb) {
  const int i = blockIdx.x * 256 + threadIdx.x;
  if (i >= 256 * 2304) return;
  const int o = i / 2304, k = i % 2304;
  const int tap = k >> 8, c = k & 255;
  Awb[i] = f2bf(W[(size_t)o * 2304 + c * 9 + tap]);
}

// ---------------------------------------------------------------------------
// packed bilinear gather table: uint4 = {short4 idx, 4x bf16 weight}
// ---------------------------------------------------------------------------
__global__ __launch_bounds__(256) void prep_offsets_kernel(
    const float* __restrict__ om, uint4* __restrict__ prep, int B, int H,
    int Wd) {
  const int N = H * Wd;
  const int i = blockIdx.x * 256 + threadIdx.x;
  if (i >= B * 9 * N) return;
  const int p = i % N;
  const int k = (i / N) % 9;
  const int b = i / (9 * N);
  const float* omb = om + (size_t)b * 27 * N;
  const float offy = omb[(size_t)k * N + p];
  const float offx = omb[(size_t)(9 + k) * N + p];
  const float mraw = omb[(size_t)(18 + k) * N + p];
  const float mval = 1.f / (1.f + __expf(-mraw));
  const int ky = k / 3, kx = k - (k / 3) * 3;
  const int h = p / Wd, w = p - (p / Wd) * Wd;
  const float py = offy + (float)(h + ky - 1);
  const float px = offx + (float)(w + kx - 1);
  const float y0f = floorf(py), x0f = floorf(px);
  const float wy = py - y0f, wx = px - x0f;
  const int y0 = (int)y0f, x0 = (int)x0f;
  int idxs[4];
  float wts[4];
  const int ys[2] = {y0, y0 + 1};
  const int xs2[2] = {x0, x0 + 1};
  const float wyv[2] = {1.f - wy, wy};
  const float wxv[2] = {1.f - wx, wx};
#pragma unroll
  for (int a = 0; a < 2; a++)
#pragma unroll
    for (int bb = 0; bb < 2; bb++) {
      const int yi = ys[a], xi = xs2[bb];
      const bool valid = (yi >= 0) && (yi < H) && (xi >= 0) && (xi < Wd);
      const int yc = min(max(yi, 0), H - 1);
      const int xc = min(max(xi, 0), Wd - 1);
      idxs[a * 2 + bb] = yc * Wd + xc;
      wts[a * 2 + bb] = valid ? wyv[a] * wxv[bb] * mval : 0.f;
    }
  uint4 pk;
  pk.x = (uint)(ushort)idxs[0] | ((uint)(ushort)idxs[1] << 16);
  pk.y = (uint)(ushort)idxs[2] | ((uint)(ushort)idxs[3] << 16);
  pk.z = (uint)f2bf(wts[0]) | ((uint)f2bf(wts[1]) << 16);
  pk.w = (uint)f2bf(wts[2]) | ((uint)f2bf(wts[3]) << 16);
  prep[i] = pk;
}

// ---------------------------------------------------------------------------
// DCN via MFMA with fused gather, XCD-swizzled, packed prep table.
// ---------------------------------------------------------------------------
template <int MS, int NW>
__global__ __launch_bounds__(NW * 64) void dcn_mfma_kernel(
    const float* __restrict__ xsum, const uint4* __restrict__ prep,
    const ushort* __restrict__ Awb, const float* __restrict__ bias,
    float* __restrict__ out, int N) {
  constexpr int C = 256, KTOT = 2304;
  constexpr int BM = C / MS;
  constexpr int WM = BM / 64;
  constexpr int WN = NW / WM;
  constexpr int NF = 4 / WN;
  __shared__ ushort Asm[BM][40];
  __shared__ ushort Bsm[64][40];
  __shared__ int si[4][64];
  __shared__ float sw[4][64];
  int bx, by, bz;
  xcd_remap(bx, by, bz);
  const int n0 = bx * 64, m0 = by * BM, b = bz;
  const int tid = threadIdx.x, lane = tid & 63, w = tid >> 6;
  const int wr = w / WN, wc = w % WN;
  const float* xb = xsum + (size_t)b * C * N;
  f32x4 acc[4][NF];
#pragma unroll
  for (int i = 0; i < 4; i++)
#pragma unroll
    for (int j = 0; j < NF; j++) acc[i][j] = (f32x4){0.f, 0.f, 0.f, 0.f};
  for (int k0 = 0; k0 < KTOT; k0 += 32) {
    const int kpos = k0 >> 8, c0 = k0 & 255;
    if (c0 == 0) {
      if (tid < 64) {
        const int p = n0 + tid;
        if (p < N) {
          const uint4 pk = prep[((size_t)b * 9 + kpos) * N + p];
          si[0][tid] = (int)(pk.x & 0xffff);
          si[1][tid] = (int)(pk.x >> 16);
          si[2][tid] = (int)(pk.y & 0xffff);
          si[3][tid] = (int)(pk.y >> 16);
          sw[0][tid] = bf2f((ushort)(pk.z & 0xffff));
          sw[1][tid] = bf2f((ushort)(pk.z >> 16));
          sw[2][tid] = bf2f((ushort)(pk.w & 0xffff));
          sw[3][tid] = bf2f((ushort)(pk.w >> 16));
        } else {
          si[0][tid] = si[1][tid] = si[2][tid] = si[3][tid] = 0;
          sw[0][tid] = sw[1][tid] = sw[2][tid] = sw[3][tid] = 0.f;
        }
      }
      __syncthreads();
    }
    for (int u = tid; u < BM * 4; u += NW * 64) {
      const int row = u >> 2, seg = u & 3;
      *reinterpret_cast<uint4*>(&Asm[row][seg * 8]) =
          *reinterpret_cast<const uint4*>(&Awb[(size_t)(m0 + row) * KTOT + k0 + seg * 8]);
    }
    for (int u = tid; u < 64 * 16; u += NW * 64) {
      const int n = u & 63, pr = u >> 6;
      const int kk = pr * 2;
      const float* r0 = xb + (size_t)(c0 + kk) * N;
      const float* r1 = r0 + N;
      const int i0 = si[0][n], i1 = si[1][n], i2 = si[2][n], i3 = si[3][n];
      const float w0 = sw[0][n], w1 = sw[1][n], w2 = sw[2][n], w3 = sw[3][n];
      const float v0 = w0 * r0[i0] + w1 * r0[i1] + w2 * r0[i2] + w3 * r0[i3];
      const float v1 = w0 * r1[i0] + w1 * r1[i1] + w2 * r1[i2] + w3 * r1[i3];
      *reinterpret_cast<uint*>(&Bsm[n][kk]) =
          (uint)f2bf(v0) | ((uint)f2bf(v1) << 16);
    }
    __syncthreads();
    const int koff = (lane >> 4) * 8;
    bf16x8 af[4], bfr[NF];
#pragma unroll
    for (int mf = 0; mf < 4; mf++)
      af[mf] = *reinterpret_cast<const bf16x8*>(&Asm[wr * 64 + mf * 16 + (lane & 15)][koff]);
#pragma unroll
    for (int nf = 0; nf < NF; nf++)
      bfr[nf] = *reinterpret_cast<const bf16x8*>(&Bsm[wc * NF * 16 + nf * 16 + (lane & 15)][koff]);
#pragma unroll
    for (int mf = 0; mf < 4; mf++)
#pragma unroll
      for (int nf = 0; nf < NF; nf++)
        acc[mf][nf] = __builtin_amdgcn_mfma_f32_16x16x32_bf16(af[mf], bfr[nf], acc[mf][nf], 0, 0, 0);
    __syncthreads();
  }
#pragma unroll
  for (int mf = 0; mf < 4; mf++) {
    const int mbase = m0 + wr * 64 + mf * 16 + ((lane >> 4) * 4);
#pragma unroll
    for (int nf = 0; nf < NF; nf++) {
      const int gn = n0 + wc * NF * 16 + nf * 16 + (lane & 15);
      if (gn < N) {
#pragma unroll
        for (int rr = 0; rr < 4; rr++)
          out[((size_t)b * C + mbase + rr) * N + gn] = acc[mf][nf][rr] + bias[mbase + rr];
      }
    }
  }
}

// ---------------------------------------------------------------------------
extern "C" void kernel_launch(void* const* d_in, const int* in_sizes, int n_in,
                              void* d_out, int out_size, void* d_ws, size_t ws_size,
                              hipStream_t stream) {
  const float* t_in = (const float*)d_in[0];
  const float* s_in = (const float*)d_in[1];
  const float* t_qw = (const float*)d_in[2];
  const float* t_qb = (const float*)d_in[3];
  const float* t_kw = (const float*)d_in[4];
  const float* t_kb = (const float*)d_in[5];
  const float* t_vw = (const float*)d_in[6];
  const float* t_vb = (const float*)d_in[7];
  const float* t_g = (const float*)d_in[8];
  const float* s_qw = (const float*)d_in[9];
  const float* s_qb = (const float*)d_in[10];
  const float* s_kw = (const float*)d_in[11];
  const float* s_kb = (const float*)d_in[12];
  const float* s_vw = (const float*)d_in[13];
  const float* s_vb = (const float*)d_in[14];
  const float* s_g = (const float*)d_in[15];
  const float* w_t_ch = (const float*)d_in[16];
  const float* w_s_ch = (const float*)d_in[17];
  const float* w_s2t = (const float*)d_in[18];
  const float* w_t2s = (const float*)d_in[19];
  const float* t_off_w = (const float*)d_in[20];
  const float* t_off_b = (const float*)d_in[21];
  const float* t_dcn_w = (const float*)d_in[22];
  const float* t_dcn_b = (const float*)d_in[23];
  const float* s_off_w = (const float*)d_in[24];
  const float* s_off_b = (const float*)d_in[25];
  const float* s_dcn_w = (const float*)d_in[26];
  const float* s_dcn_b = (const float*)d_in[27];
  (void)in_sizes; (void)n_in; (void)out_size; (void)ws_size;

  constexpr int Bn = 16, C = 256, QKd = 32;
  constexpr int HT = 15, WT = 15, NT = HT * WT;    // 225
  constexpr int HS = 31, WS2 = 31, NS = HS * WS2;  // 961
  constexpr int NpT = 256, NpS = 992;              // col pads (mult of 32)
  constexpr int NRT = 256, NRS = 1024;             // row pads (mult of 64)

  float* ws = (float*)d_ws;
  size_t off = 0;
  auto alloc = [&](size_t n) {
    n = (n + 3) & ~(size_t)3;
    float* p = ws + off; off += n; return p;
  };
  auto allocU = [&](size_t nu) { return (ushort*)alloc((nu + 1) / 2); };

  float* qk_t = alloc((size_t)Bn * 64 * NT);
  float* qk_s = alloc((size_t)Bn * 64 * NS);
  float* qkw_t = alloc((size_t)64 * C + 64);
  float* qkw_s = alloc((size_t)64 * C + 64);
  float* qkb_t = qkw_t + (size_t)64 * C;
  float* qkb_s = qkw_s + (size_t)64 * C;
  ushort* xT_t = allocU((size_t)Bn * NRT * C);
  ushort* xT_s = allocU((size_t)Bn * NRS * C);
  ushort* xbf_t = allocU((size_t)Bn * C * NpT);
  ushort* xbf_s = allocU((size_t)Bn * C * NpS);
  ushort* Wv_t = allocU((size_t)C * C);
  ushort* Wv_s = allocU((size_t)C * C);
  ushort* v_tbf = allocU((size_t)Bn * C * NpT);
  ushort* v_sbf = allocU((size_t)Bn * C * NpS);
  ushort* S_t = allocU((size_t)Bn * NT * NpT);
  ushort* S_s = allocU((size_t)Bn * NS * NpS);
  float* xt = alloc((size_t)Bn * C * NT);
  float* xs = alloc((size_t)Bn * C * NS);
  ushort* xsT_t = allocU((size_t)Bn * NRT * C);
  ushort* xsT_s = allocU((size_t)Bn * NRS * C);
  float* Atc = alloc((size_t)Bn * C * C);
  float* Asc = alloc((size_t)Bn * C * C);
  ushort* Mc_t = allocU((size_t)Bn * C * C);
  ushort* Mc_s = allocU((size_t)Bn * C * C);
  float* om_t = alloc((size_t)Bn * 27 * NT);
  float* om_s = alloc((size_t)Bn * 27 * NS);
  ushort* owb_t = allocU((size_t)32 * 2304);
  ushort* owb_s = allocU((size_t)32 * 2304);
  ushort* Awb_t = allocU((size_t)256 * 2304);
  ushort* Awb_s = allocU((size_t)256 * 2304);
  uint4* prep_t = (uint4*)alloc((size_t)Bn * 9 * NT * 4);
  uint4* prep_s = (uint4*)alloc((size_t)Bn * 9 * NS * 4);

  dim3 blk(256);

  // merged q|k projections (fp32)
  qkcat_kernel<<<dim3((64 * C + 255) / 256), blk, 0, stream>>>(t_qw, t_qb, t_kw, t_kb, qkw_t, qkb_t, C);
  qkcat_kernel<<<dim3((64 * C + 255) / 256), blk, 0, stream>>>(s_qw, s_qb, s_kw, s_kb, qkw_s, qkb_s, C);
  conv1x1_kernel<<<dim3(4, 1, Bn), blk, 0, stream>>>(t_in, qkw_t, qkb_t, qk_t, C, NT, 64);
  conv1x1_kernel<<<dim3(16, 1, Bn), blk, 0, stream>>>(s_in, qkw_s, qkb_s, qk_s, C, NS, 64);

  // bf16 transposed inputs, padded casts, bf16 weights
  cast_transpose_kernel<<<dim3(NRT / 64, 4, Bn), blk, 0, stream>>>(t_in, xT_t, C, NT, NRT);
  cast_transpose_kernel<<<dim3(NRS / 64, 4, Bn), blk, 0, stream>>>(s_in, xT_s, C, NS, NRS);
  cast_pad_kernel<<<dim3((Bn * C * NpT + 255) / 256), blk, 0, stream>>>(t_in, xbf_t, C, NT, NpT, Bn * C * NpT);
  cast_pad_kernel<<<dim3((Bn * C * NpS + 255) / 256), blk, 0, stream>>>(s_in, xbf_s, C, NS, NpS, Bn * C * NpS);
  castw_kernel<<<dim3((C * C + 255) / 256), blk, 0, stream>>>(t_vw, Wv_t, C * C);
  castw_kernel<<<dim3((C * C + 255) / 256), blk, 0, stream>>>(s_vw, Wv_s, C * C);

  // v projection via MFMA -> bf16 padded
  gemm_abf_kernel<4, 4, 0><<<dim3(NRT / 64, 4, Bn), blk, 0, stream>>>(
      Wv_t, 0, xT_t, t_vb, v_tbf, nullptr, nullptr, NT, NpT, NRT, C);
  gemm_abf_kernel<2, 4, 0><<<dim3(NRS / 64, 2, Bn), blk, 0, stream>>>(
      Wv_s, 0, xT_s, s_vb, v_sbf, nullptr, nullptr, NS, NpS, NRS, C);

  // spatial attention: energy (MFMA) -> softmax -> PV (MFMA)
  energy_mfma_kernel<<<dim3(NpT / 64, 4, Bn), blk, 0, stream>>>(qk_t, qk_t + 32 * NT, S_t, NT, NpT, 64 * NT);
  energy_mfma_kernel<<<dim3((NpS + 63) / 64, 16, Bn), blk, 0, stream>>>(qk_s, qk_s + 32 * NS, S_s, NS, NpS, 64 * NS);
  softmax_bf16_kernel<<<dim3(Bn * NT), blk, 0, stream>>>(S_t, NT, NpT);
  softmax_bf16_kernel<<<dim3(Bn * NS), blk, 0, stream>>>(S_s, NS, NpS);
  pv_mfma_kernel<4, 4><<<dim3(4, 4, Bn), blk, 0, stream>>>(v_tbf, S_t, t_in, t_g, xt, NT, NpT);
  pv_mfma_kernel<2, 4><<<dim3(16, 2, Bn), blk, 0, stream>>>(v_sbf, S_s, s_in, s_g, xs, NS, NpS);

  // channel attention: gram (MFMA, EPI=2) -> softmax -> combined-M GEMM
  gemm_abf_kernel<2, 4, 2><<<dim3(4, 2, Bn), blk, 0, stream>>>(
      xbf_t, 1, xbf_t, nullptr, nullptr, Atc, nullptr, C, C, C, NpT);
  gemm_abf_kernel<2, 4, 2><<<dim3(4, 2, Bn), blk, 0, stream>>>(
      xbf_s, 1, xbf_s, nullptr, nullptr, Asc, nullptr, C, C, C, NpS);
  softmax_rows_kernel<<<dim3(Bn * C), blk, 0, stream>>>(Atc, C, -1.f);
  softmax_rows_kernel<<<dim3(Bn * C), blk, 0, stream>>>(Asc, C, -1.f);
  mcomb_kernel<<<dim3((Bn * C * C + 255) / 256), blk, 0, stream>>>(Atc, Asc, w_t_ch, w_s2t, Mc_t, Bn * C * C);
  mcomb_kernel<<<dim3((Bn * C * C + 255) / 256), blk, 0, stream>>>(Asc, Atc, w_s_ch, w_t2s, Mc_s, Bn * C * C);
  // chan GEMM adds into xsum (fp32) and emits bf16 transposed xsumT
  gemm_abf_kernel<4, 4, 1><<<dim3(NRT / 64, 4, Bn), blk, 0, stream>>>(
      Mc_t, 1, xT_t, nullptr, nullptr, xt, xsT_t, NT, NpT, NRT, C);
  gemm_abf_kernel<2, 4, 1><<<dim3(NRS / 64, 2, Bn), blk, 0, stream>>>(
      Mc_s, 1, xT_s, nullptr, nullptr, xs, xsT_s, NS, NpS, NRS, C);

  // offsets via MFMA (shifted-window GEMM on xsumT)
  offw_prep_kernel<<<dim3((32 * 2304 + 255) / 256), blk, 0, stream>>>(t_off_w, owb_t);
  offw_prep_kernel<<<dim3((32 * 2304 + 255) / 256), blk, 0, stream>>>(s_off_w, owb_s);
  offconv_mfma_kernel<<<dim3(4, 1, Bn), blk, 0, stream>>>(xsT_t, owb_t, t_off_b, om_t, HT, WT, NT, NRT);
  offconv_mfma_kernel<<<dim3(16, 1, Bn), blk, 0, stream>>>(xsT_s, owb_s, s_off_b, om_s, HS, WS2, NS, NRS);

  // DCN prep
  dcnw_prep_kernel<<<dim3((256 * 2304 + 255) / 256), blk, 0, stream>>>(t_dcn_w, Awb_t);
  dcnw_prep_kernel<<<dim3((256 * 2304 + 255) / 256), blk, 0, stream>>>(s_dcn_w, Awb_s);
  prep_offsets_kernel<<<dim3((Bn * 9 * NT + 255) / 256), blk, 0, stream>>>(om_t, prep_t, Bn, HT, WT);
  prep_offsets_kernel<<<dim3((Bn * 9 * NS + 255) / 256), blk, 0, stream>>>(om_s, prep_s, Bn, HS, WS2);

  float* out_t = (float*)d_out;
  float* out_s = out_t + (size_t)Bn * C * NT;
  dcn_mfma_kernel<4, 4><<<dim3(4, 4, Bn), dim3(256), 0, stream>>>(xt, prep_t, Awb_t, t_dcn_b, out_t, NT);
  dcn_mfma_kernel<1, 8><<<dim3(16, 1, Bn), dim3(512), 0, stream>>>(xs, prep_s, Awb_s, s_dcn_b, out_s, NS);
}

// Round 8
// 576.947 us; speedup vs baseline: 2.9721x; 1.2060x over previous
//
#include <hip/hip_runtime.h>
#include <hip/hip_bf16.h>
#include <cmath>

typedef __attribute__((ext_vector_type(8))) short bf16x8;
typedef __attribute__((ext_vector_type(4))) float f32x4;

__device__ inline ushort f2bf(float f) {
  __hip_bfloat16 h = __float2bfloat16(f);
  return *reinterpret_cast<ushort*>(&h);
}
__device__ inline float bf2f(ushort u) {
  return __uint_as_float((uint)u << 16);
}

// XCD-aware bijective remap (requires grid total % 8 == 0)
__device__ inline void xcd_remap(int& bx, int& by, int& bz) {
  const int gx = gridDim.x, gy = gridDim.y, gz = gridDim.z;
  const int total = gx * gy * gz;
  int id = blockIdx.x + gx * (blockIdx.y + gy * blockIdx.z);
  int wid = (id & 7) * (total >> 3) + (id >> 3);
  bx = wid % gx;
  wid /= gx;
  by = wid % gy;
  bz = wid / gy;
}

// ---------------------------------------------------------------------------
// conv1x1 (fp32): merged q|k projection (OC=64)
// ---------------------------------------------------------------------------
__global__ __launch_bounds__(256) void conv1x1_kernel(
    const float* __restrict__ x, const float* __restrict__ w,
    const float* __restrict__ bias, float* __restrict__ out,
    int C, int N, int OC) {
  __shared__ float As[64][17];
  __shared__ float Bs[16][64];
  const int b = blockIdx.z;
  const int m0 = blockIdx.y * 64, n0 = blockIdx.x * 64;
  const float* xb = x + (size_t)b * C * N;
  const int tid = threadIdx.x;
  const int tr = tid >> 4, tc = tid & 15;
  float acc[4][4] = {};
  for (int k0 = 0; k0 < C; k0 += 16) {
    for (int i = tid; i < 64 * 16; i += 256) {
      int m = i >> 4, kk = i & 15;
      int gm = m0 + m;
      As[m][kk] = (gm < OC) ? w[(size_t)gm * C + k0 + kk] : 0.f;
    }
    for (int i = tid; i < 16 * 64; i += 256) {
      int kk = i >> 6, n = i & 63;
      int gn = n0 + n;
      Bs[kk][n] = (gn < N) ? xb[(size_t)(k0 + kk) * N + gn] : 0.f;
    }
    __syncthreads();
#pragma unroll
    for (int kk = 0; kk < 16; ++kk) {
      float a[4], bb[4];
#pragma unroll
      for (int i = 0; i < 4; i++) a[i] = As[tr * 4 + i][kk];
#pragma unroll
      for (int j = 0; j < 4; j++) bb[j] = Bs[kk][tc * 4 + j];
#pragma unroll
      for (int i = 0; i < 4; i++)
#pragma unroll
        for (int j = 0; j < 4; j++) acc[i][j] += a[i] * bb[j];
    }
    __syncthreads();
  }
  for (int i = 0; i < 4; i++) {
    int gm = m0 + tr * 4 + i;
    if (gm >= OC) continue;
    float bv = bias[gm];
    for (int j = 0; j < 4; j++) {
      int gn = n0 + tc * 4 + j;
      if (gn < N) out[((size_t)b * OC + gm) * N + gn] = acc[i][j] + bv;
    }
  }
}

// ---------------------------------------------------------------------------
// concat q,k weights/biases -> [64][C] / [64]
// ---------------------------------------------------------------------------
__global__ __launch_bounds__(256) void qkcat_kernel(
    const float* __restrict__ qw, const float* __restrict__ qb,
    const float* __restrict__ kw, const float* __restrict__ kb,
    float* __restrict__ w, float* __restrict__ b, int C) {
  const int i = blockIdx.x * 256 + threadIdx.x;
  if (i < 32 * C) w[i] = qw[i];
  else if (i < 64 * C) w[i] = kw[i - 32 * C];
  if (i < 32) b[i] = qb[i];
  else if (i < 64) b[i] = kb[i - 32];
}

// ---------------------------------------------------------------------------
// cast+transpose: x fp32 [C][N] -> xT bf16 [NR][C] (rows >= N zeroed)
// ---------------------------------------------------------------------------
__global__ __launch_bounds__(256) void cast_transpose_kernel(
    const float* __restrict__ x, ushort* __restrict__ xT, int C, int N,
    int NR) {
  __shared__ float T[64][65];
  const int b = blockIdx.z;
  const int n0 = blockIdx.x * 64, c0 = blockIdx.y * 64;
  const float* xb = x + (size_t)b * C * N;
  const int tid = threadIdx.x;
  for (int u = tid; u < 4096; u += 256) {
    const int cc = u >> 6, nn = u & 63;
    const int gn = n0 + nn;
    T[cc][nn] = (gn < N) ? xb[(size_t)(c0 + cc) * N + gn] : 0.f;
  }
  __syncthreads();
  ushort* ob = xT + (size_t)b * NR * C;
  for (int u = tid; u < 4096; u += 256) {
    const int nn = u >> 6, cc = u & 63;
    ob[(size_t)(n0 + nn) * C + c0 + cc] = f2bf(T[cc][nn]);
  }
}

// ---------------------------------------------------------------------------
// elementwise fp32 -> bf16 cast (weights)
// ---------------------------------------------------------------------------
__global__ __launch_bounds__(256) void castw_kernel(
    const float* __restrict__ W, ushort* __restrict__ out, int total) {
  const int i = blockIdx.x * 256 + threadIdx.x;
  if (i < total) out[i] = f2bf(W[i]);
}

// ---------------------------------------------------------------------------
// cast with col pad: x fp32 [B][C][N] -> xbf bf16 [B][C][Np] (pads zero)
// ---------------------------------------------------------------------------
__global__ __launch_bounds__(256) void cast_pad_kernel(
    const float* __restrict__ x, ushort* __restrict__ xbf, int C, int N,
    int Np, int total) {
  const int i = blockIdx.x * 256 + threadIdx.x;
  if (i >= total) return;
  const int np = i % Np;
  const int c = (i / Np) % C;
  const int b = i / (Np * C);
  xbf[i] = (np < N) ? f2bf(x[((size_t)b * C + c) * N + np]) : (ushort)0;
}

// ---------------------------------------------------------------------------
// Mcomb = bf16(w1*Aown + w2*Aoth)
// ---------------------------------------------------------------------------
__global__ __launch_bounds__(256) void mcomb_kernel(
    const float* __restrict__ Ao, const float* __restrict__ Ax,
    const float* __restrict__ w1p, const float* __restrict__ w2p,
    ushort* __restrict__ out, int total) {
  const int i = blockIdx.x * 256 + threadIdx.x;
  if (i < total) out[i] = f2bf((*w1p) * Ao[i] + (*w2p) * Ax[i]);
}

// ---------------------------------------------------------------------------
// generic bf16 GEMM: out[m][n] = sum_k A[m][k] * Bt[n][k], M=256.
// EPI 0: outBf[b][m][Np] = bf16(acc+bias[m]) (cols>=N zeroed)  [conv1x1-v]
// EPI 1: outF[b][m][N] += acc; xsT[b][n][m] = bf16(sum)        [chan_use]
// EPI 2: outF[b][m][N] = acc                                   [gram]
// ---------------------------------------------------------------------------
template <int MS, int NW, int EPI>
__global__ __launch_bounds__(NW * 64) void gemm_abf_kernel(
    const ushort* __restrict__ A, int aPerBatch,
    const ushort* __restrict__ Bt, const float* __restrict__ bias,
    ushort* __restrict__ outBf, float* __restrict__ outF,
    ushort* __restrict__ xsT, int N, int Np, int NR, int Kp) {
  constexpr int CM = 256;
  constexpr int BM = CM / MS;
  constexpr int WM = BM / 64;
  constexpr int WN = NW / WM;
  constexpr int NF = 4 / WN;
  __shared__ ushort Asm[BM][40];
  __shared__ ushort Bsm[64][40];
  int bx, by, bz;
  xcd_remap(bx, by, bz);
  const int n0 = bx * 64, m0 = by * BM, b = bz;
  const ushort* Ab = A + (size_t)(aPerBatch ? b : 0) * CM * Kp;
  const ushort* Bb = Bt + (size_t)b * NR * Kp;
  const int tid = threadIdx.x, lane = tid & 63, w = tid >> 6;
  const int wr = w / WN, wc = w % WN;
  f32x4 acc[4][NF];
#pragma unroll
  for (int i = 0; i < 4; i++)
#pragma unroll
    for (int j = 0; j < NF; j++) acc[i][j] = (f32x4){0.f, 0.f, 0.f, 0.f};
  for (int k0 = 0; k0 < Kp; k0 += 32) {
    for (int u = tid; u < BM * 4; u += NW * 64) {
      const int row = u >> 2, seg = u & 3;
      *reinterpret_cast<uint4*>(&Asm[row][seg * 8]) =
          *reinterpret_cast<const uint4*>(&Ab[(size_t)(m0 + row) * Kp + k0 + seg * 8]);
    }
    for (int u = tid; u < 64 * 4; u += NW * 64) {
      const int row = u >> 2, seg = u & 3;
      *reinterpret_cast<uint4*>(&Bsm[row][seg * 8]) =
          *reinterpret_cast<const uint4*>(&Bb[(size_t)(n0 + row) * Kp + k0 + seg * 8]);
    }
    __syncthreads();
    const int koff = (lane >> 4) * 8;
    bf16x8 af[4], bfr[NF];
#pragma unroll
    for (int mf = 0; mf < 4; mf++)
      af[mf] = *reinterpret_cast<const bf16x8*>(&Asm[wr * 64 + mf * 16 + (lane & 15)][koff]);
#pragma unroll
    for (int nf = 0; nf < NF; nf++)
      bfr[nf] = *reinterpret_cast<const bf16x8*>(&Bsm[wc * NF * 16 + nf * 16 + (lane & 15)][koff]);
#pragma unroll
    for (int mf = 0; mf < 4; mf++)
#pragma unroll
      for (int nf = 0; nf < NF; nf++)
        acc[mf][nf] = __builtin_amdgcn_mfma_f32_16x16x32_bf16(af[mf], bfr[nf], acc[mf][nf], 0, 0, 0);
    __syncthreads();
  }
#pragma unroll
  for (int mf = 0; mf < 4; mf++) {
    const int mbase = m0 + wr * 64 + mf * 16 + ((lane >> 4) * 4);
#pragma unroll
    for (int nf = 0; nf < NF; nf++) {
      const int gn = n0 + wc * NF * 16 + nf * 16 + (lane & 15);
      if (EPI == 0) {
#pragma unroll
        for (int rr = 0; rr < 4; rr++) {
          const int m = mbase + rr;
          if (gn < Np) {
            ushort v = (gn < N) ? f2bf(acc[mf][nf][rr] + bias[m]) : (ushort)0;
            outBf[((size_t)b * CM + m) * Np + gn] = v;
          }
        }
      } else if (EPI == 1) {
        if (gn < N) {
          float s[4];
#pragma unroll
          for (int rr = 0; rr < 4; rr++) {
            const size_t idx = ((size_t)b * CM + mbase + rr) * N + gn;
            s[rr] = outF[idx] + acc[mf][nf][rr];
            outF[idx] = s[rr];
          }
          uint lo = (uint)f2bf(s[0]) | ((uint)f2bf(s[1]) << 16);
          uint hi = (uint)f2bf(s[2]) | ((uint)f2bf(s[3]) << 16);
          *reinterpret_cast<uint2*>(&xsT[((size_t)b * NR + gn) * CM + mbase]) =
              make_uint2(lo, hi);
        }
      } else {
#pragma unroll
        for (int rr = 0; rr < 4; rr++) {
          if (gn < N)
            outF[((size_t)b * CM + mbase + rr) * N + gn] = acc[mf][nf][rr];
        }
      }
    }
  }
}

// ---------------------------------------------------------------------------
// energy via MFMA (K=32): S[b][n][m] = sum_q q[q][n]*k[q][m] -> bf16, padded
// ---------------------------------------------------------------------------
__global__ __launch_bounds__(256) void energy_mfma_kernel(
    const float* __restrict__ qg, const float* __restrict__ kg,
    ushort* __restrict__ Sbf, int N, int Np, int bstride) {
  __shared__ ushort Aq[64][40];
  __shared__ ushort Bk[64][40];
  int bx, by, bz;
  xcd_remap(bx, by, bz);
  const int m0 = bx * 64, n0 = by * 64, b = bz;
  const float* qb = qg + (size_t)b * bstride;
  const float* kb = kg + (size_t)b * bstride;
  const int tid = threadIdx.x, lane = tid & 63, w = tid >> 6;
  for (int u = tid; u < 2048; u += 256) {
    const int c = u >> 6, nn = u & 63;
    const int gn = n0 + nn, gm = m0 + nn;
    Aq[nn][c] = (gn < N) ? f2bf(qb[(size_t)c * N + gn]) : (ushort)0;
    Bk[nn][c] = (gm < N) ? f2bf(kb[(size_t)c * N + gm]) : (ushort)0;
  }
  __syncthreads();
  const int koff = (lane >> 4) * 8;
  const bf16x8 af = *reinterpret_cast<const bf16x8*>(&Aq[w * 16 + (lane & 15)][koff]);
  f32x4 acc[4];
#pragma unroll
  for (int j = 0; j < 4; j++) {
    const bf16x8 bf = *reinterpret_cast<const bf16x8*>(&Bk[j * 16 + (lane & 15)][koff]);
    acc[j] = __builtin_amdgcn_mfma_f32_16x16x32_bf16(af, bf, (f32x4){0.f, 0.f, 0.f, 0.f}, 0, 0, 0);
  }
#pragma unroll
  for (int j = 0; j < 4; j++) {
    const int m = m0 + j * 16 + (lane & 15);
    if (m >= Np) continue;
#pragma unroll
    for (int r = 0; r < 4; r++) {
      const int n = n0 + w * 16 + (lane >> 4) * 4 + r;
      if (n < N) Sbf[((size_t)b * N + n) * Np + m] = (m < N) ? f2bf(acc[j][r]) : (ushort)0;
    }
  }
}

// ---------------------------------------------------------------------------
// fp32 in-place row softmax of sign*r (channel attention)
// ---------------------------------------------------------------------------
__global__ __launch_bounds__(256) void softmax_rows_kernel(
    float* __restrict__ e, int N, float sign) {
  const size_t row = blockIdx.x;
  float* r = e + row * (size_t)N;
  const int tid = threadIdx.x;
  __shared__ float red[4];
  float mx = -1e30f;
  for (int i = tid; i < N; i += 256) mx = fmaxf(mx, sign * r[i]);
#pragma unroll
  for (int off = 32; off; off >>= 1) mx = fmaxf(mx, __shfl_xor(mx, off, 64));
  if ((tid & 63) == 0) red[tid >> 6] = mx;
  __syncthreads();
  if (tid == 0) {
    float m2 = red[0];
    for (int i = 1; i < 4; i++) m2 = fmaxf(m2, red[i]);
    red[0] = m2;
  }
  __syncthreads();
  mx = red[0];
  __syncthreads();
  float s = 0.f;
  for (int i = tid; i < N; i += 256) {
    float v = __expf(sign * r[i] - mx);
    r[i] = v;
    s += v;
  }
#pragma unroll
  for (int off = 32; off; off >>= 1) s += __shfl_xor(s, off, 64);
  if ((tid & 63) == 0) red[tid >> 6] = s;
  __syncthreads();
  if (tid == 0) {
    float t = 0.f;
    for (int i = 0; i < 4; i++) t += red[i];
    red[0] = t;
  }
  __syncthreads();
  const float inv = 1.f / red[0];
  for (int i = tid; i < N; i += 256) r[i] *= inv;
}

// ---------------------------------------------------------------------------
// bf16 in-place row softmax (spatial attention scores)
// ---------------------------------------------------------------------------
__global__ __launch_bounds__(256) void softmax_bf16_kernel(
    ushort* __restrict__ Sbf, int N, int Np) {
  __shared__ float buf[992];
  __shared__ float red[4];
  const size_t row = blockIdx.x;
  ushort* r = Sbf + row * (size_t)Np;
  const int tid = threadIdx.x;
  float mx = -1e30f;
  for (int i = tid; i < N; i += 256) {
    float f = bf2f(r[i]);
    buf[i] = f;
    mx = fmaxf(mx, f);
  }
#pragma unroll
  for (int off = 32; off; off >>= 1) mx = fmaxf(mx, __shfl_xor(mx, off, 64));
  if ((tid & 63) == 0) red[tid >> 6] = mx;
  __syncthreads();
  if (tid == 0) {
    float m2 = red[0];
    for (int i = 1; i < 4; i++) m2 = fmaxf(m2, red[i]);
    red[0] = m2;
  }
  __syncthreads();
  mx = red[0];
  __syncthreads();
  float s = 0.f;
  for (int i = tid; i < N; i += 256) {
    float v = __expf(buf[i] - mx);
    buf[i] = v;
    s += v;
  }
#pragma unroll
  for (int off = 32; off; off >>= 1) s += __shfl_xor(s, off, 64);
  if ((tid & 63) == 0) red[tid >> 6] = s;
  __syncthreads();
  if (tid == 0) {
    float t = 0.f;
    for (int i = 0; i < 4; i++) t += red[i];
    red[0] = t;
  }
  __syncthreads();
  const float inv = 1.f / red[0];
  for (int i = tid; i < N; i += 256) r[i] = f2bf(buf[i] * inv);
}

// ---------------------------------------------------------------------------
// PV via MFMA: xsum = x + g * v @ A^T, XCD-swizzled
// ---------------------------------------------------------------------------
template <int MS, int NW>
__global__ __launch_bounds__(NW * 64) void pv_mfma_kernel(
    const ushort* __restrict__ vbf, const ushort* __restrict__ Abf,
    const float* __restrict__ x, const float* __restrict__ gp,
    float* __restrict__ xsum, int N, int Np) {
  constexpr int C = 256;
  constexpr int BM = C / MS;
  constexpr int WM = BM / 64;
  constexpr int WN = NW / WM;
  constexpr int NF = 4 / WN;
  __shared__ ushort Asm[BM][40];
  __shared__ ushort Bsm[64][40];
  int bx, by, bz;
  xcd_remap(bx, by, bz);
  const int n0 = bx * 64, m0 = by * BM, b = bz;
  const int tid = threadIdx.x, lane = tid & 63, w = tid >> 6;
  const int wr = w / WN, wc = w % WN;
  const ushort* vb = vbf + (size_t)b * C * Np;
  const ushort* Ab = Abf + (size_t)b * (size_t)N * Np;
  f32x4 acc[4][NF];
#pragma unroll
  for (int i = 0; i < 4; i++)
#pragma unroll
    for (int j = 0; j < NF; j++) acc[i][j] = (f32x4){0.f, 0.f, 0.f, 0.f};
  for (int k0 = 0; k0 < Np; k0 += 32) {
    for (int u = tid; u < BM * 4; u += NW * 64) {
      const int row = u >> 2, seg = u & 3;
      *reinterpret_cast<uint4*>(&Asm[row][seg * 8]) =
          *reinterpret_cast<const uint4*>(&vb[(size_t)(m0 + row) * Np + k0 + seg * 8]);
    }
    for (int u = tid; u < 64 * 4; u += NW * 64) {
      const int row = u >> 2, seg = u & 3;
      const int gn = n0 + row;
      uint4 val;
      if (gn < N)
        val = *reinterpret_cast<const uint4*>(&Ab[(size_t)gn * Np + k0 + seg * 8]);
      else
        val = make_uint4(0, 0, 0, 0);
      *reinterpret_cast<uint4*>(&Bsm[row][seg * 8]) = val;
    }
    __syncthreads();
    const int koff = (lane >> 4) * 8;
    bf16x8 af[4], bfr[NF];
#pragma unroll
    for (int mf = 0; mf < 4; mf++)
      af[mf] = *reinterpret_cast<const bf16x8*>(&Asm[wr * 64 + mf * 16 + (lane & 15)][koff]);
#pragma unroll
    for (int nf = 0; nf < NF; nf++)
      bfr[nf] = *reinterpret_cast<const bf16x8*>(&Bsm[wc * NF * 16 + nf * 16 + (lane & 15)][koff]);
#pragma unroll
    for (int mf = 0; mf < 4; mf++)
#pragma unroll
      for (int nf = 0; nf < NF; nf++)
        acc[mf][nf] = __builtin_amdgcn_mfma_f32_16x16x32_bf16(af[mf], bfr[nf], acc[mf][nf], 0, 0, 0);
    __syncthreads();
  }
  const float g = *gp;
#pragma unroll
  for (int mf = 0; mf < 4; mf++) {
    const int mbase = m0 + wr * 64 + mf * 16 + ((lane >> 4) * 4);
#pragma unroll
    for (int nf = 0; nf < NF; nf++) {
      const int gn = n0 + wc * NF * 16 + nf * 16 + (lane & 15);
      if (gn < N) {
#pragma unroll
        for (int rr = 0; rr < 4; rr++) {
          const size_t idx = ((size_t)b * C + mbase + rr) * N + gn;
          xsum[idx] = x[idx] + g * acc[mf][nf][rr];
        }
      }
    }
  }
}

// ---------------------------------------------------------------------------
// offconv weight reorder: ow[27][C][9] -> owb[32][tap*256+c] bf16 (rows>=27 = 0)
// ---------------------------------------------------------------------------
__global__ __launch_bounds__(256) void offw_prep_kernel(
    const float* __restrict__ ow, ushort* __restrict__ owb) {
  const int i = blockIdx.x * 256 + threadIdx.x;
  if (i >= 32 * 2304) return;
  const int o = i / 2304, k = i % 2304;
  const int tap = k >> 8, c = k & 255;
  owb[i] = (o < 27) ? f2bf(ow[(size_t)o * 2304 + c * 9 + tap]) : (ushort)0;
}

// ---------------------------------------------------------------------------
// offconv via MFMA on xsT (shifted-window GEMM)
// ---------------------------------------------------------------------------
__global__ __launch_bounds__(256) void offconv_mfma_kernel(
    const ushort* __restrict__ xsT, const ushort* __restrict__ owb,
    const float* __restrict__ ob, float* __restrict__ om,
    int H, int Wd, int N, int NR) {
  __shared__ ushort Asm[32][72];
  __shared__ ushort Bsm[64][72];
  __shared__ int qsrc[64];
  int bx, by, bz;
  xcd_remap(bx, by, bz);
  const int n0 = bx * 64, b = bz;
  const int tid = threadIdx.x, lane = tid & 63, w = tid >> 6;
  const ushort* xb = xsT + (size_t)b * NR * 256;
  f32x4 acc[2];
  acc[0] = (f32x4){0.f, 0.f, 0.f, 0.f};
  acc[1] = (f32x4){0.f, 0.f, 0.f, 0.f};
  for (int tap = 0; tap < 9; ++tap) {
    const int dy = tap / 3 - 1, dx = tap - (tap / 3) * 3 - 1;
    if (tid < 64) {
      const int p = n0 + tid;
      int q = -1;
      if (p < N) {
        const int h = p / Wd, ww = p - (p / Wd) * Wd;
        const int yy = h + dy, xx = ww + dx;
        if (yy >= 0 && yy < H && xx >= 0 && xx < Wd) q = yy * Wd + xx;
      }
      qsrc[tid] = q;
    }
    __syncthreads();
    for (int ks = 0; ks < 4; ++ks) {
      const int k0 = tap * 256 + ks * 64;
      {
        const int row = tid >> 3, seg = tid & 7;
        *reinterpret_cast<uint4*>(&Asm[row][seg * 8]) =
            *reinterpret_cast<const uint4*>(&owb[(size_t)row * 2304 + k0 + seg * 8]);
      }
      for (int u = tid; u < 512; u += 256) {
        const int row = u >> 3, seg = u & 7;
        const int q = qsrc[row];
        uint4 val = make_uint4(0, 0, 0, 0);
        if (q >= 0)
          val = *reinterpret_cast<const uint4*>(&xb[(size_t)q * 256 + ks * 64 + seg * 8]);
        *reinterpret_cast<uint4*>(&Bsm[row][seg * 8]) = val;
      }
      __syncthreads();
#pragma unroll
      for (int sub = 0; sub < 2; ++sub) {
        const int koff = sub * 32 + (lane >> 4) * 8;
        const bf16x8 b0 = *reinterpret_cast<const bf16x8*>(&Bsm[w * 16 + (lane & 15)][koff]);
#pragma unroll
        for (int mf = 0; mf < 2; ++mf) {
          const bf16x8 a0 = *reinterpret_cast<const bf16x8*>(&Asm[mf * 16 + (lane & 15)][koff]);
          acc[mf] = __builtin_amdgcn_mfma_f32_16x16x32_bf16(a0, b0, acc[mf], 0, 0, 0);
        }
      }
      __syncthreads();
    }
  }
#pragma unroll
  for (int mf = 0; mf < 2; ++mf) {
#pragma unroll
    for (int r = 0; r < 4; ++r) {
      const int o = mf * 16 + (lane >> 4) * 4 + r;
      const int n = n0 + w * 16 + (lane & 15);
      if (o < 27 && n < N)
        om[((size_t)b * 27 + o) * N + n] = acc[mf][r] + ob[o];
    }
  }
}

// ---------------------------------------------------------------------------
// reorder+convert DCN weights (O,C,3,3) fp32 -> Awb[o][k=tap*256+c] bf16
// ---------------------------------------------------------------------------
__global__ __launch_bounds__(256) void dcnw_prep_kernel(
    const float* __restrict__ W, ushort* __restrict__ Awb) {
  const int i = blockIdx.x * 256 + threadIdx.x;
  if (i >= 256 * 2304) return;
  const int o = i / 2304, k = i % 2304;
  const int tap = k >> 8, c = k & 255;
  Awb[i] = f2bf(W[(size_t)o * 2304 + c * 9 + tap]);
}

// ---------------------------------------------------------------------------
// packed bilinear gather table (r8): uint4 = {q00, w00|w01, w10|w11, 0}
// corners at q00, q00+1, q00+W, q00+W+1 with base clamped to [0,H-2]x[0,W-2];
// per-sampled-position weights reproduce the reference's validity mask.
// ---------------------------------------------------------------------------
__global__ __launch_bounds__(256) void prep_offsets_kernel(
    const float* __restrict__ om, uint4* __restrict__ prep, int B, int H,
    int Wd) {
  const int N = H * Wd;
  const int i = blockIdx.x * 256 + threadIdx.x;
  if (i >= B * 9 * N) return;
  const int p = i % N;
  const int k = (i / N) % 9;
  const int b = i / (9 * N);
  const float* omb = om + (size_t)b * 27 * N;
  const float offy = omb[(size_t)k * N + p];
  const float offx = omb[(size_t)(9 + k) * N + p];
  const float mraw = omb[(size_t)(18 + k) * N + p];
  const float mval = 1.f / (1.f + __expf(-mraw));
  const int ky = k / 3, kx = k - (k / 3) * 3;
  const int h = p / Wd, w = p - (p / Wd) * Wd;
  const float py = offy + (float)(h + ky - 1);
  const float px = offx + (float)(w + kx - 1);
  const float y0f = floorf(py), x0f = floorf(px);
  const float wy = py - y0f, wx = px - x0f;
  const int y0 = (int)y0f, x0 = (int)x0f;
  const int ys0 = min(max(y0, 0), H - 2);
  const int xs0 = min(max(x0, 0), Wd - 2);
  // weight of each sampled grid position (0 if it isn't y0/y0+1 within bounds)
  const float wr0 = (ys0 == y0) ? (1.f - wy) : ((ys0 == y0 + 1) ? wy : 0.f);
  const float wr1 = (ys0 + 1 == y0) ? (1.f - wy) : ((ys0 + 1 == y0 + 1) ? wy : 0.f);
  const float wc0 = (xs0 == x0) ? (1.f - wx) : ((xs0 == x0 + 1) ? wx : 0.f);
  const float wc1 = (xs0 + 1 == x0) ? (1.f - wx) : ((xs0 + 1 == x0 + 1) ? wx : 0.f);
  const float w00 = wr0 * wc0 * mval, w01 = wr0 * wc1 * mval;
  const float w10 = wr1 * wc0 * mval, w11 = wr1 * wc1 * mval;
  uint4 pk;
  pk.x = (uint)(ys0 * Wd + xs0);
  pk.y = (uint)f2bf(w00) | ((uint)f2bf(w01) << 16);
  pk.z = (uint)f2bf(w10) | ((uint)f2bf(w11) << 16);
  pk.w = 0;
  prep[i] = pk;
}

// ---------------------------------------------------------------------------
// DCN via MFMA, gather from bf16 xsT [p][c] with vector corner loads.
// BM=256/MS, BN=32, BK=32, 8 waves (512 thr). grid (ceil(N/32), MS, B).
// ---------------------------------------------------------------------------
template <int MS>
__global__ __launch_bounds__(512) void dcn_mfma_kernel(
    const ushort* __restrict__ xsT, const uint4* __restrict__ prep,
    const ushort* __restrict__ Awb, const float* __restrict__ bias,
    float* __restrict__ out, int N, int Wd, int NR) {
  constexpr int C = 256, KTOT = 2304;
  constexpr int BM = C / MS;   // 256 or 128
  constexpr int MF = BM / 64;  // 4 or 2 fragments per wave (wave tile BM/4 x 16)
  __shared__ ushort Asm[BM][40];
  __shared__ ushort Bsm[32][40];
  __shared__ int sq[32];
  __shared__ float sw0[32], sw1[32], sw2[32], sw3[32];
  int bx, by, bz;
  xcd_remap(bx, by, bz);
  const int n0 = bx * 32, m0 = by * BM, b = bz;
  const int tid = threadIdx.x, lane = tid & 63, w = tid >> 6;
  const int wr = w >> 1, wc = w & 1;  // 4 waves in M, 2 in N
  const ushort* xb = xsT + (size_t)b * NR * C;
  f32x4 acc[MF];
#pragma unroll
  for (int i = 0; i < MF; i++) acc[i] = (f32x4){0.f, 0.f, 0.f, 0.f};
  for (int k0 = 0; k0 < KTOT; k0 += 32) {
    const int kpos = k0 >> 8, c0 = k0 & 255;
    if (c0 == 0) {
      if (tid < 32) {
        const int p = n0 + tid;
        if (p < N) {
          const uint4 pk = prep[((size_t)b * 9 + kpos) * N + p];
          sq[tid] = (int)pk.x * C;
          sw0[tid] = bf2f((ushort)(pk.y & 0xffff));
          sw1[tid] = bf2f((ushort)(pk.y >> 16));
          sw2[tid] = bf2f((ushort)(pk.z & 0xffff));
          sw3[tid] = bf2f((ushort)(pk.z >> 16));
        } else {
          sq[tid] = 0;
          sw0[tid] = sw1[tid] = sw2[tid] = sw3[tid] = 0.f;
        }
      }
      __syncthreads();
    }
    // A-stage: BM rows x 32 k = BM*4 uint4
    for (int u = tid; u < BM * 4; u += 512) {
      const int row = u >> 2, seg = u & 3;
      *reinterpret_cast<uint4*>(&Asm[row][seg * 8]) =
          *reinterpret_cast<const uint4*>(&Awb[(size_t)(m0 + row) * KTOT + k0 + seg * 8]);
    }
    // B-stage: 512 units = 32 cols x 16 channel-pairs; vector corner loads
    {
      const int n = tid >> 4, pr = tid & 15;
      const int kk = pr * 2;
      const ushort* p0 = xb + sq[n] + c0 + kk;
      const uint a00 = *reinterpret_cast<const uint*>(p0);
      const uint a01 = *reinterpret_cast<const uint*>(p0 + C);
      const uint a10 = *reinterpret_cast<const uint*>(p0 + (size_t)Wd * C);
      const uint a11 = *reinterpret_cast<const uint*>(p0 + (size_t)(Wd + 1) * C);
      const float w00 = sw0[n], w01 = sw1[n], w10 = sw2[n], w11 = sw3[n];
      const float vlo = w00 * __uint_as_float(a00 << 16) +
                        w01 * __uint_as_float(a01 << 16) +
                        w10 * __uint_as_float(a10 << 16) +
                        w11 * __uint_as_float(a11 << 16);
      const float vhi = w00 * __uint_as_float(a00 & 0xffff0000u) +
                        w01 * __uint_as_float(a01 & 0xffff0000u) +
                        w10 * __uint_as_float(a10 & 0xffff0000u) +
                        w11 * __uint_as_float(a11 & 0xffff0000u);
      *reinterpret_cast<uint*>(&Bsm[n][kk]) =
          (uint)f2bf(vlo) | ((uint)f2bf(vhi) << 16);
    }
    __syncthreads();
    const int koff = (lane >> 4) * 8;
    const bf16x8 bf = *reinterpret_cast<const bf16x8*>(&Bsm[wc * 16 + (lane & 15)][koff]);
#pragma unroll
    for (int mf = 0; mf < MF; mf++) {
      const bf16x8 af = *reinterpret_cast<const bf16x8*>(
          &Asm[wr * (BM / 4) + mf * 16 + (lane & 15)][koff]);
      acc[mf] = __builtin_amdgcn_mfma_f32_16x16x32_bf16(af, bf, acc[mf], 0, 0, 0);
    }
    __syncthreads();
  }
  const int gn = n0 + wc * 16 + (lane & 15);
#pragma unroll
  for (int mf = 0; mf < MF; mf++) {
    const int mbase = m0 + wr * (BM / 4) + mf * 16 + ((lane >> 4) * 4);
    if (gn < N) {
#pragma unroll
      for (int rr = 0; rr < 4; rr++)
        out[((size_t)b * C + mbase + rr) * N + gn] = acc[mf][rr] + bias[mbase + rr];
    }
  }
}

// ---------------------------------------------------------------------------
extern "C" void kernel_launch(void* const* d_in, const int* in_sizes, int n_in,
                              void* d_out, int out_size, void* d_ws, size_t ws_size,
                              hipStream_t stream) {
  const float* t_in = (const float*)d_in[0];
  const float* s_in = (const float*)d_in[1];
  const float* t_qw = (const float*)d_in[2];
  const float* t_qb = (const float*)d_in[3];
  const float* t_kw = (const float*)d_in[4];
  const float* t_kb = (const float*)d_in[5];
  const float* t_vw = (const float*)d_in[6];
  const float* t_vb = (const float*)d_in[7];
  const float* t_g = (const float*)d_in[8];
  const float* s_qw = (const float*)d_in[9];
  const float* s_qb = (const float*)d_in[10];
  const float* s_kw = (const float*)d_in[11];
  const float* s_kb = (const float*)d_in[12];
  const float* s_vw = (const float*)d_in[13];
  const float* s_vb = (const float*)d_in[14];
  const float* s_g = (const float*)d_in[15];
  const float* w_t_ch = (const float*)d_in[16];
  const float* w_s_ch = (const float*)d_in[17];
  const float* w_s2t = (const float*)d_in[18];
  const float* w_t2s = (const float*)d_in[19];
  const float* t_off_w = (const float*)d_in[20];
  const float* t_off_b = (const float*)d_in[21];
  const float* t_dcn_w = (const float*)d_in[22];
  const float* t_dcn_b = (const float*)d_in[23];
  const float* s_off_w = (const float*)d_in[24];
  const float* s_off_b = (const float*)d_in[25];
  const float* s_dcn_w = (const float*)d_in[26];
  const float* s_dcn_b = (const float*)d_in[27];
  (void)in_sizes; (void)n_in; (void)out_size; (void)ws_size;

  constexpr int Bn = 16, C = 256, QKd = 32;
  constexpr int HT = 15, WT = 15, NT = HT * WT;    // 225
  constexpr int HS = 31, WS2 = 31, NS = HS * WS2;  // 961
  constexpr int NpT = 256, NpS = 992;              // col pads (mult of 32)
  constexpr int NRT = 256, NRS = 1024;             // row pads (mult of 64)

  float* ws = (float*)d_ws;
  size_t off = 0;
  auto alloc = [&](size_t n) {
    n = (n + 3) & ~(size_t)3;
    float* p = ws + off; off += n; return p;
  };
  auto allocU = [&](size_t nu) { return (ushort*)alloc((nu + 1) / 2); };

  float* qk_t = alloc((size_t)Bn * 64 * NT);
  float* qk_s = alloc((size_t)Bn * 64 * NS);
  float* qkw_t = alloc((size_t)64 * C + 64);
  float* qkw_s = alloc((size_t)64 * C + 64);
  float* qkb_t = qkw_t + (size_t)64 * C;
  float* qkb_s = qkw_s + (size_t)64 * C;
  ushort* xT_t = allocU((size_t)Bn * NRT * C);
  ushort* xT_s = allocU((size_t)Bn * NRS * C);
  ushort* xbf_t = allocU((size_t)Bn * C * NpT);
  ushort* xbf_s = allocU((size_t)Bn * C * NpS);
  ushort* Wv_t = allocU((size_t)C * C);
  ushort* Wv_s = allocU((size_t)C * C);
  ushort* v_tbf = allocU((size_t)Bn * C * NpT);
  ushort* v_sbf = allocU((size_t)Bn * C * NpS);
  ushort* S_t = allocU((size_t)Bn * NT * NpT);
  ushort* S_s = allocU((size_t)Bn * NS * NpS);
  float* xt = alloc((size_t)Bn * C * NT);
  float* xs = alloc((size_t)Bn * C * NS);
  ushort* xsT_t = allocU((size_t)Bn * NRT * C);
  ushort* xsT_s = allocU((size_t)Bn * NRS * C);
  float* Atc = alloc((size_t)Bn * C * C);
  float* Asc = alloc((size_t)Bn * C * C);
  ushort* Mc_t = allocU((size_t)Bn * C * C);
  ushort* Mc_s = allocU((size_t)Bn * C * C);
  float* om_t = alloc((size_t)Bn * 27 * NT);
  float* om_s = alloc((size_t)Bn * 27 * NS);
  ushort* owb_t = allocU((size_t)32 * 2304);
  ushort* owb_s = allocU((size_t)32 * 2304);
  ushort* Awb_t = allocU((size_t)256 * 2304);
  ushort* Awb_s = allocU((size_t)256 * 2304);
  uint4* prep_t = (uint4*)alloc((size_t)Bn * 9 * NT * 4);
  uint4* prep_s = (uint4*)alloc((size_t)Bn * 9 * NS * 4);

  dim3 blk(256);

  // merged q|k projections (fp32)
  qkcat_kernel<<<dim3((64 * C + 255) / 256), blk, 0, stream>>>(t_qw, t_qb, t_kw, t_kb, qkw_t, qkb_t, C);
  qkcat_kernel<<<dim3((64 * C + 255) / 256), blk, 0, stream>>>(s_qw, s_qb, s_kw, s_kb, qkw_s, qkb_s, C);
  conv1x1_kernel<<<dim3(4, 1, Bn), blk, 0, stream>>>(t_in, qkw_t, qkb_t, qk_t, C, NT, 64);
  conv1x1_kernel<<<dim3(16, 1, Bn), blk, 0, stream>>>(s_in, qkw_s, qkb_s, qk_s, C, NS, 64);

  // bf16 transposed inputs, padded casts, bf16 weights
  cast_transpose_kernel<<<dim3(NRT / 64, 4, Bn), blk, 0, stream>>>(t_in, xT_t, C, NT, NRT);
  cast_transpose_kernel<<<dim3(NRS / 64, 4, Bn), blk, 0, stream>>>(s_in, xT_s, C, NS, NRS);
  cast_pad_kernel<<<dim3((Bn * C * NpT + 255) / 256), blk, 0, stream>>>(t_in, xbf_t, C, NT, NpT, Bn * C * NpT);
  cast_pad_kernel<<<dim3((Bn * C * NpS + 255) / 256), blk, 0, stream>>>(s_in, xbf_s, C, NS, NpS, Bn * C * NpS);
  castw_kernel<<<dim3((C * C + 255) / 256), blk, 0, stream>>>(t_vw, Wv_t, C * C);
  castw_kernel<<<dim3((C * C + 255) / 256), blk, 0, stream>>>(s_vw, Wv_s, C * C);

  // v projection via MFMA -> bf16 padded
  gemm_abf_kernel<4, 4, 0><<<dim3(NRT / 64, 4, Bn), blk, 0, stream>>>(
      Wv_t, 0, xT_t, t_vb, v_tbf, nullptr, nullptr, NT, NpT, NRT, C);
  gemm_abf_kernel<2, 4, 0><<<dim3(NRS / 64, 2, Bn), blk, 0, stream>>>(
      Wv_s, 0, xT_s, s_vb, v_sbf, nullptr, nullptr, NS, NpS, NRS, C);

  // spatial attention: energy (MFMA) -> softmax -> PV (MFMA)
  energy_mfma_kernel<<<dim3(NpT / 64, 4, Bn), blk, 0, stream>>>(qk_t, qk_t + 32 * NT, S_t, NT, NpT, 64 * NT);
  energy_mfma_kernel<<<dim3((NpS + 63) / 64, 16, Bn), blk, 0, stream>>>(qk_s, qk_s + 32 * NS, S_s, NS, NpS, 64 * NS);
  softmax_bf16_kernel<<<dim3(Bn * NT), blk, 0, stream>>>(S_t, NT, NpT);
  softmax_bf16_kernel<<<dim3(Bn * NS), blk, 0, stream>>>(S_s, NS, NpS);
  pv_mfma_kernel<4, 4><<<dim3(4, 4, Bn), blk, 0, stream>>>(v_tbf, S_t, t_in, t_g, xt, NT, NpT);
  pv_mfma_kernel<2, 4><<<dim3(16, 2, Bn), blk, 0, stream>>>(v_sbf, S_s, s_in, s_g, xs, NS, NpS);

  // channel attention: gram (MFMA, EPI=2) -> softmax -> combined-M GEMM
  gemm_abf_kernel<2, 4, 2><<<dim3(4, 2, Bn), blk, 0, stream>>>(
      xbf_t, 1, xbf_t, nullptr, nullptr, Atc, nullptr, C, C, C, NpT);
  gemm_abf_kernel<2, 4, 2><<<dim3(4, 2, Bn), blk, 0, stream>>>(
      xbf_s, 1, xbf_s, nullptr, nullptr, Asc, nullptr, C, C, C, NpS);
  softmax_rows_kernel<<<dim3(Bn * C), blk, 0, stream>>>(Atc, C, -1.f);
  softmax_rows_kernel<<<dim3(Bn * C), blk, 0, stream>>>(Asc, C, -1.f);
  mcomb_kernel<<<dim3((Bn * C * C + 255) / 256), blk, 0, stream>>>(Atc, Asc, w_t_ch, w_s2t, Mc_t, Bn * C * C);
  mcomb_kernel<<<dim3((Bn * C * C + 255) / 256), blk, 0, stream>>>(Asc, Atc, w_s_ch, w_t2s, Mc_s, Bn * C * C);
  // chan GEMM adds into xsum (fp32) and emits bf16 transposed xsumT
  gemm_abf_kernel<4, 4, 1><<<dim3(NRT / 64, 4, Bn), blk, 0, stream>>>(
      Mc_t, 1, xT_t, nullptr, nullptr, xt, xsT_t, NT, NpT, NRT, C);
  gemm_abf_kernel<2, 4, 1><<<dim3(NRS / 64, 2, Bn), blk, 0, stream>>>(
      Mc_s, 1, xT_s, nullptr, nullptr, xs, xsT_s, NS, NpS, NRS, C);

  // offsets via MFMA (shifted-window GEMM on xsumT)
  offw_prep_kernel<<<dim3((32 * 2304 + 255) / 256), blk, 0, stream>>>(t_off_w, owb_t);
  offw_prep_kernel<<<dim3((32 * 2304 + 255) / 256), blk, 0, stream>>>(s_off_w, owb_s);
  offconv_mfma_kernel<<<dim3(4, 1, Bn), blk, 0, stream>>>(xsT_t, owb_t, t_off_b, om_t, HT, WT, NT, NRT);
  offconv_mfma_kernel<<<dim3(16, 1, Bn), blk, 0, stream>>>(xsT_s, owb_s, s_off_b, om_s, HS, WS2, NS, NRS);

  // DCN prep
  dcnw_prep_kernel<<<dim3((256 * 2304 + 255) / 256), blk, 0, stream>>>(t_dcn_w, Awb_t);
  dcnw_prep_kernel<<<dim3((256 * 2304 + 255) / 256), blk, 0, stream>>>(s_dcn_w, Awb_s);
  prep_offsets_kernel<<<dim3((Bn * 9 * NT + 255) / 256), blk, 0, stream>>>(om_t, prep_t, Bn, HT, WT);
  prep_offsets_kernel<<<dim3((Bn * 9 * NS + 255) / 256), blk, 0, stream>>>(om_s, prep_s, Bn, HS, WS2);

  float* out_t = (float*)d_out;
  float* out_s = out_t + (size_t)Bn * C * NT;
  // DCN: gather from xsT (bf16, [p][c]); s: BM=256 tiles, t: M-split 2
  dcn_mfma_kernel<2><<<dim3(8, 2, Bn), dim3(512), 0, stream>>>(
      xsT_t, prep_t, Awb_t, t_dcn_b, out_t, NT, WT, NRT);
  dcn_mfma_kernel<1><<<dim3(32, 1, Bn), dim3(512), 0, stream>>>(
      xsT_s, prep_s, Awb_s, s_dcn_b, out_s, NS, WS2, NRS);
}

// Round 9
// 560.337 us; speedup vs baseline: 3.0602x; 1.0296x over previous
//
#include <hip/hip_runtime.h>
#include <hip/hip_bf16.h>
#include <cmath>

typedef __attribute__((ext_vector_type(8))) short bf16x8;
typedef __attribute__((ext_vector_type(4))) float f32x4;

__device__ inline ushort f2bf(float f) {
  __hip_bfloat16 h = __float2bfloat16(f);
  return *reinterpret_cast<ushort*>(&h);
}
__device__ inline float bf2f(ushort u) {
  return __uint_as_float((uint)u << 16);
}

// XCD-aware bijective remap (requires grid total % 8 == 0)
__device__ inline void xcd_remap(int& bx, int& by, int& bz) {
  const int gx = gridDim.x, gy = gridDim.y, gz = gridDim.z;
  const int total = gx * gy * gz;
  int id = blockIdx.x + gx * (blockIdx.y + gy * blockIdx.z);
  int wid = (id & 7) * (total >> 3) + (id >> 3);
  bx = wid % gx;
  wid /= gx;
  by = wid % gy;
  bz = wid / gy;
}

// ---------------------------------------------------------------------------
// fused weight prep: qk concat (t,s) + bf16 casts of v-weights +
// offconv reorder (t,s) + dcn reorder (t,s). One launch replaces 8.
// ---------------------------------------------------------------------------
__global__ __launch_bounds__(256) void prep_weights_kernel(
    const float* __restrict__ t_qw, const float* __restrict__ t_qb,
    const float* __restrict__ t_kw, const float* __restrict__ t_kb,
    const float* __restrict__ s_qw, const float* __restrict__ s_qb,
    const float* __restrict__ s_kw, const float* __restrict__ s_kb,
    const float* __restrict__ t_vw, const float* __restrict__ s_vw,
    const float* __restrict__ t_off_w, const float* __restrict__ s_off_w,
    const float* __restrict__ t_dcn_w, const float* __restrict__ s_dcn_w,
    float* __restrict__ qkw_t, float* __restrict__ qkb_t,
    float* __restrict__ qkw_s, float* __restrict__ qkb_s,
    ushort* __restrict__ Wv_t, ushort* __restrict__ Wv_s,
    ushort* __restrict__ owb_t, ushort* __restrict__ owb_s,
    ushort* __restrict__ Awb_t, ushort* __restrict__ Awb_s) {
  int i = blockIdx.x * 256 + threadIdx.x;
  // qk t (64*256 w + 64 b)
  if (i < 16448) {
    if (i < 8192) qkw_t[i] = t_qw[i];
    else if (i < 16384) qkw_t[i] = t_kw[i - 8192];
    else { int j = i - 16384; qkb_t[j] = (j < 32) ? t_qb[j] : t_kb[j - 32]; }
    return;
  }
  i -= 16448;
  if (i < 16448) {
    if (i < 8192) qkw_s[i] = s_qw[i];
    else if (i < 16384) qkw_s[i] = s_kw[i - 8192];
    else { int j = i - 16384; qkb_s[j] = (j < 32) ? s_qb[j] : s_kb[j - 32]; }
    return;
  }
  i -= 16448;
  if (i < 65536) { Wv_t[i] = f2bf(t_vw[i]); return; }
  i -= 65536;
  if (i < 65536) { Wv_s[i] = f2bf(s_vw[i]); return; }
  i -= 65536;
  if (i < 73728) {
    const int o = i / 2304, k = i % 2304, tap = k >> 8, c = k & 255;
    owb_t[i] = (o < 27) ? f2bf(t_off_w[(size_t)o * 2304 + c * 9 + tap]) : (ushort)0;
    return;
  }
  i -= 73728;
  if (i < 73728) {
    const int o = i / 2304, k = i % 2304, tap = k >> 8, c = k & 255;
    owb_s[i] = (o < 27) ? f2bf(s_off_w[(size_t)o * 2304 + c * 9 + tap]) : (ushort)0;
    return;
  }
  i -= 73728;
  if (i < 589824) {
    const int o = i / 2304, k = i % 2304, tap = k >> 8, c = k & 255;
    Awb_t[i] = f2bf(t_dcn_w[(size_t)o * 2304 + c * 9 + tap]);
    return;
  }
  i -= 589824;
  if (i < 589824) {
    const int o = i / 2304, k = i % 2304, tap = k >> 8, c = k & 255;
    Awb_s[i] = f2bf(s_dcn_w[(size_t)o * 2304 + c * 9 + tap]);
  }
}

// ---------------------------------------------------------------------------
// conv1x1 (fp32): merged q|k projection (OC=64)
// ---------------------------------------------------------------------------
__global__ __launch_bounds__(256) void conv1x1_kernel(
    const float* __restrict__ x, const float* __restrict__ w,
    const float* __restrict__ bias, float* __restrict__ out,
    int C, int N, int OC) {
  __shared__ float As[64][17];
  __shared__ float Bs[16][64];
  const int b = blockIdx.z;
  const int m0 = blockIdx.y * 64, n0 = blockIdx.x * 64;
  const float* xb = x + (size_t)b * C * N;
  const int tid = threadIdx.x;
  const int tr = tid >> 4, tc = tid & 15;
  float acc[4][4] = {};
  for (int k0 = 0; k0 < C; k0 += 16) {
    for (int i = tid; i < 64 * 16; i += 256) {
      int m = i >> 4, kk = i & 15;
      int gm = m0 + m;
      As[m][kk] = (gm < OC) ? w[(size_t)gm * C + k0 + kk] : 0.f;
    }
    for (int i = tid; i < 16 * 64; i += 256) {
      int kk = i >> 6, n = i & 63;
      int gn = n0 + n;
      Bs[kk][n] = (gn < N) ? xb[(size_t)(k0 + kk) * N + gn] : 0.f;
    }
    __syncthreads();
#pragma unroll
    for (int kk = 0; kk < 16; ++kk) {
      float a[4], bb[4];
#pragma unroll
      for (int i = 0; i < 4; i++) a[i] = As[tr * 4 + i][kk];
#pragma unroll
      for (int j = 0; j < 4; j++) bb[j] = Bs[kk][tc * 4 + j];
#pragma unroll
      for (int i = 0; i < 4; i++)
#pragma unroll
        for (int j = 0; j < 4; j++) acc[i][j] += a[i] * bb[j];
    }
    __syncthreads();
  }
  for (int i = 0; i < 4; i++) {
    int gm = m0 + tr * 4 + i;
    if (gm >= OC) continue;
    float bv = bias[gm];
    for (int j = 0; j < 4; j++) {
      int gn = n0 + tc * 4 + j;
      if (gn < N) out[((size_t)b * OC + gm) * N + gn] = acc[i][j] + bv;
    }
  }
}

// ---------------------------------------------------------------------------
// cast+transpose: x fp32 [C][N] -> xT bf16 [NR][C] (rows >= N zeroed)
// ---------------------------------------------------------------------------
__global__ __launch_bounds__(256) void cast_transpose_kernel(
    const float* __restrict__ x, ushort* __restrict__ xT, int C, int N,
    int NR) {
  __shared__ float T[64][65];
  const int b = blockIdx.z;
  const int n0 = blockIdx.x * 64, c0 = blockIdx.y * 64;
  const float* xb = x + (size_t)b * C * N;
  const int tid = threadIdx.x;
  for (int u = tid; u < 4096; u += 256) {
    const int cc = u >> 6, nn = u & 63;
    const int gn = n0 + nn;
    T[cc][nn] = (gn < N) ? xb[(size_t)(c0 + cc) * N + gn] : 0.f;
  }
  __syncthreads();
  ushort* ob = xT + (size_t)b * NR * C;
  for (int u = tid; u < 4096; u += 256) {
    const int nn = u >> 6, cc = u & 63;
    ob[(size_t)(n0 + nn) * C + c0 + cc] = f2bf(T[cc][nn]);
  }
}

// ---------------------------------------------------------------------------
// cast with col pad: x fp32 [B][C][N] -> xbf bf16 [B][C][Np] (pads zero)
// ---------------------------------------------------------------------------
__global__ __launch_bounds__(256) void cast_pad_kernel(
    const float* __restrict__ x, ushort* __restrict__ xbf, int C, int N,
    int Np, int total) {
  const int i = blockIdx.x * 256 + threadIdx.x;
  if (i >= total) return;
  const int np = i % Np;
  const int c = (i / Np) % C;
  const int b = i / (Np * C);
  xbf[i] = (np < N) ? f2bf(x[((size_t)b * C + c) * N + np]) : (ushort)0;
}

// ---------------------------------------------------------------------------
// Mcomb = bf16(w1*Aown + w2*Aoth)
// ---------------------------------------------------------------------------
__global__ __launch_bounds__(256) void mcomb_kernel(
    const float* __restrict__ Ao, const float* __restrict__ Ax,
    const float* __restrict__ w1p, const float* __restrict__ w2p,
    ushort* __restrict__ out, int total) {
  const int i = blockIdx.x * 256 + threadIdx.x;
  if (i < total) out[i] = f2bf((*w1p) * Ao[i] + (*w2p) * Ax[i]);
}

// ---------------------------------------------------------------------------
// generic bf16 GEMM: out[m][n] = sum_k A[m][k] * Bt[n][k], M=256.
// EPI 0: outBf[b][m][Np] = bf16(acc+bias[m])   EPI 1: += and xsT  EPI 2: =
// ---------------------------------------------------------------------------
template <int MS, int NW, int EPI>
__global__ __launch_bounds__(NW * 64) void gemm_abf_kernel(
    const ushort* __restrict__ A, int aPerBatch,
    const ushort* __restrict__ Bt, const float* __restrict__ bias,
    ushort* __restrict__ outBf, float* __restrict__ outF,
    ushort* __restrict__ xsT, int N, int Np, int NR, int Kp) {
  constexpr int CM = 256;
  constexpr int BM = CM / MS;
  constexpr int WM = BM / 64;
  constexpr int WN = NW / WM;
  constexpr int NF = 4 / WN;
  __shared__ ushort Asm[BM][40];
  __shared__ ushort Bsm[64][40];
  int bx, by, bz;
  xcd_remap(bx, by, bz);
  const int n0 = bx * 64, m0 = by * BM, b = bz;
  const ushort* Ab = A + (size_t)(aPerBatch ? b : 0) * CM * Kp;
  const ushort* Bb = Bt + (size_t)b * NR * Kp;
  const int tid = threadIdx.x, lane = tid & 63, w = tid >> 6;
  const int wr = w / WN, wc = w % WN;
  f32x4 acc[4][NF];
#pragma unroll
  for (int i = 0; i < 4; i++)
#pragma unroll
    for (int j = 0; j < NF; j++) acc[i][j] = (f32x4){0.f, 0.f, 0.f, 0.f};
  for (int k0 = 0; k0 < Kp; k0 += 32) {
    for (int u = tid; u < BM * 4; u += NW * 64) {
      const int row = u >> 2, seg = u & 3;
      *reinterpret_cast<uint4*>(&Asm[row][seg * 8]) =
          *reinterpret_cast<const uint4*>(&Ab[(size_t)(m0 + row) * Kp + k0 + seg * 8]);
    }
    for (int u = tid; u < 64 * 4; u += NW * 64) {
      const int row = u >> 2, seg = u & 3;
      *reinterpret_cast<uint4*>(&Bsm[row][seg * 8]) =
          *reinterpret_cast<const uint4*>(&Bb[(size_t)(n0 + row) * Kp + k0 + seg * 8]);
    }
    __syncthreads();
    const int koff = (lane >> 4) * 8;
    bf16x8 af[4], bfr[NF];
#pragma unroll
    for (int mf = 0; mf < 4; mf++)
      af[mf] = *reinterpret_cast<const bf16x8*>(&Asm[wr * 64 + mf * 16 + (lane & 15)][koff]);
#pragma unroll
    for (int nf = 0; nf < NF; nf++)
      bfr[nf] = *reinterpret_cast<const bf16x8*>(&Bsm[wc * NF * 16 + nf * 16 + (lane & 15)][koff]);
#pragma unroll
    for (int mf = 0; mf < 4; mf++)
#pragma unroll
      for (int nf = 0; nf < NF; nf++)
        acc[mf][nf] = __builtin_amdgcn_mfma_f32_16x16x32_bf16(af[mf], bfr[nf], acc[mf][nf], 0, 0, 0);
    __syncthreads();
  }
#pragma unroll
  for (int mf = 0; mf < 4; mf++) {
    const int mbase = m0 + wr * 64 + mf * 16 + ((lane >> 4) * 4);
#pragma unroll
    for (int nf = 0; nf < NF; nf++) {
      const int gn = n0 + wc * NF * 16 + nf * 16 + (lane & 15);
      if (EPI == 0) {
#pragma unroll
        for (int rr = 0; rr < 4; rr++) {
          const int m = mbase + rr;
          if (gn < Np) {
            ushort v = (gn < N) ? f2bf(acc[mf][nf][rr] + bias[m]) : (ushort)0;
            outBf[((size_t)b * CM + m) * Np + gn] = v;
          }
        }
      } else if (EPI == 1) {
        if (gn < N) {
          float s[4];
#pragma unroll
          for (int rr = 0; rr < 4; rr++) {
            const size_t idx = ((size_t)b * CM + mbase + rr) * N + gn;
            s[rr] = outF[idx] + acc[mf][nf][rr];
            outF[idx] = s[rr];
          }
          uint lo = (uint)f2bf(s[0]) | ((uint)f2bf(s[1]) << 16);
          uint hi = (uint)f2bf(s[2]) | ((uint)f2bf(s[3]) << 16);
          *reinterpret_cast<uint2*>(&xsT[((size_t)b * NR + gn) * CM + mbase]) =
              make_uint2(lo, hi);
        }
      } else {
#pragma unroll
        for (int rr = 0; rr < 4; rr++) {
          if (gn < N)
            outF[((size_t)b * CM + mbase + rr) * N + gn] = acc[mf][nf][rr];
        }
      }
    }
  }
}

// ---------------------------------------------------------------------------
// energy via MFMA (K=32): S[b][n][m] = sum_q q[q][n]*k[q][m] -> bf16, padded
// ---------------------------------------------------------------------------
__global__ __launch_bounds__(256) void energy_mfma_kernel(
    const float* __restrict__ qg, const float* __restrict__ kg,
    ushort* __restrict__ Sbf, int N, int Np, int bstride) {
  __shared__ ushort Aq[64][40];
  __shared__ ushort Bk[64][40];
  int bx, by, bz;
  xcd_remap(bx, by, bz);
  const int m0 = bx * 64, n0 = by * 64, b = bz;
  const float* qb = qg + (size_t)b * bstride;
  const float* kb = kg + (size_t)b * bstride;
  const int tid = threadIdx.x, lane = tid & 63, w = tid >> 6;
  for (int u = tid; u < 2048; u += 256) {
    const int c = u >> 6, nn = u & 63;
    const int gn = n0 + nn, gm = m0 + nn;
    Aq[nn][c] = (gn < N) ? f2bf(qb[(size_t)c * N + gn]) : (ushort)0;
    Bk[nn][c] = (gm < N) ? f2bf(kb[(size_t)c * N + gm]) : (ushort)0;
  }
  __syncthreads();
  const int koff = (lane >> 4) * 8;
  const bf16x8 af = *reinterpret_cast<const bf16x8*>(&Aq[w * 16 + (lane & 15)][koff]);
  f32x4 acc[4];
#pragma unroll
  for (int j = 0; j < 4; j++) {
    const bf16x8 bf = *reinterpret_cast<const bf16x8*>(&Bk[j * 16 + (lane & 15)][koff]);
    acc[j] = __builtin_amdgcn_mfma_f32_16x16x32_bf16(af, bf, (f32x4){0.f, 0.f, 0.f, 0.f}, 0, 0, 0);
  }
#pragma unroll
  for (int j = 0; j < 4; j++) {
    const int m = m0 + j * 16 + (lane & 15);
    if (m >= Np) continue;
#pragma unroll
    for (int r = 0; r < 4; r++) {
      const int n = n0 + w * 16 + (lane >> 4) * 4 + r;
      if (n < N) Sbf[((size_t)b * N + n) * Np + m] = (m < N) ? f2bf(acc[j][r]) : (ushort)0;
    }
  }
}

// ---------------------------------------------------------------------------
// fp32 in-place row softmax of sign*r (channel attention)
// ---------------------------------------------------------------------------
__global__ __launch_bounds__(256) void softmax_rows_kernel(
    float* __restrict__ e, int N, float sign) {
  const size_t row = blockIdx.x;
  float* r = e + row * (size_t)N;
  const int tid = threadIdx.x;
  __shared__ float red[4];
  float mx = -1e30f;
  for (int i = tid; i < N; i += 256) mx = fmaxf(mx, sign * r[i]);
#pragma unroll
  for (int off = 32; off; off >>= 1) mx = fmaxf(mx, __shfl_xor(mx, off, 64));
  if ((tid & 63) == 0) red[tid >> 6] = mx;
  __syncthreads();
  if (tid == 0) {
    float m2 = red[0];
    for (int i = 1; i < 4; i++) m2 = fmaxf(m2, red[i]);
    red[0] = m2;
  }
  __syncthreads();
  mx = red[0];
  __syncthreads();
  float s = 0.f;
  for (int i = tid; i < N; i += 256) {
    float v = __expf(sign * r[i] - mx);
    r[i] = v;
    s += v;
  }
#pragma unroll
  for (int off = 32; off; off >>= 1) s += __shfl_xor(s, off, 64);
  if ((tid & 63) == 0) red[tid >> 6] = s;
  __syncthreads();
  if (tid == 0) {
    float t = 0.f;
    for (int i = 0; i < 4; i++) t += red[i];
    red[0] = t;
  }
  __syncthreads();
  const float inv = 1.f / red[0];
  for (int i = tid; i < N; i += 256) r[i] *= inv;
}

// ---------------------------------------------------------------------------
// bf16 in-place row softmax (spatial attention scores)
// ---------------------------------------------------------------------------
__global__ __launch_bounds__(256) void softmax_bf16_kernel(
    ushort* __restrict__ Sbf, int N, int Np) {
  __shared__ float buf[992];
  __shared__ float red[4];
  const size_t row = blockIdx.x;
  ushort* r = Sbf + row * (size_t)Np;
  const int tid = threadIdx.x;
  float mx = -1e30f;
  for (int i = tid; i < N; i += 256) {
    float f = bf2f(r[i]);
    buf[i] = f;
    mx = fmaxf(mx, f);
  }
#pragma unroll
  for (int off = 32; off; off >>= 1) mx = fmaxf(mx, __shfl_xor(mx, off, 64));
  if ((tid & 63) == 0) red[tid >> 6] = mx;
  __syncthreads();
  if (tid == 0) {
    float m2 = red[0];
    for (int i = 1; i < 4; i++) m2 = fmaxf(m2, red[i]);
    red[0] = m2;
  }
  __syncthreads();
  mx = red[0];
  __syncthreads();
  float s = 0.f;
  for (int i = tid; i < N; i += 256) {
    float v = __expf(buf[i] - mx);
    buf[i] = v;
    s += v;
  }
#pragma unroll
  for (int off = 32; off; off >>= 1) s += __shfl_xor(s, off, 64);
  if ((tid & 63) == 0) red[tid >> 6] = s;
  __syncthreads();
  if (tid == 0) {
    float t = 0.f;
    for (int i = 0; i < 4; i++) t += red[i];
    red[0] = t;
  }
  __syncthreads();
  const float inv = 1.f / red[0];
  for (int i = tid; i < N; i += 256) r[i] = f2bf(buf[i] * inv);
}

// ---------------------------------------------------------------------------
// PV via MFMA: xsum = x + g * v @ A^T, XCD-swizzled
// ---------------------------------------------------------------------------
template <int MS, int NW>
__global__ __launch_bounds__(NW * 64) void pv_mfma_kernel(
    const ushort* __restrict__ vbf, const ushort* __restrict__ Abf,
    const float* __restrict__ x, const float* __restrict__ gp,
    float* __restrict__ xsum, int N, int Np) {
  constexpr int C = 256;
  constexpr int BM = C / MS;
  constexpr int WM = BM / 64;
  constexpr int WN = NW / WM;
  constexpr int NF = 4 / WN;
  __shared__ ushort Asm[BM][40];
  __shared__ ushort Bsm[64][40];
  int bx, by, bz;
  xcd_remap(bx, by, bz);
  const int n0 = bx * 64, m0 = by * BM, b = bz;
  const int tid = threadIdx.x, lane = tid & 63, w = tid >> 6;
  const int wr = w / WN, wc = w % WN;
  const ushort* vb = vbf + (size_t)b * C * Np;
  const ushort* Ab = Abf + (size_t)b * (size_t)N * Np;
  f32x4 acc[4][NF];
#pragma unroll
  for (int i = 0; i < 4; i++)
#pragma unroll
    for (int j = 0; j < NF; j++) acc[i][j] = (f32x4){0.f, 0.f, 0.f, 0.f};
  for (int k0 = 0; k0 < Np; k0 += 32) {
    for (int u = tid; u < BM * 4; u += NW * 64) {
      const int row = u >> 2, seg = u & 3;
      *reinterpret_cast<uint4*>(&Asm[row][seg * 8]) =
          *reinterpret_cast<const uint4*>(&vb[(size_t)(m0 + row) * Np + k0 + seg * 8]);
    }
    for (int u = tid; u < 64 * 4; u += NW * 64) {
      const int row = u >> 2, seg = u & 3;
      const int gn = n0 + row;
      uint4 val;
      if (gn < N)
        val = *reinterpret_cast<const uint4*>(&Ab[(size_t)gn * Np + k0 + seg * 8]);
      else
        val = make_uint4(0, 0, 0, 0);
      *reinterpret_cast<uint4*>(&Bsm[row][seg * 8]) = val;
    }
    __syncthreads();
    const int koff = (lane >> 4) * 8;
    bf16x8 af[4], bfr[NF];
#pragma unroll
    for (int mf = 0; mf < 4; mf++)
      af[mf] = *reinterpret_cast<const bf16x8*>(&Asm[wr * 64 + mf * 16 + (lane & 15)][koff]);
#pragma unroll
    for (int nf = 0; nf < NF; nf++)
      bfr[nf] = *reinterpret_cast<const bf16x8*>(&Bsm[wc * NF * 16 + nf * 16 + (lane & 15)][koff]);
#pragma unroll
    for (int mf = 0; mf < 4; mf++)
#pragma unroll
      for (int nf = 0; nf < NF; nf++)
        acc[mf][nf] = __builtin_amdgcn_mfma_f32_16x16x32_bf16(af[mf], bfr[nf], acc[mf][nf], 0, 0, 0);
    __syncthreads();
  }
  const float g = *gp;
#pragma unroll
  for (int mf = 0; mf < 4; mf++) {
    const int mbase = m0 + wr * 64 + mf * 16 + ((lane >> 4) * 4);
#pragma unroll
    for (int nf = 0; nf < NF; nf++) {
      const int gn = n0 + wc * NF * 16 + nf * 16 + (lane & 15);
      if (gn < N) {
#pragma unroll
        for (int rr = 0; rr < 4; rr++) {
          const size_t idx = ((size_t)b * C + mbase + rr) * N + gn;
          xsum[idx] = x[idx] + g * acc[mf][nf][rr];
        }
      }
    }
  }
}

// ---------------------------------------------------------------------------
// offconv via MFMA on xsT (shifted-window GEMM). r9: BK=128 (2 halves/tap),
// 18 staging steps instead of 36.
// ---------------------------------------------------------------------------
__global__ __launch_bounds__(256) void offconv_mfma_kernel(
    const ushort* __restrict__ xsT, const ushort* __restrict__ owb,
    const float* __restrict__ ob, float* __restrict__ om,
    int H, int Wd, int N, int NR) {
  __shared__ ushort Asm[32][136];
  __shared__ ushort Bsm[64][136];
  __shared__ int qsrc[64];
  int bx, by, bz;
  xcd_remap(bx, by, bz);
  const int n0 = bx * 64, b = bz;
  const int tid = threadIdx.x, lane = tid & 63, w = tid >> 6;
  const ushort* xb = xsT + (size_t)b * NR * 256;
  f32x4 acc[2];
  acc[0] = (f32x4){0.f, 0.f, 0.f, 0.f};
  acc[1] = (f32x4){0.f, 0.f, 0.f, 0.f};
  for (int tap = 0; tap < 9; ++tap) {
    const int dy = tap / 3 - 1, dx = tap - (tap / 3) * 3 - 1;
    if (tid < 64) {
      const int p = n0 + tid;
      int q = -1;
      if (p < N) {
        const int h = p / Wd, ww = p - (p / Wd) * Wd;
        const int yy = h + dy, xx = ww + dx;
        if (yy >= 0 && yy < H && xx >= 0 && xx < Wd) q = yy * Wd + xx;
      }
      qsrc[tid] = q;
    }
    __syncthreads();
#pragma unroll
    for (int half = 0; half < 2; ++half) {
      const int k0 = tap * 256 + half * 128;
      // A: 32 rows x 16 segs = 512 uint4 (2/thread)
      for (int u = tid; u < 512; u += 256) {
        const int row = u >> 4, seg = u & 15;
        *reinterpret_cast<uint4*>(&Asm[row][seg * 8]) =
            *reinterpret_cast<const uint4*>(&owb[(size_t)row * 2304 + k0 + seg * 8]);
      }
      // B: 64 rows x 16 segs = 1024 uint4 (4/thread)
      for (int u = tid; u < 1024; u += 256) {
        const int row = u >> 4, seg = u & 15;
        const int q = qsrc[row];
        uint4 val = make_uint4(0, 0, 0, 0);
        if (q >= 0)
          val = *reinterpret_cast<const uint4*>(&xb[(size_t)q * 256 + half * 128 + seg * 8]);
        *reinterpret_cast<uint4*>(&Bsm[row][seg * 8]) = val;
      }
      __syncthreads();
#pragma unroll
      for (int sub = 0; sub < 4; ++sub) {
        const int koff = sub * 32 + (lane >> 4) * 8;
        const bf16x8 b0 = *reinterpret_cast<const bf16x8*>(&Bsm[w * 16 + (lane & 15)][koff]);
#pragma unroll
        for (int mf = 0; mf < 2; ++mf) {
          const bf16x8 a0 = *reinterpret_cast<const bf16x8*>(&Asm[mf * 16 + (lane & 15)][koff]);
          acc[mf] = __builtin_amdgcn_mfma_f32_16x16x32_bf16(a0, b0, acc[mf], 0, 0, 0);
        }
      }
      __syncthreads();
    }
  }
#pragma unroll
  for (int mf = 0; mf < 2; ++mf) {
#pragma unroll
    for (int r = 0; r < 4; ++r) {
      const int o = mf * 16 + (lane >> 4) * 4 + r;
      const int n = n0 + w * 16 + (lane & 15);
      if (o < 27 && n < N)
        om[((size_t)b * 27 + o) * N + n] = acc[mf][r] + ob[o];
    }
  }
}

// ---------------------------------------------------------------------------
// packed bilinear gather table: uint4 = {q00, w00|w01, w10|w11, 0}
// ---------------------------------------------------------------------------
__global__ __launch_bounds__(256) void prep_offsets_kernel(
    const float* __restrict__ om, uint4* __restrict__ prep, int B, int H,
    int Wd) {
  const int N = H * Wd;
  const int i = blockIdx.x * 256 + threadIdx.x;
  if (i >= B * 9 * N) return;
  const int p = i % N;
  const int k = (i / N) % 9;
  const int b = i / (9 * N);
  const float* omb = om + (size_t)b * 27 * N;
  const float offy = omb[(size_t)k * N + p];
  const float offx = omb[(size_t)(9 + k) * N + p];
  const float mraw = omb[(size_t)(18 + k) * N + p];
  const float mval = 1.f / (1.f + __expf(-mraw));
  const int ky = k / 3, kx = k - (k / 3) * 3;
  const int h = p / Wd, w = p - (p / Wd) * Wd;
  const float py = offy + (float)(h + ky - 1);
  const float px = offx + (float)(w + kx - 1);
  const float y0f = floorf(py), x0f = floorf(px);
  const float wy = py - y0f, wx = px - x0f;
  const int y0 = (int)y0f, x0 = (int)x0f;
  const int ys0 = min(max(y0, 0), H - 2);
  const int xs0 = min(max(x0, 0), Wd - 2);
  const float wr0 = (ys0 == y0) ? (1.f - wy) : ((ys0 == y0 + 1) ? wy : 0.f);
  const float wr1 = (ys0 + 1 == y0) ? (1.f - wy) : ((ys0 + 1 == y0 + 1) ? wy : 0.f);
  const float wc0 = (xs0 == x0) ? (1.f - wx) : ((xs0 == x0 + 1) ? wx : 0.f);
  const float wc1 = (xs0 + 1 == x0) ? (1.f - wx) : ((xs0 + 1 == x0 + 1) ? wx : 0.f);
  const float w00 = wr0 * wc0 * mval, w01 = wr0 * wc1 * mval;
  const float w10 = wr1 * wc0 * mval, w11 = wr1 * wc1 * mval;
  uint4 pk;
  pk.x = (uint)(ys0 * Wd + xs0);
  pk.y = (uint)f2bf(w00) | ((uint)f2bf(w01) << 16);
  pk.z = (uint)f2bf(w10) | ((uint)f2bf(w11) << 16);
  pk.w = 0;
  prep[i] = pk;
}

// ---------------------------------------------------------------------------
// DCN via MFMA, gather from bf16 xsT [p][c]. r9: BK=64 (36 steps, half the
// barriers of r8), 8 MFMA/wave/step. BM=256/MS, BN=32, 8 waves (512 thr).
// grid (ceil(N/32), MS, B).
// ---------------------------------------------------------------------------
template <int MS>
__global__ __launch_bounds__(512) void dcn_mfma_kernel(
    const ushort* __restrict__ xsT, const uint4* __restrict__ prep,
    const ushort* __restrict__ Awb, const float* __restrict__ bias,
    float* __restrict__ out, int N, int Wd, int NR) {
  constexpr int C = 256, KTOT = 2304;
  constexpr int BM = C / MS;   // 256 or 128
  constexpr int MF = BM / 64;  // fragments per wave
  __shared__ ushort Asm[BM][72];
  __shared__ ushort Bsm[32][72];
  __shared__ int sq[32];
  __shared__ float sw0[32], sw1[32], sw2[32], sw3[32];
  int bx, by, bz;
  xcd_remap(bx, by, bz);
  const int n0 = bx * 32, m0 = by * BM, b = bz;
  const int tid = threadIdx.x, lane = tid & 63, w = tid >> 6;
  const int wr = w >> 1, wc = w & 1;  // 4 waves in M, 2 in N
  const ushort* xb = xsT + (size_t)b * NR * C;
  f32x4 acc[MF];
#pragma unroll
  for (int i = 0; i < MF; i++) acc[i] = (f32x4){0.f, 0.f, 0.f, 0.f};
  for (int k0 = 0; k0 < KTOT; k0 += 64) {
    const int kpos = k0 >> 8, c0 = k0 & 255;
    if (c0 == 0) {
      if (tid < 32) {
        const int p = n0 + tid;
        if (p < N) {
          const uint4 pk = prep[((size_t)b * 9 + kpos) * N + p];
          sq[tid] = (int)pk.x * C;
          sw0[tid] = bf2f((ushort)(pk.y & 0xffff));
          sw1[tid] = bf2f((ushort)(pk.y >> 16));
          sw2[tid] = bf2f((ushort)(pk.z & 0xffff));
          sw3[tid] = bf2f((ushort)(pk.z >> 16));
        } else {
          sq[tid] = 0;
          sw0[tid] = sw1[tid] = sw2[tid] = sw3[tid] = 0.f;
        }
      }
      __syncthreads();
    }
    // A-stage: BM rows x 64 k = BM*8 uint4
    for (int u = tid; u < BM * 8; u += 512) {
      const int row = u >> 3, seg = u & 7;
      *reinterpret_cast<uint4*>(&Asm[row][seg * 8]) =
          *reinterpret_cast<const uint4*>(&Awb[(size_t)(m0 + row) * KTOT + k0 + seg * 8]);
    }
    // B-stage: 32 cols x 32 channel-pairs = 1024 units (2/thread)
    for (int u = tid; u < 1024; u += 512) {
      const int n = u >> 5, pr = u & 31;
      const int kk = pr * 2;
      const ushort* p0 = xb + sq[n] + c0 + kk;
      const uint a00 = *reinterpret_cast<const uint*>(p0);
      const uint a01 = *reinterpret_cast<const uint*>(p0 + C);
      const uint a10 = *reinterpret_cast<const uint*>(p0 + (size_t)Wd * C);
      const uint a11 = *reinterpret_cast<const uint*>(p0 + (size_t)(Wd + 1) * C);
      const float w00 = sw0[n], w01 = sw1[n], w10 = sw2[n], w11 = sw3[n];
      const float vlo = w00 * __uint_as_float(a00 << 16) +
                        w01 * __uint_as_float(a01 << 16) +
                        w10 * __uint_as_float(a10 << 16) +
                        w11 * __uint_as_float(a11 << 16);
      const float vhi = w00 * __uint_as_float(a00 & 0xffff0000u) +
                        w01 * __uint_as_float(a01 & 0xffff0000u) +
                        w10 * __uint_as_float(a10 & 0xffff0000u) +
                        w11 * __uint_as_float(a11 & 0xffff0000u);
      *reinterpret_cast<uint*>(&Bsm[n][kk]) =
          (uint)f2bf(vlo) | ((uint)f2bf(vhi) << 16);
    }
    __syncthreads();
#pragma unroll
    for (int sub = 0; sub < 2; ++sub) {
      const int koff = sub * 32 + (lane >> 4) * 8;
      const bf16x8 bf = *reinterpret_cast<const bf16x8*>(&Bsm[wc * 16 + (lane & 15)][koff]);
#pragma unroll
      for (int mf = 0; mf < MF; mf++) {
        const bf16x8 af = *reinterpret_cast<const bf16x8*>(
            &Asm[wr * (BM / 4) + mf * 16 + (lane & 15)][koff]);
        acc[mf] = __builtin_amdgcn_mfma_f32_16x16x32_bf16(af, bf, acc[mf], 0, 0, 0);
      }
    }
    __syncthreads();
  }
  const int gn = n0 + wc * 16 + (lane & 15);
#pragma unroll
  for (int mf = 0; mf < MF; mf++) {
    const int mbase = m0 + wr * (BM / 4) + mf * 16 + ((lane >> 4) * 4);
    if (gn < N) {
#pragma unroll
      for (int rr = 0; rr < 4; rr++)
        out[((size_t)b * C + mbase + rr) * N + gn] = acc[mf][rr] + bias[mbase + rr];
    }
  }
}

// ---------------------------------------------------------------------------
extern "C" void kernel_launch(void* const* d_in, const int* in_sizes, int n_in,
                              void* d_out, int out_size, void* d_ws, size_t ws_size,
                              hipStream_t stream) {
  const float* t_in = (const float*)d_in[0];
  const float* s_in = (const float*)d_in[1];
  const float* t_qw = (const float*)d_in[2];
  const float* t_qb = (const float*)d_in[3];
  const float* t_kw = (const float*)d_in[4];
  const float* t_kb = (const float*)d_in[5];
  const float* t_vw = (const float*)d_in[6];
  const float* t_vb = (const float*)d_in[7];
  const float* t_g = (const float*)d_in[8];
  const float* s_qw = (const float*)d_in[9];
  const float* s_qb = (const float*)d_in[10];
  const float* s_kw = (const float*)d_in[11];
  const float* s_kb = (const float*)d_in[12];
  const float* s_vw = (const float*)d_in[13];
  const float* s_vb = (const float*)d_in[14];
  const float* s_g = (const float*)d_in[15];
  const float* w_t_ch = (const float*)d_in[16];
  const float* w_s_ch = (const float*)d_in[17];
  const float* w_s2t = (const float*)d_in[18];
  const float* w_t2s = (const float*)d_in[19];
  const float* t_off_w = (const float*)d_in[20];
  const float* t_off_b = (const float*)d_in[21];
  const float* t_dcn_w = (const float*)d_in[22];
  const float* t_dcn_b = (const float*)d_in[23];
  const float* s_off_w = (const float*)d_in[24];
  const float* s_off_b = (const float*)d_in[25];
  const float* s_dcn_w = (const float*)d_in[26];
  const float* s_dcn_b = (const float*)d_in[27];
  (void)in_sizes; (void)n_in; (void)out_size; (void)ws_size;

  constexpr int Bn = 16, C = 256, QKd = 32;
  constexpr int HT = 15, WT = 15, NT = HT * WT;    // 225
  constexpr int HS = 31, WS2 = 31, NS = HS * WS2;  // 961
  constexpr int NpT = 256, NpS = 992;              // col pads (mult of 32)
  constexpr int NRT = 256, NRS = 1024;             // row pads (mult of 64)

  float* ws = (float*)d_ws;
  size_t off = 0;
  auto alloc = [&](size_t n) {
    n = (n + 3) & ~(size_t)3;
    float* p = ws + off; off += n; return p;
  };
  auto allocU = [&](size_t nu) { return (ushort*)alloc((nu + 1) / 2); };

  float* qk_t = alloc((size_t)Bn * 64 * NT);
  float* qk_s = alloc((size_t)Bn * 64 * NS);
  float* qkw_t = alloc((size_t)64 * C + 64);
  float* qkw_s = alloc((size_t)64 * C + 64);
  float* qkb_t = qkw_t + (size_t)64 * C;
  float* qkb_s = qkw_s + (size_t)64 * C;
  ushort* xT_t = allocU((size_t)Bn * NRT * C);
  ushort* xT_s = allocU((size_t)Bn * NRS * C);
  ushort* xbf_t = allocU((size_t)Bn * C * NpT);
  ushort* xbf_s = allocU((size_t)Bn * C * NpS);
  ushort* Wv_t = allocU((size_t)C * C);
  ushort* Wv_s = allocU((size_t)C * C);
  ushort* v_tbf = allocU((size_t)Bn * C * NpT);
  ushort* v_sbf = allocU((size_t)Bn * C * NpS);
  ushort* S_t = allocU((size_t)Bn * NT * NpT);
  ushort* S_s = allocU((size_t)Bn * NS * NpS);
  float* xt = alloc((size_t)Bn * C * NT);
  float* xs = alloc((size_t)Bn * C * NS);
  ushort* xsT_t = allocU((size_t)Bn * NRT * C);
  ushort* xsT_s = allocU((size_t)Bn * NRS * C);
  float* Atc = alloc((size_t)Bn * C * C);
  float* Asc = alloc((size_t)Bn * C * C);
  ushort* Mc_t = allocU((size_t)Bn * C * C);
  ushort* Mc_s = allocU((size_t)Bn * C * C);
  float* om_t = alloc((size_t)Bn * 27 * NT);
  float* om_s = alloc((size_t)Bn * 27 * NS);
  ushort* owb_t = allocU((size_t)32 * 2304);
  ushort* owb_s = allocU((size_t)32 * 2304);
  ushort* Awb_t = allocU((size_t)256 * 2304);
  ushort* Awb_s = allocU((size_t)256 * 2304);
  uint4* prep_t = (uint4*)alloc((size_t)Bn * 9 * NT * 4);
  uint4* prep_s = (uint4*)alloc((size_t)Bn * 9 * NS * 4);

  dim3 blk(256);

  // fused weight prep (replaces 8 launches)
  prep_weights_kernel<<<dim3((1491072 + 255) / 256), blk, 0, stream>>>(
      t_qw, t_qb, t_kw, t_kb, s_qw, s_qb, s_kw, s_kb, t_vw, s_vw,
      t_off_w, s_off_w, t_dcn_w, s_dcn_w,
      qkw_t, qkb_t, qkw_s, qkb_s, Wv_t, Wv_s, owb_t, owb_s, Awb_t, Awb_s);

  // merged q|k projections (fp32)
  conv1x1_kernel<<<dim3(4, 1, Bn), blk, 0, stream>>>(t_in, qkw_t, qkb_t, qk_t, C, NT, 64);
  conv1x1_kernel<<<dim3(16, 1, Bn), blk, 0, stream>>>(s_in, qkw_s, qkb_s, qk_s, C, NS, 64);

  // bf16 transposed inputs, padded casts
  cast_transpose_kernel<<<dim3(NRT / 64, 4, Bn), blk, 0, stream>>>(t_in, xT_t, C, NT, NRT);
  cast_transpose_kernel<<<dim3(NRS / 64, 4, Bn), blk, 0, stream>>>(s_in, xT_s, C, NS, NRS);
  cast_pad_kernel<<<dim3((Bn * C * NpT + 255) / 256), blk, 0, stream>>>(t_in, xbf_t, C, NT, NpT, Bn * C * NpT);
  cast_pad_kernel<<<dim3((Bn * C * NpS + 255) / 256), blk, 0, stream>>>(s_in, xbf_s, C, NS, NpS, Bn * C * NpS);

  // v projection via MFMA -> bf16 padded
  gemm_abf_kernel<4, 4, 0><<<dim3(NRT / 64, 4, Bn), blk, 0, stream>>>(
      Wv_t, 0, xT_t, t_vb, v_tbf, nullptr, nullptr, NT, NpT, NRT, C);
  gemm_abf_kernel<2, 4, 0><<<dim3(NRS / 64, 2, Bn), blk, 0, stream>>>(
      Wv_s, 0, xT_s, s_vb, v_sbf, nullptr, nullptr, NS, NpS, NRS, C);

  // spatial attention: energy (MFMA) -> softmax -> PV (MFMA)
  energy_mfma_kernel<<<dim3(NpT / 64, 4, Bn), blk, 0, stream>>>(qk_t, qk_t + 32 * NT, S_t, NT, NpT, 64 * NT);
  energy_mfma_kernel<<<dim3((NpS + 63) / 64, 16, Bn), blk, 0, stream>>>(qk_s, qk_s + 32 * NS, S_s, NS, NpS, 64 * NS);
  softmax_bf16_kernel<<<dim3(Bn * NT), blk, 0, stream>>>(S_t, NT, NpT);
  softmax_bf16_kernel<<<dim3(Bn * NS), blk, 0, stream>>>(S_s, NS, NpS);
  pv_mfma_kernel<4, 4><<<dim3(4, 4, Bn), blk, 0, stream>>>(v_tbf, S_t, t_in, t_g, xt, NT, NpT);
  pv_mfma_kernel<2, 4><<<dim3(16, 2, Bn), blk, 0, stream>>>(v_sbf, S_s, s_in, s_g, xs, NS, NpS);

  // channel attention: gram (MFMA) -> softmax -> combined-M GEMM
  gemm_abf_kernel<2, 4, 2><<<dim3(4, 2, Bn), blk, 0, stream>>>(
      xbf_t, 1, xbf_t, nullptr, nullptr, Atc, nullptr, C, C, C, NpT);
  gemm_abf_kernel<2, 4, 2><<<dim3(4, 2, Bn), blk, 0, stream>>>(
      xbf_s, 1, xbf_s, nullptr, nullptr, Asc, nullptr, C, C, C, NpS);
  softmax_rows_kernel<<<dim3(Bn * C), blk, 0, stream>>>(Atc, C, -1.f);
  softmax_rows_kernel<<<dim3(Bn * C), blk, 0, stream>>>(Asc, C, -1.f);
  mcomb_kernel<<<dim3((Bn * C * C + 255) / 256), blk, 0, stream>>>(Atc, Asc, w_t_ch, w_s2t, Mc_t, Bn * C * C);
  mcomb_kernel<<<dim3((Bn * C * C + 255) / 256), blk, 0, stream>>>(Asc, Atc, w_s_ch, w_t2s, Mc_s, Bn * C * C);
  gemm_abf_kernel<4, 4, 1><<<dim3(NRT / 64, 4, Bn), blk, 0, stream>>>(
      Mc_t, 1, xT_t, nullptr, nullptr, xt, xsT_t, NT, NpT, NRT, C);
  gemm_abf_kernel<2, 4, 1><<<dim3(NRS / 64, 2, Bn), blk, 0, stream>>>(
      Mc_s, 1, xT_s, nullptr, nullptr, xs, xsT_s, NS, NpS, NRS, C);

  // offsets via MFMA (shifted-window GEMM on xsumT)
  offconv_mfma_kernel<<<dim3(4, 1, Bn), blk, 0, stream>>>(xsT_t, owb_t, t_off_b, om_t, HT, WT, NT, NRT);
  offconv_mfma_kernel<<<dim3(16, 1, Bn), blk, 0, stream>>>(xsT_s, owb_s, s_off_b, om_s, HS, WS2, NS, NRS);

  // DCN prep
  prep_offsets_kernel<<<dim3((Bn * 9 * NT + 255) / 256), blk, 0, stream>>>(om_t, prep_t, Bn, HT, WT);
  prep_offsets_kernel<<<dim3((Bn * 9 * NS + 255) / 256), blk, 0, stream>>>(om_s, prep_s, Bn, HS, WS2);

  float* out_t = (float*)d_out;
  float* out_s = out_t + (size_t)Bn * C * NT;
  dcn_mfma_kernel<2><<<dim3(8, 2, Bn), dim3(512), 0, stream>>>(
      xsT_t, prep_t, Awb_t, t_dcn_b, out_t, NT, WT, NRT);
  dcn_mfma_kernel<1><<<dim3(32, 1, Bn), dim3(512), 0, stream>>>(
      xsT_s, prep_s, Awb_s, s_dcn_b, out_s, NS, WS2, NRS);
}

// Round 10
// 399.666 us; speedup vs baseline: 4.2905x; 1.4020x over previous
//
#include <hip/hip_runtime.h>
#include <hip/hip_bf16.h>
#include <cmath>

typedef __attribute__((ext_vector_type(8))) short bf16x8;
typedef __attribute__((ext_vector_type(4))) float f32x4;

__device__ inline ushort f2bf(float f) {
  __hip_bfloat16 h = __float2bfloat16(f);
  return *reinterpret_cast<ushort*>(&h);
}
__device__ inline float bf2f(ushort u) {
  return __uint_as_float((uint)u << 16);
}

// Fused-side decode with XCD-aware bijective chunking.
// 1D grid, gridDim.x = totalS + gxT*gyT*16 (must be %8==0).
// Blocks [0,totalS) -> s side, rest -> t side.
__device__ inline bool fdecode(int totalS, int gxS, int gyS, int gxT, int gyT,
                               int& bx, int& by, int& bz, bool& isT) {
  const int total = gridDim.x;
  const int id = blockIdx.x;
  int wid = (id & 7) * (total >> 3) + (id >> 3);
  const int totalT = gxT * gyT * 16;
  if (wid >= totalS + totalT) return false;
  isT = wid >= totalS;
  int lid = isT ? wid - totalS : wid;
  const int gx = isT ? gxT : gxS;
  const int gy = isT ? gyT : gyS;
  bx = lid % gx;
  lid /= gx;
  by = lid % gy;
  bz = lid / gy;
  return true;
}

// ---------------------------------------------------------------------------
// fused weight prep (replaces 8 launches)
// ---------------------------------------------------------------------------
__global__ __launch_bounds__(256) void prep_weights_kernel(
    const float* __restrict__ t_qw, const float* __restrict__ t_qb,
    const float* __restrict__ t_kw, const float* __restrict__ t_kb,
    const float* __restrict__ s_qw, const float* __restrict__ s_qb,
    const float* __restrict__ s_kw, const float* __restrict__ s_kb,
    const float* __restrict__ t_vw, const float* __restrict__ s_vw,
    const float* __restrict__ t_off_w, const float* __restrict__ s_off_w,
    const float* __restrict__ t_dcn_w, const float* __restrict__ s_dcn_w,
    float* __restrict__ qkw_t, float* __restrict__ qkb_t,
    float* __restrict__ qkw_s, float* __restrict__ qkb_s,
    ushort* __restrict__ Wv_t, ushort* __restrict__ Wv_s,
    ushort* __restrict__ owb_t, ushort* __restrict__ owb_s,
    ushort* __restrict__ Awb_t, ushort* __restrict__ Awb_s) {
  int i = blockIdx.x * 256 + threadIdx.x;
  if (i < 16448) {
    if (i < 8192) qkw_t[i] = t_qw[i];
    else if (i < 16384) qkw_t[i] = t_kw[i - 8192];
    else { int j = i - 16384; qkb_t[j] = (j < 32) ? t_qb[j] : t_kb[j - 32]; }
    return;
  }
  i -= 16448;
  if (i < 16448) {
    if (i < 8192) qkw_s[i] = s_qw[i];
    else if (i < 16384) qkw_s[i] = s_kw[i - 8192];
    else { int j = i - 16384; qkb_s[j] = (j < 32) ? s_qb[j] : s_kb[j - 32]; }
    return;
  }
  i -= 16448;
  if (i < 65536) { Wv_t[i] = f2bf(t_vw[i]); return; }
  i -= 65536;
  if (i < 65536) { Wv_s[i] = f2bf(s_vw[i]); return; }
  i -= 65536;
  if (i < 73728) {
    const int o = i / 2304, k = i % 2304, tap = k >> 8, c = k & 255;
    owb_t[i] = (o < 27) ? f2bf(t_off_w[(size_t)o * 2304 + c * 9 + tap]) : (ushort)0;
    return;
  }
  i -= 73728;
  if (i < 73728) {
    const int o = i / 2304, k = i % 2304, tap = k >> 8, c = k & 255;
    owb_s[i] = (o < 27) ? f2bf(s_off_w[(size_t)o * 2304 + c * 9 + tap]) : (ushort)0;
    return;
  }
  i -= 73728;
  if (i < 589824) {
    const int o = i / 2304, k = i % 2304, tap = k >> 8, c = k & 255;
    Awb_t[i] = f2bf(t_dcn_w[(size_t)o * 2304 + c * 9 + tap]);
    return;
  }
  i -= 589824;
  if (i < 589824) {
    const int o = i / 2304, k = i % 2304, tap = k >> 8, c = k & 255;
    Awb_s[i] = f2bf(s_dcn_w[(size_t)o * 2304 + c * 9 + tap]);
  }
}

// ---------------------------------------------------------------------------
// fused conv1x1 (fp32) q|k projection, OC=64. s: gx=16, t: gx=4; gy=1.
// ---------------------------------------------------------------------------
__global__ __launch_bounds__(256) void conv1x1_fused_kernel(
    const float* __restrict__ xS, const float* __restrict__ wS,
    const float* __restrict__ bS, float* __restrict__ oS, int NS_,
    const float* __restrict__ xT, const float* __restrict__ wT,
    const float* __restrict__ bT, float* __restrict__ oT, int NT_) {
  constexpr int C = 256, OC = 64;
  __shared__ float As[64][17];
  __shared__ float Bs[16][64];
  int bx, by, bz; bool isT;
  if (!fdecode(256, 16, 1, 4, 1, bx, by, bz, isT)) return;
  const float* x = isT ? xT : xS;
  const float* w = isT ? wT : wS;
  const float* bias = isT ? bT : bS;
  float* out = isT ? oT : oS;
  const int N = isT ? NT_ : NS_;
  const int b = bz;
  const int n0 = bx * 64;
  const float* xb = x + (size_t)b * C * N;
  const int tid = threadIdx.x;
  const int tr = tid >> 4, tc = tid & 15;
  float acc[4][4] = {};
  for (int k0 = 0; k0 < C; k0 += 16) {
    for (int i = tid; i < 64 * 16; i += 256) {
      int m = i >> 4, kk = i & 15;
      As[m][kk] = w[(size_t)m * C + k0 + kk];
    }
    for (int i = tid; i < 16 * 64; i += 256) {
      int kk = i >> 6, n = i & 63;
      int gn = n0 + n;
      Bs[kk][n] = (gn < N) ? xb[(size_t)(k0 + kk) * N + gn] : 0.f;
    }
    __syncthreads();
#pragma unroll
    for (int kk = 0; kk < 16; ++kk) {
      float a[4], bb[4];
#pragma unroll
      for (int i = 0; i < 4; i++) a[i] = As[tr * 4 + i][kk];
#pragma unroll
      for (int j = 0; j < 4; j++) bb[j] = Bs[kk][tc * 4 + j];
#pragma unroll
      for (int i = 0; i < 4; i++)
#pragma unroll
        for (int j = 0; j < 4; j++) acc[i][j] += a[i] * bb[j];
    }
    __syncthreads();
  }
  for (int i = 0; i < 4; i++) {
    int gm = tr * 4 + i;
    if (gm >= OC) continue;
    float bv = bias[gm];
    for (int j = 0; j < 4; j++) {
      int gn = n0 + tc * 4 + j;
      if (gn < N) out[((size_t)b * OC + gm) * N + gn] = acc[i][j] + bv;
    }
  }
}

// ---------------------------------------------------------------------------
// fused cast+transpose: x fp32 [C][N] -> xT bf16 [NR][C]. s gx=16,gy=4; t 4,4
// ---------------------------------------------------------------------------
__global__ __launch_bounds__(256) void cast_transpose_fused_kernel(
    const float* __restrict__ xS, ushort* __restrict__ oS, int NS_, int NRS_,
    const float* __restrict__ xT, ushort* __restrict__ oT, int NT_, int NRT_) {
  constexpr int C = 256;
  __shared__ float T[64][65];
  int bx, by, bz; bool isT;
  if (!fdecode(1024, 16, 4, 4, 4, bx, by, bz, isT)) return;
  const float* x = isT ? xT : xS;
  ushort* xTo = isT ? oT : oS;
  const int N = isT ? NT_ : NS_;
  const int NR = isT ? NRT_ : NRS_;
  const int b = bz;
  const int n0 = bx * 64, c0 = by * 64;
  const float* xb = x + (size_t)b * C * N;
  const int tid = threadIdx.x;
  for (int u = tid; u < 4096; u += 256) {
    const int cc = u >> 6, nn = u & 63;
    const int gn = n0 + nn;
    T[cc][nn] = (gn < N) ? xb[(size_t)(c0 + cc) * N + gn] : 0.f;
  }
  __syncthreads();
  ushort* ob = xTo + (size_t)b * NR * C;
  for (int u = tid; u < 4096; u += 256) {
    const int nn = u >> 6, cc = u & 63;
    ob[(size_t)(n0 + nn) * C + c0 + cc] = f2bf(T[cc][nn]);
  }
}

// ---------------------------------------------------------------------------
// fused cast+pad (both sides, 1D streaming)
// ---------------------------------------------------------------------------
__global__ __launch_bounds__(256) void cast_pad_fused_kernel(
    const float* __restrict__ xS, ushort* __restrict__ oS, int NS_, int NpS_,
    int totS,
    const float* __restrict__ xT, ushort* __restrict__ oT, int NT_, int NpT_,
    int totT) {
  constexpr int C = 256;
  int i = blockIdx.x * 256 + threadIdx.x;
  if (i < totS) {
    const int np = i % NpS_;
    const int c = (i / NpS_) % C;
    const int b = i / (NpS_ * C);
    oS[i] = (np < NS_) ? f2bf(xS[((size_t)b * C + c) * NS_ + np]) : (ushort)0;
    return;
  }
  i -= totS;
  if (i < totT) {
    const int np = i % NpT_;
    const int c = (i / NpT_) % C;
    const int b = i / (NpT_ * C);
    oT[i] = (np < NT_) ? f2bf(xT[((size_t)b * C + c) * NT_ + np]) : (ushort)0;
  }
}

// ---------------------------------------------------------------------------
// fused Mcomb: Mc_t = bf16(w_t_ch*Atc + w_s2t*Asc); Mc_s = bf16(w_s_ch*Asc + w_t2s*Atc)
// ---------------------------------------------------------------------------
__global__ __launch_bounds__(256) void mcomb_fused_kernel(
    const float* __restrict__ Atc, const float* __restrict__ Asc,
    const float* __restrict__ w_t_ch, const float* __restrict__ w_s2t,
    const float* __restrict__ w_s_ch, const float* __restrict__ w_t2s,
    ushort* __restrict__ Mc_t, ushort* __restrict__ Mc_s, int n) {
  const int i = blockIdx.x * 256 + threadIdx.x;
  if (i < n) {
    Mc_t[i] = f2bf(w_t_ch[0] * Atc[i] + w_s2t[0] * Asc[i]);
  } else if (i < 2 * n) {
    const int j = i - n;
    Mc_s[j] = f2bf(w_s_ch[0] * Asc[j] + w_t2s[0] * Atc[j]);
  }
}

// ---------------------------------------------------------------------------
// fused generic bf16 GEMM, BM=128 (MS=2), NW=4. s gx at gy=2; t gx at gy=2.
// EPI 0: outBf = bf16(acc+bias) padded   EPI 1: outF += acc; xsT=bf16(sum)
// EPI 2: outF = acc
// ---------------------------------------------------------------------------
template <int EPI>
__global__ __launch_bounds__(256) void gemm_fused_kernel(
    const ushort* __restrict__ AS, int aPerB_S, const ushort* __restrict__ BtS,
    const float* __restrict__ biasS, ushort* __restrict__ outBfS,
    float* __restrict__ outFS, ushort* __restrict__ xsTS, int NS_, int NpS_,
    int NRS_, int KpS_,
    const ushort* __restrict__ AT, int aPerB_T, const ushort* __restrict__ BtT,
    const float* __restrict__ biasT, ushort* __restrict__ outBfT,
    float* __restrict__ outFT, ushort* __restrict__ xsTT, int NT_, int NpT_,
    int NRT_, int KpT_, int totalS, int gxS, int gxT) {
  constexpr int CM = 256, BM = 128, NW = 4, NF = 2, WN = 2;
  __shared__ ushort Asm[BM][40];
  __shared__ ushort Bsm[64][40];
  int bx, by, bz; bool isT;
  if (!fdecode(totalS, gxS, 2, gxT, 2, bx, by, bz, isT)) return;
  const ushort* A = isT ? AT : AS;
  const ushort* Bt = isT ? BtT : BtS;
  const float* bias = isT ? biasT : biasS;
  ushort* outBf = isT ? outBfT : outBfS;
  float* outF = isT ? outFT : outFS;
  ushort* xsT = isT ? xsTT : xsTS;
  const int aPerBatch = isT ? aPerB_T : aPerB_S;
  const int N = isT ? NT_ : NS_, Np = isT ? NpT_ : NpS_;
  const int NR = isT ? NRT_ : NRS_, Kp = isT ? KpT_ : KpS_;
  const int n0 = bx * 64, m0 = by * BM, b = bz;
  const ushort* Ab = A + (size_t)(aPerBatch ? b : 0) * CM * Kp;
  const ushort* Bb = Bt + (size_t)b * NR * Kp;
  const int tid = threadIdx.x, lane = tid & 63, w = tid >> 6;
  const int wr = w / WN, wc = w % WN;
  f32x4 acc[4][NF];
#pragma unroll
  for (int i = 0; i < 4; i++)
#pragma unroll
    for (int j = 0; j < NF; j++) acc[i][j] = (f32x4){0.f, 0.f, 0.f, 0.f};
  for (int k0 = 0; k0 < Kp; k0 += 32) {
    for (int u = tid; u < BM * 4; u += NW * 64) {
      const int row = u >> 2, seg = u & 3;
      *reinterpret_cast<uint4*>(&Asm[row][seg * 8]) =
          *reinterpret_cast<const uint4*>(&Ab[(size_t)(m0 + row) * Kp + k0 + seg * 8]);
    }
    for (int u = tid; u < 64 * 4; u += NW * 64) {
      const int row = u >> 2, seg = u & 3;
      *reinterpret_cast<uint4*>(&Bsm[row][seg * 8]) =
          *reinterpret_cast<const uint4*>(&Bb[(size_t)(n0 + row) * Kp + k0 + seg * 8]);
    }
    __syncthreads();
    const int koff = (lane >> 4) * 8;
    bf16x8 af[4], bfr[NF];
#pragma unroll
    for (int mf = 0; mf < 4; mf++)
      af[mf] = *reinterpret_cast<const bf16x8*>(&Asm[wr * 64 + mf * 16 + (lane & 15)][koff]);
#pragma unroll
    for (int nf = 0; nf < NF; nf++)
      bfr[nf] = *reinterpret_cast<const bf16x8*>(&Bsm[wc * NF * 16 + nf * 16 + (lane & 15)][koff]);
#pragma unroll
    for (int mf = 0; mf < 4; mf++)
#pragma unroll
      for (int nf = 0; nf < NF; nf++)
        acc[mf][nf] = __builtin_amdgcn_mfma_f32_16x16x32_bf16(af[mf], bfr[nf], acc[mf][nf], 0, 0, 0);
    __syncthreads();
  }
#pragma unroll
  for (int mf = 0; mf < 4; mf++) {
    const int mbase = m0 + wr * 64 + mf * 16 + ((lane >> 4) * 4);
#pragma unroll
    for (int nf = 0; nf < NF; nf++) {
      const int gn = n0 + wc * NF * 16 + nf * 16 + (lane & 15);
      if (EPI == 0) {
#pragma unroll
        for (int rr = 0; rr < 4; rr++) {
          const int m = mbase + rr;
          if (gn < Np) {
            ushort v = (gn < N) ? f2bf(acc[mf][nf][rr] + bias[m]) : (ushort)0;
            outBf[((size_t)b * CM + m) * Np + gn] = v;
          }
        }
      } else if (EPI == 1) {
        if (gn < N) {
          float s[4];
#pragma unroll
          for (int rr = 0; rr < 4; rr++) {
            const size_t idx = ((size_t)b * CM + mbase + rr) * N + gn;
            s[rr] = outF[idx] + acc[mf][nf][rr];
            outF[idx] = s[rr];
          }
          uint lo = (uint)f2bf(s[0]) | ((uint)f2bf(s[1]) << 16);
          uint hi = (uint)f2bf(s[2]) | ((uint)f2bf(s[3]) << 16);
          *reinterpret_cast<uint2*>(&xsT[((size_t)b * NR + gn) * CM + mbase]) =
              make_uint2(lo, hi);
        }
      } else {
#pragma unroll
        for (int rr = 0; rr < 4; rr++) {
          if (gn < N)
            outF[((size_t)b * CM + mbase + rr) * N + gn] = acc[mf][nf][rr];
        }
      }
    }
  }
}

// ---------------------------------------------------------------------------
// fused energy (K=32): s gx=16,gy=16; t gx=4,gy=4
// ---------------------------------------------------------------------------
__global__ __launch_bounds__(256) void energy_fused_kernel(
    const float* __restrict__ qkS, ushort* __restrict__ SS, int NS_, int NpS_,
    const float* __restrict__ qkT, ushort* __restrict__ ST, int NT_, int NpT_) {
  __shared__ ushort Aq[64][40];
  __shared__ ushort Bk[64][40];
  int bx, by, bz; bool isT;
  if (!fdecode(4096, 16, 16, 4, 4, bx, by, bz, isT)) return;
  const float* qk = isT ? qkT : qkS;
  ushort* Sbf = isT ? ST : SS;
  const int N = isT ? NT_ : NS_, Np = isT ? NpT_ : NpS_;
  const int m0 = bx * 64, n0 = by * 64, b = bz;
  const float* qb = qk + (size_t)b * 64 * N;
  const float* kb = qb + (size_t)32 * N;
  const int tid = threadIdx.x, lane = tid & 63, w = tid >> 6;
  for (int u = tid; u < 2048; u += 256) {
    const int c = u >> 6, nn = u & 63;
    const int gn = n0 + nn, gm = m0 + nn;
    Aq[nn][c] = (gn < N) ? f2bf(qb[(size_t)c * N + gn]) : (ushort)0;
    Bk[nn][c] = (gm < N) ? f2bf(kb[(size_t)c * N + gm]) : (ushort)0;
  }
  __syncthreads();
  const int koff = (lane >> 4) * 8;
  const bf16x8 af = *reinterpret_cast<const bf16x8*>(&Aq[w * 16 + (lane & 15)][koff]);
  f32x4 acc[4];
#pragma unroll
  for (int j = 0; j < 4; j++) {
    const bf16x8 bf = *reinterpret_cast<const bf16x8*>(&Bk[j * 16 + (lane & 15)][koff]);
    acc[j] = __builtin_amdgcn_mfma_f32_16x16x32_bf16(af, bf, (f32x4){0.f, 0.f, 0.f, 0.f}, 0, 0, 0);
  }
#pragma unroll
  for (int j = 0; j < 4; j++) {
    const int m = m0 + j * 16 + (lane & 15);
    if (m >= Np) continue;
#pragma unroll
    for (int r = 0; r < 4; r++) {
      const int n = n0 + w * 16 + (lane >> 4) * 4 + r;
      if (n < N) Sbf[((size_t)b * N + n) * Np + m] = (m < N) ? f2bf(acc[j][r]) : (ushort)0;
    }
  }
}

// ---------------------------------------------------------------------------
// fp32 in-place row softmax of sign*r (channel attention; Atc||Asc contiguous)
// ---------------------------------------------------------------------------
__global__ __launch_bounds__(256) void softmax_rows_kernel(
    float* __restrict__ e, int N, float sign) {
  const size_t row = blockIdx.x;
  float* r = e + row * (size_t)N;
  const int tid = threadIdx.x;
  __shared__ float red[4];
  float mx = -1e30f;
  for (int i = tid; i < N; i += 256) mx = fmaxf(mx, sign * r[i]);
#pragma unroll
  for (int off = 32; off; off >>= 1) mx = fmaxf(mx, __shfl_xor(mx, off, 64));
  if ((tid & 63) == 0) red[tid >> 6] = mx;
  __syncthreads();
  if (tid == 0) {
    float m2 = red[0];
    for (int i = 1; i < 4; i++) m2 = fmaxf(m2, red[i]);
    red[0] = m2;
  }
  __syncthreads();
  mx = red[0];
  __syncthreads();
  float s = 0.f;
  for (int i = tid; i < N; i += 256) {
    float v = __expf(sign * r[i] - mx);
    r[i] = v;
    s += v;
  }
#pragma unroll
  for (int off = 32; off; off >>= 1) s += __shfl_xor(s, off, 64);
  if ((tid & 63) == 0) red[tid >> 6] = s;
  __syncthreads();
  if (tid == 0) {
    float t = 0.f;
    for (int i = 0; i < 4; i++) t += red[i];
    red[0] = t;
  }
  __syncthreads();
  const float inv = 1.f / red[0];
  for (int i = tid; i < N; i += 256) r[i] *= inv;
}

// ---------------------------------------------------------------------------
// fused bf16 row softmax (spatial scores, both sides). rowsS = Bn*NS first.
// ---------------------------------------------------------------------------
__global__ __launch_bounds__(256) void softmax_bf16_fused_kernel(
    ushort* __restrict__ Ss, int Ns, int Nps, ushort* __restrict__ St, int Nt,
    int Npt, int rowsS) {
  __shared__ float buf[992];
  __shared__ float red[4];
  const int row = blockIdx.x;
  ushort* r;
  int N, Np;
  if (row < rowsS) {
    r = Ss + (size_t)row * Nps;
    N = Ns; Np = Npt;  // Np unused below except pads already zero
    Np = Nps;
  } else {
    r = St + (size_t)(row - rowsS) * Npt;
    N = Nt; Np = Npt;
  }
  (void)Np;
  const int tid = threadIdx.x;
  float mx = -1e30f;
  for (int i = tid; i < N; i += 256) {
    float f = bf2f(r[i]);
    buf[i] = f;
    mx = fmaxf(mx, f);
  }
#pragma unroll
  for (int off = 32; off; off >>= 1) mx = fmaxf(mx, __shfl_xor(mx, off, 64));
  if ((tid & 63) == 0) red[tid >> 6] = mx;
  __syncthreads();
  if (tid == 0) {
    float m2 = red[0];
    for (int i = 1; i < 4; i++) m2 = fmaxf(m2, red[i]);
    red[0] = m2;
  }
  __syncthreads();
  mx = red[0];
  __syncthreads();
  float s = 0.f;
  for (int i = tid; i < N; i += 256) {
    float v = __expf(buf[i] - mx);
    buf[i] = v;
    s += v;
  }
#pragma unroll
  for (int off = 32; off; off >>= 1) s += __shfl_xor(s, off, 64);
  if ((tid & 63) == 0) red[tid >> 6] = s;
  __syncthreads();
  if (tid == 0) {
    float t = 0.f;
    for (int i = 0; i < 4; i++) t += red[i];
    red[0] = t;
  }
  __syncthreads();
  const float inv = 1.f / red[0];
  for (int i = tid; i < N; i += 256) r[i] = f2bf(buf[i] * inv);
}

// ---------------------------------------------------------------------------
// fused PV (BM=128): xsum = x + g * v @ A^T. s gx=16, t gx=4; gy=2.
// ---------------------------------------------------------------------------
__global__ __launch_bounds__(256) void pv_fused_kernel(
    const ushort* __restrict__ vS, const ushort* __restrict__ AS,
    const float* __restrict__ xS, const float* __restrict__ gS,
    float* __restrict__ oS, int NS_, int NpS_,
    const ushort* __restrict__ vT, const ushort* __restrict__ AT,
    const float* __restrict__ xT, const float* __restrict__ gT,
    float* __restrict__ oT, int NT_, int NpT_) {
  constexpr int C = 256, BM = 128, NW = 4, NF = 2, WN = 2;
  __shared__ ushort Asm[BM][40];
  __shared__ ushort Bsm[64][40];
  int bx, by, bz; bool isT;
  if (!fdecode(512, 16, 2, 4, 2, bx, by, bz, isT)) return;
  const ushort* vbf = isT ? vT : vS;
  const ushort* Abf = isT ? AT : AS;
  const float* x = isT ? xT : xS;
  const float* gp = isT ? gT : gS;
  float* xsum = isT ? oT : oS;
  const int N = isT ? NT_ : NS_, Np = isT ? NpT_ : NpS_;
  const int n0 = bx * 64, m0 = by * BM, b = bz;
  const int tid = threadIdx.x, lane = tid & 63, w = tid >> 6;
  const int wr = w / WN, wc = w % WN;
  const ushort* vb = vbf + (size_t)b * C * Np;
  const ushort* Ab = Abf + (size_t)b * (size_t)N * Np;
  f32x4 acc[4][NF];
#pragma unroll
  for (int i = 0; i < 4; i++)
#pragma unroll
    for (int j = 0; j < NF; j++) acc[i][j] = (f32x4){0.f, 0.f, 0.f, 0.f};
  for (int k0 = 0; k0 < Np; k0 += 32) {
    for (int u = tid; u < BM * 4; u += NW * 64) {
      const int row = u >> 2, seg = u & 3;
      *reinterpret_cast<uint4*>(&Asm[row][seg * 8]) =
          *reinterpret_cast<const uint4*>(&vb[(size_t)(m0 + row) * Np + k0 + seg * 8]);
    }
    for (int u = tid; u < 64 * 4; u += NW * 64) {
      const int row = u >> 2, seg = u & 3;
      const int gn = n0 + row;
      uint4 val;
      if (gn < N)
        val = *reinterpret_cast<const uint4*>(&Ab[(size_t)gn * Np + k0 + seg * 8]);
      else
        val = make_uint4(0, 0, 0, 0);
      *reinterpret_cast<uint4*>(&Bsm[row][seg * 8]) = val;
    }
    __syncthreads();
    const int koff = (lane >> 4) * 8;
    bf16x8 af[4], bfr[NF];
#pragma unroll
    for (int mf = 0; mf < 4; mf++)
      af[mf] = *reinterpret_cast<const bf16x8*>(&Asm[wr * 64 + mf * 16 + (lane & 15)][koff]);
#pragma unroll
    for (int nf = 0; nf < NF; nf++)
      bfr[nf] = *reinterpret_cast<const bf16x8*>(&Bsm[wc * NF * 16 + nf * 16 + (lane & 15)][koff]);
#pragma unroll
    for (int mf = 0; mf < 4; mf++)
#pragma unroll
      for (int nf = 0; nf < NF; nf++)
        acc[mf][nf] = __builtin_amdgcn_mfma_f32_16x16x32_bf16(af[mf], bfr[nf], acc[mf][nf], 0, 0, 0);
    __syncthreads();
  }
  const float g = *gp;
#pragma unroll
  for (int mf = 0; mf < 4; mf++) {
    const int mbase = m0 + wr * 64 + mf * 16 + ((lane >> 4) * 4);
#pragma unroll
    for (int nf = 0; nf < NF; nf++) {
      const int gn = n0 + wc * NF * 16 + nf * 16 + (lane & 15);
      if (gn < N) {
#pragma unroll
        for (int rr = 0; rr < 4; rr++) {
          const size_t idx = ((size_t)b * C + mbase + rr) * N + gn;
          xsum[idx] = x[idx] + g * acc[mf][nf][rr];
        }
      }
    }
  }
}

// ---------------------------------------------------------------------------
// fused offconv via MFMA on xsT. s gx=16, t gx=4; gy=1. BK=128.
// ---------------------------------------------------------------------------
__global__ __launch_bounds__(256) void offconv_fused_kernel(
    const ushort* __restrict__ xS, const ushort* __restrict__ owS,
    const float* __restrict__ obS, float* __restrict__ omS, int HS_, int WS_,
    int NS_, int NRS_,
    const ushort* __restrict__ xT, const ushort* __restrict__ owT,
    const float* __restrict__ obT, float* __restrict__ omT, int HT_, int WT_,
    int NT_, int NRT_) {
  __shared__ ushort Asm[32][136];
  __shared__ ushort Bsm[64][136];
  __shared__ int qsrc[64];
  int bx, by, bz; bool isT;
  if (!fdecode(256, 16, 1, 4, 1, bx, by, bz, isT)) return;
  const ushort* xsT = isT ? xT : xS;
  const ushort* owb = isT ? owT : owS;
  const float* ob = isT ? obT : obS;
  float* om = isT ? omT : omS;
  const int H = isT ? HT_ : HS_, Wd = isT ? WT_ : WS_;
  const int N = isT ? NT_ : NS_, NR = isT ? NRT_ : NRS_;
  const int n0 = bx * 64, b = bz;
  const int tid = threadIdx.x, lane = tid & 63, w = tid >> 6;
  const ushort* xb = xsT + (size_t)b * NR * 256;
  f32x4 acc[2];
  acc[0] = (f32x4){0.f, 0.f, 0.f, 0.f};
  acc[1] = (f32x4){0.f, 0.f, 0.f, 0.f};
  for (int tap = 0; tap < 9; ++tap) {
    const int dy = tap / 3 - 1, dx = tap - (tap / 3) * 3 - 1;
    if (tid < 64) {
      const int p = n0 + tid;
      int q = -1;
      if (p < N) {
        const int h = p / Wd, ww = p - (p / Wd) * Wd;
        const int yy = h + dy, xx = ww + dx;
        if (yy >= 0 && yy < H && xx >= 0 && xx < Wd) q = yy * Wd + xx;
      }
      qsrc[tid] = q;
    }
    __syncthreads();
#pragma unroll
    for (int half = 0; half < 2; ++half) {
      const int k0 = tap * 256 + half * 128;
      for (int u = tid; u < 512; u += 256) {
        const int row = u >> 4, seg = u & 15;
        *reinterpret_cast<uint4*>(&Asm[row][seg * 8]) =
            *reinterpret_cast<const uint4*>(&owb[(size_t)row * 2304 + k0 + seg * 8]);
      }
      for (int u = tid; u < 1024; u += 256) {
        const int row = u >> 4, seg = u & 15;
        const int q = qsrc[row];
        uint4 val = make_uint4(0, 0, 0, 0);
        if (q >= 0)
          val = *reinterpret_cast<const uint4*>(&xb[(size_t)q * 256 + half * 128 + seg * 8]);
        *reinterpret_cast<uint4*>(&Bsm[row][seg * 8]) = val;
      }
      __syncthreads();
#pragma unroll
      for (int sub = 0; sub < 4; ++sub) {
        const int koff = sub * 32 + (lane >> 4) * 8;
        const bf16x8 b0 = *reinterpret_cast<const bf16x8*>(&Bsm[w * 16 + (lane & 15)][koff]);
#pragma unroll
        for (int mf = 0; mf < 2; ++mf) {
          const bf16x8 a0 = *reinterpret_cast<const bf16x8*>(&Asm[mf * 16 + (lane & 15)][koff]);
          acc[mf] = __builtin_amdgcn_mfma_f32_16x16x32_bf16(a0, b0, acc[mf], 0, 0, 0);
        }
      }
      __syncthreads();
    }
  }
#pragma unroll
  for (int mf = 0; mf < 2; ++mf) {
#pragma unroll
    for (int r = 0; r < 4; ++r) {
      const int o = mf * 16 + (lane >> 4) * 4 + r;
      const int n = n0 + w * 16 + (lane & 15);
      if (o < 27 && n < N)
        om[((size_t)b * 27 + o) * N + n] = acc[mf][r] + ob[o];
    }
  }
}

// ---------------------------------------------------------------------------
// fused bilinear gather table prep (1D streaming)
// ---------------------------------------------------------------------------
__device__ inline void prep_one(const float* omb, uint4* prep, int i, int p,
                                int k, int H, int Wd, int N) {
  const float offy = omb[(size_t)k * N + p];
  const float offx = omb[(size_t)(9 + k) * N + p];
  const float mraw = omb[(size_t)(18 + k) * N + p];
  const float mval = 1.f / (1.f + __expf(-mraw));
  const int ky = k / 3, kx = k - (k / 3) * 3;
  const int h = p / Wd, w = p - (p / Wd) * Wd;
  const float py = offy + (float)(h + ky - 1);
  const float px = offx + (float)(w + kx - 1);
  const float y0f = floorf(py), x0f = floorf(px);
  const float wy = py - y0f, wx = px - x0f;
  const int y0 = (int)y0f, x0 = (int)x0f;
  const int ys0 = min(max(y0, 0), H - 2);
  const int xs0 = min(max(x0, 0), Wd - 2);
  const float wr0 = (ys0 == y0) ? (1.f - wy) : ((ys0 == y0 + 1) ? wy : 0.f);
  const float wr1 = (ys0 + 1 == y0) ? (1.f - wy) : ((ys0 + 1 == y0 + 1) ? wy : 0.f);
  const float wc0 = (xs0 == x0) ? (1.f - wx) : ((xs0 == x0 + 1) ? wx : 0.f);
  const float wc1 = (xs0 + 1 == x0) ? (1.f - wx) : ((xs0 + 1 == x0 + 1) ? wx : 0.f);
  const float w00 = wr0 * wc0 * mval, w01 = wr0 * wc1 * mval;
  const float w10 = wr1 * wc0 * mval, w11 = wr1 * wc1 * mval;
  uint4 pk;
  pk.x = (uint)(ys0 * Wd + xs0);
  pk.y = (uint)f2bf(w00) | ((uint)f2bf(w01) << 16);
  pk.z = (uint)f2bf(w10) | ((uint)f2bf(w11) << 16);
  pk.w = 0;
  prep[i] = pk;
}

__global__ __launch_bounds__(256) void prep_offsets_fused_kernel(
    const float* __restrict__ omS, uint4* __restrict__ prepS, int HS_, int WS_,
    int totS,
    const float* __restrict__ omT, uint4* __restrict__ prepT, int HT_, int WT_,
    int totT) {
  int i = blockIdx.x * 256 + threadIdx.x;
  if (i < totS) {
    const int N = HS_ * WS_;
    const int p = i % N, k = (i / N) % 9, b = i / (9 * N);
    prep_one(omS + (size_t)b * 27 * N, prepS, i, p, k, HS_, WS_, N);
    return;
  }
  i -= totS;
  if (i < totT) {
    const int N = HT_ * WT_;
    const int p = i % N, k = (i / N) % 9, b = i / (9 * N);
    prep_one(omT + (size_t)b * 27 * N, prepT, i, p, k, HT_, WT_, N);
  }
}

// ---------------------------------------------------------------------------
// fused DCN via MFMA (BM=256, BK=64, BN=32, 512 thr). s gx=32, t gx=8; gy=1.
// ---------------------------------------------------------------------------
__global__ __launch_bounds__(512) void dcn_fused_kernel(
    const ushort* __restrict__ xS, const uint4* __restrict__ prS,
    const ushort* __restrict__ AwS, const float* __restrict__ biS,
    float* __restrict__ oS, int NS_, int WS_, int NRS_,
    const ushort* __restrict__ xT, const uint4* __restrict__ prT,
    const ushort* __restrict__ AwT, const float* __restrict__ biT,
    float* __restrict__ oT, int NT_, int WT_, int NRT_) {
  constexpr int C = 256, KTOT = 2304, BM = 256, MF = 4;
  __shared__ ushort Asm[BM][72];
  __shared__ ushort Bsm[32][72];
  __shared__ int sq[32];
  __shared__ float sw0[32], sw1[32], sw2[32], sw3[32];
  int bx, by, bz; bool isT;
  if (!fdecode(512, 32, 1, 8, 1, bx, by, bz, isT)) return;
  const ushort* xsT = isT ? xT : xS;
  const uint4* prep = isT ? prT : prS;
  const ushort* Awb = isT ? AwT : AwS;
  const float* bias = isT ? biT : biS;
  float* out = isT ? oT : oS;
  const int N = isT ? NT_ : NS_, Wd = isT ? WT_ : WS_, NR = isT ? NRT_ : NRS_;
  const int n0 = bx * 32, b = bz;
  const int tid = threadIdx.x, lane = tid & 63, w = tid >> 6;
  const int wr = w >> 1, wc = w & 1;
  const ushort* xb = xsT + (size_t)b * NR * C;
  f32x4 acc[MF];
#pragma unroll
  for (int i = 0; i < MF; i++) acc[i] = (f32x4){0.f, 0.f, 0.f, 0.f};
  for (int k0 = 0; k0 < KTOT; k0 += 64) {
    const int kpos = k0 >> 8, c0 = k0 & 255;
    if (c0 == 0) {
      if (tid < 32) {
        const int p = n0 + tid;
        if (p < N) {
          const uint4 pk = prep[((size_t)b * 9 + kpos) * N + p];
          sq[tid] = (int)pk.x * C;
          sw0[tid] = bf2f((ushort)(pk.y & 0xffff));
          sw1[tid] = bf2f((ushort)(pk.y >> 16));
          sw2[tid] = bf2f((ushort)(pk.z & 0xffff));
          sw3[tid] = bf2f((ushort)(pk.z >> 16));
        } else {
          sq[tid] = 0;
          sw0[tid] = sw1[tid] = sw2[tid] = sw3[tid] = 0.f;
        }
      }
      __syncthreads();
    }
    for (int u = tid; u < BM * 8; u += 512) {
      const int row = u >> 3, seg = u & 7;
      *reinterpret_cast<uint4*>(&Asm[row][seg * 8]) =
          *reinterpret_cast<const uint4*>(&Awb[(size_t)row * KTOT + k0 + seg * 8]);
    }
    for (int u = tid; u < 1024; u += 512) {
      const int n = u >> 5, pr = u & 31;
      const int kk = pr * 2;
      const ushort* p0 = xb + sq[n] + c0 + kk;
      const uint a00 = *reinterpret_cast<const uint*>(p0);
      const uint a01 = *reinterpret_cast<const uint*>(p0 + C);
      const uint a10 = *reinterpret_cast<const uint*>(p0 + (size_t)Wd * C);
      const uint a11 = *reinterpret_cast<const uint*>(p0 + (size_t)(Wd + 1) * C);
      const float w00 = sw0[n], w01 = sw1[n], w10 = sw2[n], w11 = sw3[n];
      const float vlo = w00 * __uint_as_float(a00 << 16) +
                        w01 * __uint_as_float(a01 << 16) +
                        w10 * __uint_as_float(a10 << 16) +
                        w11 * __uint_as_float(a11 << 16);
      const float vhi = w00 * __uint_as_float(a00 & 0xffff0000u) +
                        w01 * __uint_as_float(a01 & 0xffff0000u) +
                        w10 * __uint_as_float(a10 & 0xffff0000u) +
                        w11 * __uint_as_float(a11 & 0xffff0000u);
      *reinterpret_cast<uint*>(&Bsm[n][kk]) =
          (uint)f2bf(vlo) | ((uint)f2bf(vhi) << 16);
    }
    __syncthreads();
#pragma unroll
    for (int sub = 0; sub < 2; ++sub) {
      const int koff = sub * 32 + (lane >> 4) * 8;
      const bf16x8 bf = *reinterpret_cast<const bf16x8*>(&Bsm[wc * 16 + (lane & 15)][koff]);
#pragma unroll
      for (int mf = 0; mf < MF; mf++) {
        const bf16x8 af = *reinterpret_cast<const bf16x8*>(
            &Asm[wr * 64 + mf * 16 + (lane & 15)][koff]);
        acc[mf] = __builtin_amdgcn_mfma_f32_16x16x32_bf16(af, bf, acc[mf], 0, 0, 0);
      }
    }
    __syncthreads();
  }
  const int gn = n0 + wc * 16 + (lane & 15);
#pragma unroll
  for (int mf = 0; mf < MF; mf++) {
    const int mbase = wr * 64 + mf * 16 + ((lane >> 4) * 4);
    if (gn < N) {
#pragma unroll
      for (int rr = 0; rr < 4; rr++)
        out[((size_t)b * C + mbase + rr) * N + gn] = acc[mf][rr] + bias[mbase + rr];
    }
  }
}

// ---------------------------------------------------------------------------
extern "C" void kernel_launch(void* const* d_in, const int* in_sizes, int n_in,
                              void* d_out, int out_size, void* d_ws, size_t ws_size,
                              hipStream_t stream) {
  const float* t_in = (const float*)d_in[0];
  const float* s_in = (const float*)d_in[1];
  const float* t_qw = (const float*)d_in[2];
  const float* t_qb = (const float*)d_in[3];
  const float* t_kw = (const float*)d_in[4];
  const float* t_kb = (const float*)d_in[5];
  const float* t_vw = (const float*)d_in[6];
  const float* t_vb = (const float*)d_in[7];
  const float* t_g = (const float*)d_in[8];
  const float* s_qw = (const float*)d_in[9];
  const float* s_qb = (const float*)d_in[10];
  const float* s_kw = (const float*)d_in[11];
  const float* s_kb = (const float*)d_in[12];
  const float* s_vw = (const float*)d_in[13];
  const float* s_vb = (const float*)d_in[14];
  const float* s_g = (const float*)d_in[15];
  const float* w_t_ch = (const float*)d_in[16];
  const float* w_s_ch = (const float*)d_in[17];
  const float* w_s2t = (const float*)d_in[18];
  const float* w_t2s = (const float*)d_in[19];
  const float* t_off_w = (const float*)d_in[20];
  const float* t_off_b = (const float*)d_in[21];
  const float* t_dcn_w = (const float*)d_in[22];
  const float* t_dcn_b = (const float*)d_in[23];
  const float* s_off_w = (const float*)d_in[24];
  const float* s_off_b = (const float*)d_in[25];
  const float* s_dcn_w = (const float*)d_in[26];
  const float* s_dcn_b = (const float*)d_in[27];
  (void)in_sizes; (void)n_in; (void)out_size; (void)ws_size;

  constexpr int Bn = 16, C = 256;
  constexpr int HT = 15, WT = 15, NT = HT * WT;    // 225
  constexpr int HS = 31, WS2 = 31, NS = HS * WS2;  // 961
  constexpr int NpT = 256, NpS = 992;
  constexpr int NRT = 256, NRS = 1024;

  float* ws = (float*)d_ws;
  size_t off = 0;
  auto alloc = [&](size_t n) {
    n = (n + 3) & ~(size_t)3;
    float* p = ws + off; off += n; return p;
  };
  auto allocU = [&](size_t nu) { return (ushort*)alloc((nu + 1) / 2); };

  float* qk_t = alloc((size_t)Bn * 64 * NT);
  float* qk_s = alloc((size_t)Bn * 64 * NS);
  float* qkw_t = alloc((size_t)64 * C + 64);
  float* qkw_s = alloc((size_t)64 * C + 64);
  float* qkb_t = qkw_t + (size_t)64 * C;
  float* qkb_s = qkw_s + (size_t)64 * C;
  ushort* xT_t = allocU((size_t)Bn * NRT * C);
  ushort* xT_s = allocU((size_t)Bn * NRS * C);
  ushort* xbf_t = allocU((size_t)Bn * C * NpT);
  ushort* xbf_s = allocU((size_t)Bn * C * NpS);
  ushort* Wv_t = allocU((size_t)C * C);
  ushort* Wv_s = allocU((size_t)C * C);
  ushort* v_tbf = allocU((size_t)Bn * C * NpT);
  ushort* v_sbf = allocU((size_t)Bn * C * NpS);
  ushort* S_t = allocU((size_t)Bn * NT * NpT);
  ushort* S_s = allocU((size_t)Bn * NS * NpS);
  float* xt = alloc((size_t)Bn * C * NT);
  float* xs = alloc((size_t)Bn * C * NS);
  ushort* xsT_t = allocU((size_t)Bn * NRT * C);
  ushort* xsT_s = allocU((size_t)Bn * NRS * C);
  float* Atc = alloc((size_t)Bn * C * C);  // NOTE: Asc must stay adjacent
  float* Asc = alloc((size_t)Bn * C * C);
  ushort* Mc_t = allocU((size_t)Bn * C * C);
  ushort* Mc_s = allocU((size_t)Bn * C * C);
  float* om_t = alloc((size_t)Bn * 27 * NT);
  float* om_s = alloc((size_t)Bn * 27 * NS);
  ushort* owb_t = allocU((size_t)32 * 2304);
  ushort* owb_s = allocU((size_t)32 * 2304);
  ushort* Awb_t = allocU((size_t)256 * 2304);
  ushort* Awb_s = allocU((size_t)256 * 2304);
  uint4* prep_t = (uint4*)alloc((size_t)Bn * 9 * NT * 4);
  uint4* prep_s = (uint4*)alloc((size_t)Bn * 9 * NS * 4);

  dim3 blk(256);

  // 1. fused weight prep
  prep_weights_kernel<<<dim3((1491072 + 255) / 256), blk, 0, stream>>>(
      t_qw, t_qb, t_kw, t_kb, s_qw, s_qb, s_kw, s_kb, t_vw, s_vw,
      t_off_w, s_off_w, t_dcn_w, s_dcn_w,
      qkw_t, qkb_t, qkw_s, qkb_s, Wv_t, Wv_s, owb_t, owb_s, Awb_t, Awb_s);

  // 2. fused q|k projections
  conv1x1_fused_kernel<<<dim3(320), blk, 0, stream>>>(
      s_in, qkw_s, qkb_s, qk_s, NS, t_in, qkw_t, qkb_t, qk_t, NT);

  // 3-4. fused casts
  cast_transpose_fused_kernel<<<dim3(1280), blk, 0, stream>>>(
      s_in, xT_s, NS, NRS, t_in, xT_t, NT, NRT);
  cast_pad_fused_kernel<<<dim3((Bn * C * NpS + Bn * C * NpT + 255) / 256), blk, 0, stream>>>(
      s_in, xbf_s, NS, NpS, Bn * C * NpS, t_in, xbf_t, NT, NpT, Bn * C * NpT);

  // 5. fused v projection (EPI=0)
  gemm_fused_kernel<0><<<dim3(640), blk, 0, stream>>>(
      Wv_s, 0, xT_s, s_vb, v_sbf, nullptr, nullptr, NS, NpS, NRS, C,
      Wv_t, 0, xT_t, t_vb, v_tbf, nullptr, nullptr, NT, NpT, NRT, C,
      512, 16, 4);

  // 6. fused energy
  energy_fused_kernel<<<dim3(4352), blk, 0, stream>>>(
      qk_s, S_s, NS, NpS, qk_t, S_t, NT, NpT);

  // 7. fused spatial softmax
  softmax_bf16_fused_kernel<<<dim3(Bn * NS + Bn * NT), blk, 0, stream>>>(
      S_s, NS, NpS, S_t, NT, NpT, Bn * NS);

  // 8. fused PV
  pv_fused_kernel<<<dim3(640), blk, 0, stream>>>(
      v_sbf, S_s, s_in, s_g, xs, NS, NpS, v_tbf, S_t, t_in, t_g, xt, NT, NpT);

  // 9. fused gram (EPI=2): out rows = C, Bt = xbf (per batch)
  gemm_fused_kernel<2><<<dim3(256), blk, 0, stream>>>(
      xbf_s, 1, xbf_s, nullptr, nullptr, Asc, nullptr, C, C, C, NpS,
      xbf_t, 1, xbf_t, nullptr, nullptr, Atc, nullptr, C, C, C, NpT,
      128, 4, 4);

  // 10. channel softmax over Atc||Asc (contiguous)
  softmax_rows_kernel<<<dim3(2 * Bn * C), blk, 0, stream>>>(Atc, C, -1.f);

  // 11. fused mcomb
  mcomb_fused_kernel<<<dim3((2 * Bn * C * C + 255) / 256), blk, 0, stream>>>(
      Atc, Asc, w_t_ch, w_s2t, w_s_ch, w_t2s, Mc_t, Mc_s, Bn * C * C);

  // 12. fused chan GEMM (EPI=1): xsum += ..., writes xsT
  gemm_fused_kernel<1><<<dim3(640), blk, 0, stream>>>(
      Mc_s, 1, xT_s, nullptr, nullptr, xs, xsT_s, NS, NpS, NRS, C,
      Mc_t, 1, xT_t, nullptr, nullptr, xt, xsT_t, NT, NpT, NRT, C,
      512, 16, 4);

  // 13. fused offconv
  offconv_fused_kernel<<<dim3(320), blk, 0, stream>>>(
      xsT_s, owb_s, s_off_b, om_s, HS, WS2, NS, NRS,
      xsT_t, owb_t, t_off_b, om_t, HT, WT, NT, NRT);

  // 14. fused gather-table prep
  prep_offsets_fused_kernel<<<dim3((Bn * 9 * NS + Bn * 9 * NT + 255) / 256), blk, 0, stream>>>(
      om_s, prep_s, HS, WS2, Bn * 9 * NS, om_t, prep_t, HT, WT, Bn * 9 * NT);

  // 15. fused DCN
  float* out_t = (float*)d_out;
  float* out_s = out_t + (size_t)Bn * C * NT;
  dcn_fused_kernel<<<dim3(640), dim3(512), 0, stream>>>(
      xsT_s, prep_s, Awb_s, s_dcn_b, out_s, NS, WS2, NRS,
      xsT_t, prep_t, Awb_t, t_dcn_b, out_t, NT, WT, NRT);
}

// Round 11
// 372.673 us; speedup vs baseline: 4.6013x; 1.0724x over previous
//
#include <hip/hip_runtime.h>
#include <hip/hip_bf16.h>
#include <cmath>

typedef __attribute__((ext_vector_type(8))) short bf16x8;
typedef __attribute__((ext_vector_type(4))) float f32x4;

__device__ inline ushort f2bf(float f) {
  __hip_bfloat16 h = __float2bfloat16(f);
  return *reinterpret_cast<ushort*>(&h);
}
__device__ inline float bf2f(ushort u) {
  return __uint_as_float((uint)u << 16);
}
__device__ inline float bflo(uint x) { return __uint_as_float(x << 16); }
__device__ inline float bfhi(uint x) { return __uint_as_float(x & 0xffff0000u); }

// Fused-side decode with XCD-aware bijective chunking.
__device__ inline bool fdecode(int totalS, int gxS, int gyS, int gxT, int gyT,
                               int& bx, int& by, int& bz, bool& isT) {
  const int total = gridDim.x;
  const int id = blockIdx.x;
  int wid = (id & 7) * (total >> 3) + (id >> 3);
  const int totalT = gxT * gyT * 16;
  if (wid >= totalS + totalT) return false;
  isT = wid >= totalS;
  int lid = isT ? wid - totalS : wid;
  const int gx = isT ? gxT : gxS;
  const int gy = isT ? gyT : gyS;
  bx = lid % gx;
  lid /= gx;
  by = lid % gy;
  bz = lid / gy;
  return true;
}

// ---------------------------------------------------------------------------
// fused weight prep
// ---------------------------------------------------------------------------
__global__ __launch_bounds__(256) void prep_weights_kernel(
    const float* __restrict__ t_qw, const float* __restrict__ t_qb,
    const float* __restrict__ t_kw, const float* __restrict__ t_kb,
    const float* __restrict__ s_qw, const float* __restrict__ s_qb,
    const float* __restrict__ s_kw, const float* __restrict__ s_kb,
    const float* __restrict__ t_vw, const float* __restrict__ s_vw,
    const float* __restrict__ t_off_w, const float* __restrict__ s_off_w,
    const float* __restrict__ t_dcn_w, const float* __restrict__ s_dcn_w,
    float* __restrict__ qkw_t, float* __restrict__ qkb_t,
    float* __restrict__ qkw_s, float* __restrict__ qkb_s,
    ushort* __restrict__ Wv_t, ushort* __restrict__ Wv_s,
    ushort* __restrict__ owb_t, ushort* __restrict__ owb_s,
    ushort* __restrict__ Awb_t, ushort* __restrict__ Awb_s) {
  int i = blockIdx.x * 256 + threadIdx.x;
  if (i < 16448) {
    if (i < 8192) qkw_t[i] = t_qw[i];
    else if (i < 16384) qkw_t[i] = t_kw[i - 8192];
    else { int j = i - 16384; qkb_t[j] = (j < 32) ? t_qb[j] : t_kb[j - 32]; }
    return;
  }
  i -= 16448;
  if (i < 16448) {
    if (i < 8192) qkw_s[i] = s_qw[i];
    else if (i < 16384) qkw_s[i] = s_kw[i - 8192];
    else { int j = i - 16384; qkb_s[j] = (j < 32) ? s_qb[j] : s_kb[j - 32]; }
    return;
  }
  i -= 16448;
  if (i < 65536) { Wv_t[i] = f2bf(t_vw[i]); return; }
  i -= 65536;
  if (i < 65536) { Wv_s[i] = f2bf(s_vw[i]); return; }
  i -= 65536;
  if (i < 73728) {
    const int o = i / 2304, k = i % 2304, tap = k >> 8, c = k & 255;
    owb_t[i] = (o < 27) ? f2bf(t_off_w[(size_t)o * 2304 + c * 9 + tap]) : (ushort)0;
    return;
  }
  i -= 73728;
  if (i < 73728) {
    const int o = i / 2304, k = i % 2304, tap = k >> 8, c = k & 255;
    owb_s[i] = (o < 27) ? f2bf(s_off_w[(size_t)o * 2304 + c * 9 + tap]) : (ushort)0;
    return;
  }
  i -= 73728;
  if (i < 589824) {
    const int o = i / 2304, k = i % 2304, tap = k >> 8, c = k & 255;
    Awb_t[i] = f2bf(t_dcn_w[(size_t)o * 2304 + c * 9 + tap]);
    return;
  }
  i -= 589824;
  if (i < 589824) {
    const int o = i / 2304, k = i % 2304, tap = k >> 8, c = k & 255;
    Awb_s[i] = f2bf(s_dcn_w[(size_t)o * 2304 + c * 9 + tap]);
  }
}

// ---------------------------------------------------------------------------
// fused conv1x1 (fp32) q|k projection, OC=64
// ---------------------------------------------------------------------------
__global__ __launch_bounds__(256) void conv1x1_fused_kernel(
    const float* __restrict__ xS, const float* __restrict__ wS,
    const float* __restrict__ bS, float* __restrict__ oS, int NS_,
    const float* __restrict__ xT, const float* __restrict__ wT,
    const float* __restrict__ bT, float* __restrict__ oT, int NT_) {
  constexpr int C = 256, OC = 64;
  __shared__ float As[64][17];
  __shared__ float Bs[16][64];
  int bx, by, bz; bool isT;
  if (!fdecode(256, 16, 1, 4, 1, bx, by, bz, isT)) return;
  const float* x = isT ? xT : xS;
  const float* w = isT ? wT : wS;
  const float* bias = isT ? bT : bS;
  float* out = isT ? oT : oS;
  const int N = isT ? NT_ : NS_;
  const int b = bz;
  const int n0 = bx * 64;
  const float* xb = x + (size_t)b * C * N;
  const int tid = threadIdx.x;
  const int tr = tid >> 4, tc = tid & 15;
  float acc[4][4] = {};
  for (int k0 = 0; k0 < C; k0 += 16) {
    for (int i = tid; i < 64 * 16; i += 256) {
      int m = i >> 4, kk = i & 15;
      As[m][kk] = w[(size_t)m * C + k0 + kk];
    }
    for (int i = tid; i < 16 * 64; i += 256) {
      int kk = i >> 6, n = i & 63;
      int gn = n0 + n;
      Bs[kk][n] = (gn < N) ? xb[(size_t)(k0 + kk) * N + gn] : 0.f;
    }
    __syncthreads();
#pragma unroll
    for (int kk = 0; kk < 16; ++kk) {
      float a[4], bb[4];
#pragma unroll
      for (int i = 0; i < 4; i++) a[i] = As[tr * 4 + i][kk];
#pragma unroll
      for (int j = 0; j < 4; j++) bb[j] = Bs[kk][tc * 4 + j];
#pragma unroll
      for (int i = 0; i < 4; i++)
#pragma unroll
        for (int j = 0; j < 4; j++) acc[i][j] += a[i] * bb[j];
    }
    __syncthreads();
  }
  for (int i = 0; i < 4; i++) {
    int gm = tr * 4 + i;
    if (gm >= OC) continue;
    float bv = bias[gm];
    for (int j = 0; j < 4; j++) {
      int gn = n0 + tc * 4 + j;
      if (gn < N) out[((size_t)b * OC + gm) * N + gn] = acc[i][j] + bv;
    }
  }
}

// ---------------------------------------------------------------------------
// fused cast+transpose: x fp32 [C][N] -> xT bf16 [NR][C]
// ---------------------------------------------------------------------------
__global__ __launch_bounds__(256) void cast_transpose_fused_kernel(
    const float* __restrict__ xS, ushort* __restrict__ oS, int NS_, int NRS_,
    const float* __restrict__ xT, ushort* __restrict__ oT, int NT_, int NRT_) {
  constexpr int C = 256;
  __shared__ float T[64][65];
  int bx, by, bz; bool isT;
  if (!fdecode(1024, 16, 4, 4, 4, bx, by, bz, isT)) return;
  const float* x = isT ? xT : xS;
  ushort* xTo = isT ? oT : oS;
  const int N = isT ? NT_ : NS_;
  const int NR = isT ? NRT_ : NRS_;
  const int b = bz;
  const int n0 = bx * 64, c0 = by * 64;
  const float* xb = x + (size_t)b * C * N;
  const int tid = threadIdx.x;
  for (int u = tid; u < 4096; u += 256) {
    const int cc = u >> 6, nn = u & 63;
    const int gn = n0 + nn;
    T[cc][nn] = (gn < N) ? xb[(size_t)(c0 + cc) * N + gn] : 0.f;
  }
  __syncthreads();
  ushort* ob = xTo + (size_t)b * NR * C;
  for (int u = tid; u < 4096; u += 256) {
    const int nn = u >> 6, cc = u & 63;
    ob[(size_t)(n0 + nn) * C + c0 + cc] = f2bf(T[cc][nn]);
  }
}

// ---------------------------------------------------------------------------
// fused cast+pad
// ---------------------------------------------------------------------------
__global__ __launch_bounds__(256) void cast_pad_fused_kernel(
    const float* __restrict__ xS, ushort* __restrict__ oS, int NS_, int NpS_,
    int totS,
    const float* __restrict__ xT, ushort* __restrict__ oT, int NT_, int NpT_,
    int totT) {
  constexpr int C = 256;
  int i = blockIdx.x * 256 + threadIdx.x;
  if (i < totS) {
    const int np = i % NpS_;
    const int c = (i / NpS_) % C;
    const int b = i / (NpS_ * C);
    oS[i] = (np < NS_) ? f2bf(xS[((size_t)b * C + c) * NS_ + np]) : (ushort)0;
    return;
  }
  i -= totS;
  if (i < totT) {
    const int np = i % NpT_;
    const int c = (i / NpT_) % C;
    const int b = i / (NpT_ * C);
    oT[i] = (np < NT_) ? f2bf(xT[((size_t)b * C + c) * NT_ + np]) : (ushort)0;
  }
}

// ---------------------------------------------------------------------------
// fused Mcomb
// ---------------------------------------------------------------------------
__global__ __launch_bounds__(256) void mcomb_fused_kernel(
    const float* __restrict__ Atc, const float* __restrict__ Asc,
    const float* __restrict__ w_t_ch, const float* __restrict__ w_s2t,
    const float* __restrict__ w_s_ch, const float* __restrict__ w_t2s,
    ushort* __restrict__ Mc_t, ushort* __restrict__ Mc_s, int n) {
  const int i = blockIdx.x * 256 + threadIdx.x;
  if (i < n) {
    Mc_t[i] = f2bf(w_t_ch[0] * Atc[i] + w_s2t[0] * Asc[i]);
  } else if (i < 2 * n) {
    const int j = i - n;
    Mc_s[j] = f2bf(w_s_ch[0] * Asc[j] + w_t2s[0] * Atc[j]);
  }
}

// ---------------------------------------------------------------------------
// fused generic bf16 GEMM, BM=128, NW=4.
// EPI 0: outBf = bf16(acc+bias) padded   EPI 2: outF = acc
// ---------------------------------------------------------------------------
template <int EPI>
__global__ __launch_bounds__(256) void gemm_fused_kernel(
    const ushort* __restrict__ AS, int aPerB_S, const ushort* __restrict__ BtS,
    const float* __restrict__ biasS, ushort* __restrict__ outBfS,
    float* __restrict__ outFS, int NS_, int NpS_, int NRS_, int KpS_,
    const ushort* __restrict__ AT, int aPerB_T, const ushort* __restrict__ BtT,
    const float* __restrict__ biasT, ushort* __restrict__ outBfT,
    float* __restrict__ outFT, int NT_, int NpT_, int NRT_, int KpT_,
    int totalS, int gxS, int gxT) {
  constexpr int CM = 256, BM = 128, NW = 4, NF = 2, WN = 2;
  __shared__ ushort Asm[BM][40];
  __shared__ ushort Bsm[64][40];
  int bx, by, bz; bool isT;
  if (!fdecode(totalS, gxS, 2, gxT, 2, bx, by, bz, isT)) return;
  const ushort* A = isT ? AT : AS;
  const ushort* Bt = isT ? BtT : BtS;
  const float* bias = isT ? biasT : biasS;
  ushort* outBf = isT ? outBfT : outBfS;
  float* outF = isT ? outFT : outFS;
  const int aPerBatch = isT ? aPerB_T : aPerB_S;
  const int N = isT ? NT_ : NS_, Np = isT ? NpT_ : NpS_;
  const int NR = isT ? NRT_ : NRS_, Kp = isT ? KpT_ : KpS_;
  const int n0 = bx * 64, m0 = by * BM, b = bz;
  const ushort* Ab = A + (size_t)(aPerBatch ? b : 0) * CM * Kp;
  const ushort* Bb = Bt + (size_t)b * NR * Kp;
  const int tid = threadIdx.x, lane = tid & 63, w = tid >> 6;
  const int wr = w / WN, wc = w % WN;
  f32x4 acc[4][NF];
#pragma unroll
  for (int i = 0; i < 4; i++)
#pragma unroll
    for (int j = 0; j < NF; j++) acc[i][j] = (f32x4){0.f, 0.f, 0.f, 0.f};
  for (int k0 = 0; k0 < Kp; k0 += 32) {
    for (int u = tid; u < BM * 4; u += NW * 64) {
      const int row = u >> 2, seg = u & 3;
      *reinterpret_cast<uint4*>(&Asm[row][seg * 8]) =
          *reinterpret_cast<const uint4*>(&Ab[(size_t)(m0 + row) * Kp + k0 + seg * 8]);
    }
    for (int u = tid; u < 64 * 4; u += NW * 64) {
      const int row = u >> 2, seg = u & 3;
      *reinterpret_cast<uint4*>(&Bsm[row][seg * 8]) =
          *reinterpret_cast<const uint4*>(&Bb[(size_t)(n0 + row) * Kp + k0 + seg * 8]);
    }
    __syncthreads();
    const int koff = (lane >> 4) * 8;
    bf16x8 af[4], bfr[NF];
#pragma unroll
    for (int mf = 0; mf < 4; mf++)
      af[mf] = *reinterpret_cast<const bf16x8*>(&Asm[wr * 64 + mf * 16 + (lane & 15)][koff]);
#pragma unroll
    for (int nf = 0; nf < NF; nf++)
      bfr[nf] = *reinterpret_cast<const bf16x8*>(&Bsm[wc * NF * 16 + nf * 16 + (lane & 15)][koff]);
#pragma unroll
    for (int mf = 0; mf < 4; mf++)
#pragma unroll
      for (int nf = 0; nf < NF; nf++)
        acc[mf][nf] = __builtin_amdgcn_mfma_f32_16x16x32_bf16(af[mf], bfr[nf], acc[mf][nf], 0, 0, 0);
    __syncthreads();
  }
#pragma unroll
  for (int mf = 0; mf < 4; mf++) {
    const int mbase = m0 + wr * 64 + mf * 16 + ((lane >> 4) * 4);
#pragma unroll
    for (int nf = 0; nf < NF; nf++) {
      const int gn = n0 + wc * NF * 16 + nf * 16 + (lane & 15);
      if (EPI == 0) {
#pragma unroll
        for (int rr = 0; rr < 4; rr++) {
          const int m = mbase + rr;
          if (gn < Np) {
            ushort v = (gn < N) ? f2bf(acc[mf][nf][rr] + bias[m]) : (ushort)0;
            outBf[((size_t)b * CM + m) * Np + gn] = v;
          }
        }
      } else {
#pragma unroll
        for (int rr = 0; rr < 4; rr++) {
          if (gn < N)
            outF[((size_t)b * CM + mbase + rr) * N + gn] = acc[mf][nf][rr];
        }
      }
    }
  }
  (void)NR;
}

// ---------------------------------------------------------------------------
// fused energy (K=32)
// ---------------------------------------------------------------------------
__global__ __launch_bounds__(256) void energy_fused_kernel(
    const float* __restrict__ qkS, ushort* __restrict__ SS, int NS_, int NpS_,
    const float* __restrict__ qkT, ushort* __restrict__ ST, int NT_, int NpT_) {
  __shared__ ushort Aq[64][40];
  __shared__ ushort Bk[64][40];
  int bx, by, bz; bool isT;
  if (!fdecode(4096, 16, 16, 4, 4, bx, by, bz, isT)) return;
  const float* qk = isT ? qkT : qkS;
  ushort* Sbf = isT ? ST : SS;
  const int N = isT ? NT_ : NS_, Np = isT ? NpT_ : NpS_;
  const int m0 = bx * 64, n0 = by * 64, b = bz;
  const float* qb = qk + (size_t)b * 64 * N;
  const float* kb = qb + (size_t)32 * N;
  const int tid = threadIdx.x, lane = tid & 63, w = tid >> 6;
  for (int u = tid; u < 2048; u += 256) {
    const int c = u >> 6, nn = u & 63;
    const int gn = n0 + nn, gm = m0 + nn;
    Aq[nn][c] = (gn < N) ? f2bf(qb[(size_t)c * N + gn]) : (ushort)0;
    Bk[nn][c] = (gm < N) ? f2bf(kb[(size_t)c * N + gm]) : (ushort)0;
  }
  __syncthreads();
  const int koff = (lane >> 4) * 8;
  const bf16x8 af = *reinterpret_cast<const bf16x8*>(&Aq[w * 16 + (lane & 15)][koff]);
  f32x4 acc[4];
#pragma unroll
  for (int j = 0; j < 4; j++) {
    const bf16x8 bf = *reinterpret_cast<const bf16x8*>(&Bk[j * 16 + (lane & 15)][koff]);
    acc[j] = __builtin_amdgcn_mfma_f32_16x16x32_bf16(af, bf, (f32x4){0.f, 0.f, 0.f, 0.f}, 0, 0, 0);
  }
#pragma unroll
  for (int j = 0; j < 4; j++) {
    const int m = m0 + j * 16 + (lane & 15);
    if (m >= Np) continue;
#pragma unroll
    for (int r = 0; r < 4; r++) {
      const int n = n0 + w * 16 + (lane >> 4) * 4 + r;
      if (n < N) Sbf[((size_t)b * N + n) * Np + m] = (m < N) ? f2bf(acc[j][r]) : (ushort)0;
    }
  }
}

// ---------------------------------------------------------------------------
// fp32 in-place row softmax of sign*r (channel attention; Atc||Asc contiguous)
// ---------------------------------------------------------------------------
__global__ __launch_bounds__(256) void softmax_rows_kernel(
    float* __restrict__ e, int N, float sign) {
  const size_t row = blockIdx.x;
  float* r = e + row * (size_t)N;
  const int tid = threadIdx.x;
  __shared__ float red[4];
  float mx = -1e30f;
  for (int i = tid; i < N; i += 256) mx = fmaxf(mx, sign * r[i]);
#pragma unroll
  for (int off = 32; off; off >>= 1) mx = fmaxf(mx, __shfl_xor(mx, off, 64));
  if ((tid & 63) == 0) red[tid >> 6] = mx;
  __syncthreads();
  if (tid == 0) {
    float m2 = red[0];
    for (int i = 1; i < 4; i++) m2 = fmaxf(m2, red[i]);
    red[0] = m2;
  }
  __syncthreads();
  mx = red[0];
  __syncthreads();
  float s = 0.f;
  for (int i = tid; i < N; i += 256) {
    float v = __expf(sign * r[i] - mx);
    r[i] = v;
    s += v;
  }
#pragma unroll
  for (int off = 32; off; off >>= 1) s += __shfl_xor(s, off, 64);
  if ((tid & 63) == 0) red[tid >> 6] = s;
  __syncthreads();
  if (tid == 0) {
    float t = 0.f;
    for (int i = 0; i < 4; i++) t += red[i];
    red[0] = t;
  }
  __syncthreads();
  const float inv = 1.f / red[0];
  for (int i = tid; i < N; i += 256) r[i] *= inv;
}

// ---------------------------------------------------------------------------
// fused bf16 row softmax (spatial scores)
// ---------------------------------------------------------------------------
__global__ __launch_bounds__(256) void softmax_bf16_fused_kernel(
    ushort* __restrict__ Ss, int Ns, int Nps, ushort* __restrict__ St, int Nt,
    int Npt, int rowsS) {
  __shared__ float buf[992];
  __shared__ float red[4];
  const int row = blockIdx.x;
  ushort* r;
  int N;
  if (row < rowsS) {
    r = Ss + (size_t)row * Nps;
    N = Ns;
  } else {
    r = St + (size_t)(row - rowsS) * Npt;
    N = Nt;
  }
  const int tid = threadIdx.x;
  float mx = -1e30f;
  for (int i = tid; i < N; i += 256) {
    float f = bf2f(r[i]);
    buf[i] = f;
    mx = fmaxf(mx, f);
  }
#pragma unroll
  for (int off = 32; off; off >>= 1) mx = fmaxf(mx, __shfl_xor(mx, off, 64));
  if ((tid & 63) == 0) red[tid >> 6] = mx;
  __syncthreads();
  if (tid == 0) {
    float m2 = red[0];
    for (int i = 1; i < 4; i++) m2 = fmaxf(m2, red[i]);
    red[0] = m2;
  }
  __syncthreads();
  mx = red[0];
  __syncthreads();
  float s = 0.f;
  for (int i = tid; i < N; i += 256) {
    float v = __expf(buf[i] - mx);
    buf[i] = v;
    s += v;
  }
#pragma unroll
  for (int off = 32; off; off >>= 1) s += __shfl_xor(s, off, 64);
  if ((tid & 63) == 0) red[tid >> 6] = s;
  __syncthreads();
  if (tid == 0) {
    float t = 0.f;
    for (int i = 0; i < 4; i++) t += red[i];
    red[0] = t;
  }
  __syncthreads();
  const float inv = 1.f / red[0];
  for (int i = tid; i < N; i += 256) r[i] = f2bf(buf[i] * inv);
}

// ---------------------------------------------------------------------------
// fused PV+CHAN merged GEMM (BM=128): acc = PV(v@S^T); acc *= g;
// acc += Mc@xT; out_xsT = bf16(x + acc). No fp32 xsum intermediate.
// s gx=16, t gx=4; gy=2.
// ---------------------------------------------------------------------------
__global__ __launch_bounds__(256) void pv_chan_fused_kernel(
    const ushort* __restrict__ vS, const ushort* __restrict__ SS,
    const ushort* __restrict__ McS, const ushort* __restrict__ xTS,
    const float* __restrict__ xS, const float* __restrict__ gS,
    ushort* __restrict__ xsTS, int NS_, int NpS_, int NRS_,
    const ushort* __restrict__ vT, const ushort* __restrict__ ST,
    const ushort* __restrict__ McT, const ushort* __restrict__ xTT,
    const float* __restrict__ xT_, const float* __restrict__ gT,
    ushort* __restrict__ xsTT, int NT_, int NpT_, int NRT_) {
  constexpr int C = 256, BM = 128, NW = 4, NF = 2, WN = 2;
  __shared__ ushort Asm[BM][40];
  __shared__ ushort Bsm[64][40];
  int bx, by, bz; bool isT;
  if (!fdecode(512, 16, 2, 4, 2, bx, by, bz, isT)) return;
  const ushort* vbf = isT ? vT : vS;
  const ushort* Sbf = isT ? ST : SS;
  const ushort* Mc = isT ? McT : McS;
  const ushort* xTb = isT ? xTT : xTS;
  const float* x = isT ? xT_ : xS;
  const float* gp = isT ? gT : gS;
  ushort* xsT = isT ? xsTT : xsTS;
  const int N = isT ? NT_ : NS_, Np = isT ? NpT_ : NpS_;
  const int NR = isT ? NRT_ : NRS_;
  const int n0 = bx * 64, m0 = by * BM, b = bz;
  const int tid = threadIdx.x, lane = tid & 63, w = tid >> 6;
  const int wr = w / WN, wc = w % WN;
  f32x4 acc[4][NF];
#pragma unroll
  for (int i = 0; i < 4; i++)
#pragma unroll
    for (int j = 0; j < NF; j++) acc[i][j] = (f32x4){0.f, 0.f, 0.f, 0.f};
  const int koff = (lane >> 4) * 8;
  // phase 1: PV, K = Np
  {
    const ushort* Ab = vbf + (size_t)b * C * Np;
    const ushort* Bb = Sbf + (size_t)b * (size_t)N * Np;
    for (int k0 = 0; k0 < Np; k0 += 32) {
      for (int u = tid; u < BM * 4; u += NW * 64) {
        const int row = u >> 2, seg = u & 3;
        *reinterpret_cast<uint4*>(&Asm[row][seg * 8]) =
            *reinterpret_cast<const uint4*>(&Ab[(size_t)(m0 + row) * Np + k0 + seg * 8]);
      }
      for (int u = tid; u < 64 * 4; u += NW * 64) {
        const int row = u >> 2, seg = u & 3;
        const int gn = n0 + row;
        uint4 val;
        if (gn < N)
          val = *reinterpret_cast<const uint4*>(&Bb[(size_t)gn * Np + k0 + seg * 8]);
        else
          val = make_uint4(0, 0, 0, 0);
        *reinterpret_cast<uint4*>(&Bsm[row][seg * 8]) = val;
      }
      __syncthreads();
      bf16x8 af[4], bfr[NF];
#pragma unroll
      for (int mf = 0; mf < 4; mf++)
        af[mf] = *reinterpret_cast<const bf16x8*>(&Asm[wr * 64 + mf * 16 + (lane & 15)][koff]);
#pragma unroll
      for (int nf = 0; nf < NF; nf++)
        bfr[nf] = *reinterpret_cast<const bf16x8*>(&Bsm[wc * NF * 16 + nf * 16 + (lane & 15)][koff]);
#pragma unroll
      for (int mf = 0; mf < 4; mf++)
#pragma unroll
        for (int nf = 0; nf < NF; nf++)
          acc[mf][nf] = __builtin_amdgcn_mfma_f32_16x16x32_bf16(af[mf], bfr[nf], acc[mf][nf], 0, 0, 0);
      __syncthreads();
    }
  }
  // scale by g
  const float g = *gp;
#pragma unroll
  for (int mf = 0; mf < 4; mf++)
#pragma unroll
    for (int nf = 0; nf < NF; nf++)
#pragma unroll
      for (int rr = 0; rr < 4; rr++) acc[mf][nf][rr] *= g;
  // phase 2: chan, K = C
  {
    const ushort* Ab = Mc + (size_t)b * C * C;
    const ushort* Bb = xTb + (size_t)b * NR * C;
    for (int k0 = 0; k0 < C; k0 += 32) {
      for (int u = tid; u < BM * 4; u += NW * 64) {
        const int row = u >> 2, seg = u & 3;
        *reinterpret_cast<uint4*>(&Asm[row][seg * 8]) =
            *reinterpret_cast<const uint4*>(&Ab[(size_t)(m0 + row) * C + k0 + seg * 8]);
      }
      for (int u = tid; u < 64 * 4; u += NW * 64) {
        const int row = u >> 2, seg = u & 3;
        *reinterpret_cast<uint4*>(&Bsm[row][seg * 8]) =
            *reinterpret_cast<const uint4*>(&Bb[(size_t)(n0 + row) * C + k0 + seg * 8]);
      }
      __syncthreads();
      bf16x8 af[4], bfr[NF];
#pragma unroll
      for (int mf = 0; mf < 4; mf++)
        af[mf] = *reinterpret_cast<const bf16x8*>(&Asm[wr * 64 + mf * 16 + (lane & 15)][koff]);
#pragma unroll
      for (int nf = 0; nf < NF; nf++)
        bfr[nf] = *reinterpret_cast<const bf16x8*>(&Bsm[wc * NF * 16 + nf * 16 + (lane & 15)][koff]);
#pragma unroll
      for (int mf = 0; mf < 4; mf++)
#pragma unroll
        for (int nf = 0; nf < NF; nf++)
          acc[mf][nf] = __builtin_amdgcn_mfma_f32_16x16x32_bf16(af[mf], bfr[nf], acc[mf][nf], 0, 0, 0);
      __syncthreads();
    }
  }
  // epilogue: val = x + acc -> xsT (bf16, transposed). No fp32 write.
#pragma unroll
  for (int mf = 0; mf < 4; mf++) {
    const int mbase = m0 + wr * 64 + mf * 16 + ((lane >> 4) * 4);
#pragma unroll
    for (int nf = 0; nf < NF; nf++) {
      const int gn = n0 + wc * NF * 16 + nf * 16 + (lane & 15);
      if (gn < N) {
        float s[4];
#pragma unroll
        for (int rr = 0; rr < 4; rr++)
          s[rr] = x[((size_t)b * C + mbase + rr) * N + gn] + acc[mf][nf][rr];
        uint lo = (uint)f2bf(s[0]) | ((uint)f2bf(s[1]) << 16);
        uint hi = (uint)f2bf(s[2]) | ((uint)f2bf(s[3]) << 16);
        *reinterpret_cast<uint2*>(&xsT[((size_t)b * NR + gn) * C + mbase]) =
            make_uint2(lo, hi);
      }
    }
  }
}

// ---------------------------------------------------------------------------
// fused offconv via MFMA on xsT. BK=128.
// ---------------------------------------------------------------------------
__global__ __launch_bounds__(256) void offconv_fused_kernel(
    const ushort* __restrict__ xS, const ushort* __restrict__ owS,
    const float* __restrict__ obS, float* __restrict__ omS, int HS_, int WS_,
    int NS_, int NRS_,
    const ushort* __restrict__ xT, const ushort* __restrict__ owT,
    const float* __restrict__ obT, float* __restrict__ omT, int HT_, int WT_,
    int NT_, int NRT_) {
  __shared__ ushort Asm[32][136];
  __shared__ ushort Bsm[64][136];
  __shared__ int qsrc[64];
  int bx, by, bz; bool isT;
  if (!fdecode(256, 16, 1, 4, 1, bx, by, bz, isT)) return;
  const ushort* xsT = isT ? xT : xS;
  const ushort* owb = isT ? owT : owS;
  const float* ob = isT ? obT : obS;
  float* om = isT ? omT : omS;
  const int H = isT ? HT_ : HS_, Wd = isT ? WT_ : WS_;
  const int N = isT ? NT_ : NS_, NR = isT ? NRT_ : NRS_;
  const int n0 = bx * 64, b = bz;
  const int tid = threadIdx.x, lane = tid & 63, w = tid >> 6;
  const ushort* xb = xsT + (size_t)b * NR * 256;
  f32x4 acc[2];
  acc[0] = (f32x4){0.f, 0.f, 0.f, 0.f};
  acc[1] = (f32x4){0.f, 0.f, 0.f, 0.f};
  for (int tap = 0; tap < 9; ++tap) {
    const int dy = tap / 3 - 1, dx = tap - (tap / 3) * 3 - 1;
    if (tid < 64) {
      const int p = n0 + tid;
      int q = -1;
      if (p < N) {
        const int h = p / Wd, ww = p - (p / Wd) * Wd;
        const int yy = h + dy, xx = ww + dx;
        if (yy >= 0 && yy < H && xx >= 0 && xx < Wd) q = yy * Wd + xx;
      }
      qsrc[tid] = q;
    }
    __syncthreads();
#pragma unroll
    for (int half = 0; half < 2; ++half) {
      const int k0 = tap * 256 + half * 128;
      for (int u = tid; u < 512; u += 256) {
        const int row = u >> 4, seg = u & 15;
        *reinterpret_cast<uint4*>(&Asm[row][seg * 8]) =
            *reinterpret_cast<const uint4*>(&owb[(size_t)row * 2304 + k0 + seg * 8]);
      }
      for (int u = tid; u < 1024; u += 256) {
        const int row = u >> 4, seg = u & 15;
        const int q = qsrc[row];
        uint4 val = make_uint4(0, 0, 0, 0);
        if (q >= 0)
          val = *reinterpret_cast<const uint4*>(&xb[(size_t)q * 256 + half * 128 + seg * 8]);
        *reinterpret_cast<uint4*>(&Bsm[row][seg * 8]) = val;
      }
      __syncthreads();
#pragma unroll
      for (int sub = 0; sub < 4; ++sub) {
        const int koff = sub * 32 + (lane >> 4) * 8;
        const bf16x8 b0 = *reinterpret_cast<const bf16x8*>(&Bsm[w * 16 + (lane & 15)][koff]);
#pragma unroll
        for (int mf = 0; mf < 2; ++mf) {
          const bf16x8 a0 = *reinterpret_cast<const bf16x8*>(&Asm[mf * 16 + (lane & 15)][koff]);
          acc[mf] = __builtin_amdgcn_mfma_f32_16x16x32_bf16(a0, b0, acc[mf], 0, 0, 0);
        }
      }
      __syncthreads();
    }
  }
#pragma unroll
  for (int mf = 0; mf < 2; ++mf) {
#pragma unroll
    for (int r = 0; r < 4; ++r) {
      const int o = mf * 16 + (lane >> 4) * 4 + r;
      const int n = n0 + w * 16 + (lane & 15);
      if (o < 27 && n < N)
        om[((size_t)b * 27 + o) * N + n] = acc[mf][r] + ob[o];
    }
  }
}

// ---------------------------------------------------------------------------
// fused bilinear gather table prep
// ---------------------------------------------------------------------------
__device__ inline void prep_one(const float* omb, uint4* prep, int i, int p,
                                int k, int H, int Wd, int N) {
  const float offy = omb[(size_t)k * N + p];
  const float offx = omb[(size_t)(9 + k) * N + p];
  const float mraw = omb[(size_t)(18 + k) * N + p];
  const float mval = 1.f / (1.f + __expf(-mraw));
  const int ky = k / 3, kx = k - (k / 3) * 3;
  const int h = p / Wd, w = p - (p / Wd) * Wd;
  const float py = offy + (float)(h + ky - 1);
  const float px = offx + (float)(w + kx - 1);
  const float y0f = floorf(py), x0f = floorf(px);
  const float wy = py - y0f, wx = px - x0f;
  const int y0 = (int)y0f, x0 = (int)x0f;
  const int ys0 = min(max(y0, 0), H - 2);
  const int xs0 = min(max(x0, 0), Wd - 2);
  const float wr0 = (ys0 == y0) ? (1.f - wy) : ((ys0 == y0 + 1) ? wy : 0.f);
  const float wr1 = (ys0 + 1 == y0) ? (1.f - wy) : ((ys0 + 1 == y0 + 1) ? wy : 0.f);
  const float wc0 = (xs0 == x0) ? (1.f - wx) : ((xs0 == x0 + 1) ? wx : 0.f);
  const float wc1 = (xs0 + 1 == x0) ? (1.f - wx) : ((xs0 + 1 == x0 + 1) ? wx : 0.f);
  const float w00 = wr0 * wc0 * mval, w01 = wr0 * wc1 * mval;
  const float w10 = wr1 * wc0 * mval, w11 = wr1 * wc1 * mval;
  uint4 pk;
  pk.x = (uint)(ys0 * Wd + xs0);
  pk.y = (uint)f2bf(w00) | ((uint)f2bf(w01) << 16);
  pk.z = (uint)f2bf(w10) | ((uint)f2bf(w11) << 16);
  pk.w = 0;
  prep[i] = pk;
}

__global__ __launch_bounds__(256) void prep_offsets_fused_kernel(
    const float* __restrict__ omS, uint4* __restrict__ prepS, int HS_, int WS_,
    int totS,
    const float* __restrict__ omT, uint4* __restrict__ prepT, int HT_, int WT_,
    int totT) {
  int i = blockIdx.x * 256 + threadIdx.x;
  if (i < totS) {
    const int N = HS_ * WS_;
    const int p = i % N, k = (i / N) % 9, b = i / (9 * N);
    prep_one(omS + (size_t)b * 27 * N, prepS, i, p, k, HS_, WS_, N);
    return;
  }
  i -= totS;
  if (i < totT) {
    const int N = HT_ * WT_;
    const int p = i % N, k = (i / N) % 9, b = i / (9 * N);
    prep_one(omT + (size_t)b * 27 * N, prepT, i, p, k, HT_, WT_, N);
  }
}

// ---------------------------------------------------------------------------
// fused DCN via MFMA (BM=256, BK=64, BN=32, 512 thr) with B-gather register
// prefetch (next K-step's corners load during current step's MFMA).
// s gx=32, t gx=8; gy=1.
// ---------------------------------------------------------------------------
__global__ __launch_bounds__(512) void dcn_fused_kernel(
    const ushort* __restrict__ xS, const uint4* __restrict__ prS,
    const ushort* __restrict__ AwS, const float* __restrict__ biS,
    float* __restrict__ oS, int NS_, int WS_, int NRS_,
    const ushort* __restrict__ xT, const uint4* __restrict__ prT,
    const ushort* __restrict__ AwT, const float* __restrict__ biT,
    float* __restrict__ oT, int NT_, int WT_, int NRT_) {
  constexpr int C = 256, BM = 256, MF = 4;
  __shared__ ushort Asm[BM][72];
  __shared__ ushort Bsm[32][72];
  __shared__ int sq[32];
  __shared__ float swl[4][32];
  int bx, by, bz; bool isT;
  if (!fdecode(512, 32, 1, 8, 1, bx, by, bz, isT)) return;
  const ushort* xsT = isT ? xT : xS;
  const uint4* prep = isT ? prT : prS;
  const ushort* Awb = isT ? AwT : AwS;
  const float* bias = isT ? biT : biS;
  float* out = isT ? oT : oS;
  const int N = isT ? NT_ : NS_, Wd = isT ? WT_ : WS_, NR = isT ? NRT_ : NRS_;
  const int n0 = bx * 32, b = bz;
  const int tid = threadIdx.x, lane = tid & 63, w = tid >> 6;
  const int wr = w >> 1, wc = w & 1;
  const ushort* xb = xsT + (size_t)b * NR * C;
  // gather identity: 2 units per thread (n, n+16) at channel-pair pr
  const int un0 = tid >> 5;  // 0..15
  const int un1 = un0 + 16;  // 16..31
  const int kk2 = (tid & 31) * 2;
  f32x4 acc[MF];
#pragma unroll
  for (int i = 0; i < MF; i++) acc[i] = (f32x4){0.f, 0.f, 0.f, 0.f};
  uint bReg[2][4];
  int sqr0 = 0, sqr1 = 0;
  float w0a[4], w1a[4];
  const size_t rowYp = (size_t)Wd * C;
  for (int tap = 0; tap < 9; ++tap) {
    if (tid < 32) {
      const int p = n0 + tid;
      if (p < N) {
        const uint4 pk = prep[((size_t)b * 9 + tap) * N + p];
        sq[tid] = (int)pk.x * C;
        swl[0][tid] = bf2f((ushort)(pk.y & 0xffff));
        swl[1][tid] = bf2f((ushort)(pk.y >> 16));
        swl[2][tid] = bf2f((ushort)(pk.z & 0xffff));
        swl[3][tid] = bf2f((ushort)(pk.z >> 16));
      } else {
        sq[tid] = 0;
        swl[0][tid] = swl[1][tid] = swl[2][tid] = swl[3][tid] = 0.f;
      }
    }
    __syncthreads();
    sqr0 = sq[un0];
    sqr1 = sq[un1];
#pragma unroll
    for (int q = 0; q < 4; q++) {
      w0a[q] = swl[q][un0];
      w1a[q] = swl[q][un1];
    }
    // prefetch B corners for ks=0
    {
      const ushort* pA = xb + sqr0 + kk2;
      bReg[0][0] = *reinterpret_cast<const uint*>(pA);
      bReg[0][1] = *reinterpret_cast<const uint*>(pA + C);
      bReg[0][2] = *reinterpret_cast<const uint*>(pA + rowYp);
      bReg[0][3] = *reinterpret_cast<const uint*>(pA + rowYp + C);
      const ushort* pB = xb + sqr1 + kk2;
      bReg[1][0] = *reinterpret_cast<const uint*>(pB);
      bReg[1][1] = *reinterpret_cast<const uint*>(pB + C);
      bReg[1][2] = *reinterpret_cast<const uint*>(pB + rowYp);
      bReg[1][3] = *reinterpret_cast<const uint*>(pB + rowYp + C);
    }
#pragma unroll
    for (int ks = 0; ks < 4; ++ks) {
      const int k0 = tap * 256 + ks * 64;
      // A-stage: direct global->LDS copy
#pragma unroll
      for (int i = 0; i < 4; ++i) {
        const int u = tid + 512 * i;
        const int row = u >> 3, seg = u & 7;
        *reinterpret_cast<uint4*>(&Asm[row][seg * 8]) =
            *reinterpret_cast<const uint4*>(&Awb[(size_t)row * 2304 + k0 + seg * 8]);
      }
      // B-stage: pack prefetched corners
      {
        const float vlo0 = w0a[0] * bflo(bReg[0][0]) + w0a[1] * bflo(bReg[0][1]) +
                           w0a[2] * bflo(bReg[0][2]) + w0a[3] * bflo(bReg[0][3]);
        const float vhi0 = w0a[0] * bfhi(bReg[0][0]) + w0a[1] * bfhi(bReg[0][1]) +
                           w0a[2] * bfhi(bReg[0][2]) + w0a[3] * bfhi(bReg[0][3]);
        *reinterpret_cast<uint*>(&Bsm[un0][kk2]) =
            (uint)f2bf(vlo0) | ((uint)f2bf(vhi0) << 16);
        const float vlo1 = w1a[0] * bflo(bReg[1][0]) + w1a[1] * bflo(bReg[1][1]) +
                           w1a[2] * bflo(bReg[1][2]) + w1a[3] * bflo(bReg[1][3]);
        const float vhi1 = w1a[0] * bfhi(bReg[1][0]) + w1a[1] * bfhi(bReg[1][1]) +
                           w1a[2] * bfhi(bReg[1][2]) + w1a[3] * bfhi(bReg[1][3]);
        *reinterpret_cast<uint*>(&Bsm[un1][kk2]) =
            (uint)f2bf(vlo1) | ((uint)f2bf(vhi1) << 16);
      }
      __syncthreads();
      // prefetch next ks (overlaps MFMA)
      if (ks < 3) {
        const int c1 = (ks + 1) * 64;
        const ushort* pA = xb + sqr0 + c1 + kk2;
        bReg[0][0] = *reinterpret_cast<const uint*>(pA);
        bReg[0][1] = *reinterpret_cast<const uint*>(pA + C);
        bReg[0][2] = *reinterpret_cast<const uint*>(pA + rowYp);
        bReg[0][3] = *reinterpret_cast<const uint*>(pA + rowYp + C);
        const ushort* pB = xb + sqr1 + c1 + kk2;
        bReg[1][0] = *reinterpret_cast<const uint*>(pB);
        bReg[1][1] = *reinterpret_cast<const uint*>(pB + C);
        bReg[1][2] = *reinterpret_cast<const uint*>(pB + rowYp);
        bReg[1][3] = *reinterpret_cast<const uint*>(pB + rowYp + C);
      }
#pragma unroll
      for (int sub = 0; sub < 2; ++sub) {
        const int koff = sub * 32 + (lane >> 4) * 8;
        const bf16x8 bf = *reinterpret_cast<const bf16x8*>(&Bsm[wc * 16 + (lane & 15)][koff]);
#pragma unroll
        for (int mf = 0; mf < MF; mf++) {
          const bf16x8 af = *reinterpret_cast<const bf16x8*>(
              &Asm[wr * 64 + mf * 16 + (lane & 15)][koff]);
          acc[mf] = __builtin_amdgcn_mfma_f32_16x16x32_bf16(af, bf, acc[mf], 0, 0, 0);
        }
      }
      __syncthreads();
    }
  }
  const int gn = n0 + wc * 16 + (lane & 15);
#pragma unroll
  for (int mf = 0; mf < MF; mf++) {
    const int mbase = wr * 64 + mf * 16 + ((lane >> 4) * 4);
    if (gn < N) {
#pragma unroll
      for (int rr = 0; rr < 4; rr++)
        out[((size_t)b * C + mbase + rr) * N + gn] = acc[mf][rr] + bias[mbase + rr];
    }
  }
}

// ---------------------------------------------------------------------------
extern "C" void kernel_launch(void* const* d_in, const int* in_sizes, int n_in,
                              void* d_out, int out_size, void* d_ws, size_t ws_size,
                              hipStream_t stream) {
  const float* t_in = (const float*)d_in[0];
  const float* s_in = (const float*)d_in[1];
  const float* t_qw = (const float*)d_in[2];
  const float* t_qb = (const float*)d_in[3];
  const float* t_kw = (const float*)d_in[4];
  const float* t_kb = (const float*)d_in[5];
  const float* t_vw = (const float*)d_in[6];
  const float* t_vb = (const float*)d_in[7];
  const float* t_g = (const float*)d_in[8];
  const float* s_qw = (const float*)d_in[9];
  const float* s_qb = (const float*)d_in[10];
  const float* s_kw = (const float*)d_in[11];
  const float* s_kb = (const float*)d_in[12];
  const float* s_vw = (const float*)d_in[13];
  const float* s_vb = (const float*)d_in[14];
  const float* s_g = (const float*)d_in[15];
  const float* w_t_ch = (const float*)d_in[16];
  const float* w_s_ch = (const float*)d_in[17];
  const float* w_s2t = (const float*)d_in[18];
  const float* w_t2s = (const float*)d_in[19];
  const float* t_off_w = (const float*)d_in[20];
  const float* t_off_b = (const float*)d_in[21];
  const float* t_dcn_w = (const float*)d_in[22];
  const float* t_dcn_b = (const float*)d_in[23];
  const float* s_off_w = (const float*)d_in[24];
  const float* s_off_b = (const float*)d_in[25];
  const float* s_dcn_w = (const float*)d_in[26];
  const float* s_dcn_b = (const float*)d_in[27];
  (void)in_sizes; (void)n_in; (void)out_size; (void)ws_size;

  constexpr int Bn = 16, C = 256;
  constexpr int HT = 15, WT = 15, NT = HT * WT;    // 225
  constexpr int HS = 31, WS2 = 31, NS = HS * WS2;  // 961
  constexpr int NpT = 256, NpS = 992;
  constexpr int NRT = 256, NRS = 1024;

  float* ws = (float*)d_ws;
  size_t off = 0;
  auto alloc = [&](size_t n) {
    n = (n + 3) & ~(size_t)3;
    float* p = ws + off; off += n; return p;
  };
  auto allocU = [&](size_t nu) { return (ushort*)alloc((nu + 1) / 2); };

  float* qk_t = alloc((size_t)Bn * 64 * NT);
  float* qk_s = alloc((size_t)Bn * 64 * NS);
  float* qkw_t = alloc((size_t)64 * C + 64);
  float* qkw_s = alloc((size_t)64 * C + 64);
  float* qkb_t = qkw_t + (size_t)64 * C;
  float* qkb_s = qkw_s + (size_t)64 * C;
  ushort* xT_t = allocU((size_t)Bn * NRT * C);
  ushort* xT_s = allocU((size_t)Bn * NRS * C);
  ushort* xbf_t = allocU((size_t)Bn * C * NpT);
  ushort* xbf_s = allocU((size_t)Bn * C * NpS);
  ushort* Wv_t = allocU((size_t)C * C);
  ushort* Wv_s = allocU((size_t)C * C);
  ushort* v_tbf = allocU((size_t)Bn * C * NpT);
  ushort* v_sbf = allocU((size_t)Bn * C * NpS);
  ushort* S_t = allocU((size_t)Bn * NT * NpT);
  ushort* S_s = allocU((size_t)Bn * NS * NpS);
  ushort* xsT_t = allocU((size_t)Bn * NRT * C);
  ushort* xsT_s = allocU((size_t)Bn * NRS * C);
  float* Atc = alloc((size_t)Bn * C * C);  // Asc must stay adjacent
  float* Asc = alloc((size_t)Bn * C * C);
  ushort* Mc_t = allocU((size_t)Bn * C * C);
  ushort* Mc_s = allocU((size_t)Bn * C * C);
  float* om_t = alloc((size_t)Bn * 27 * NT);
  float* om_s = alloc((size_t)Bn * 27 * NS);
  ushort* owb_t = allocU((size_t)32 * 2304);
  ushort* owb_s = allocU((size_t)32 * 2304);
  ushort* Awb_t = allocU((size_t)256 * 2304);
  ushort* Awb_s = allocU((size_t)256 * 2304);
  uint4* prep_t = (uint4*)alloc((size_t)Bn * 9 * NT * 4);
  uint4* prep_s = (uint4*)alloc((size_t)Bn * 9 * NS * 4);

  dim3 blk(256);

  // 1. fused weight prep
  prep_weights_kernel<<<dim3((1491072 + 255) / 256), blk, 0, stream>>>(
      t_qw, t_qb, t_kw, t_kb, s_qw, s_qb, s_kw, s_kb, t_vw, s_vw,
      t_off_w, s_off_w, t_dcn_w, s_dcn_w,
      qkw_t, qkb_t, qkw_s, qkb_s, Wv_t, Wv_s, owb_t, owb_s, Awb_t, Awb_s);

  // 2. fused q|k projections
  conv1x1_fused_kernel<<<dim3(320), blk, 0, stream>>>(
      s_in, qkw_s, qkb_s, qk_s, NS, t_in, qkw_t, qkb_t, qk_t, NT);

  // 3-4. fused casts
  cast_transpose_fused_kernel<<<dim3(1280), blk, 0, stream>>>(
      s_in, xT_s, NS, NRS, t_in, xT_t, NT, NRT);
  cast_pad_fused_kernel<<<dim3((Bn * C * NpS + Bn * C * NpT + 255) / 256), blk, 0, stream>>>(
      s_in, xbf_s, NS, NpS, Bn * C * NpS, t_in, xbf_t, NT, NpT, Bn * C * NpT);

  // 5. fused v projection (EPI=0)
  gemm_fused_kernel<0><<<dim3(640), blk, 0, stream>>>(
      Wv_s, 0, xT_s, s_vb, v_sbf, nullptr, NS, NpS, NRS, C,
      Wv_t, 0, xT_t, t_vb, v_tbf, nullptr, NT, NpT, NRT, C,
      512, 16, 4);

  // 6. fused energy
  energy_fused_kernel<<<dim3(4352), blk, 0, stream>>>(
      qk_s, S_s, NS, NpS, qk_t, S_t, NT, NpT);

  // 7. fused spatial softmax
  softmax_bf16_fused_kernel<<<dim3(Bn * NS + Bn * NT), blk, 0, stream>>>(
      S_s, NS, NpS, S_t, NT, NpT, Bn * NS);

  // 8. fused gram (EPI=2)
  gemm_fused_kernel<2><<<dim3(256), blk, 0, stream>>>(
      xbf_s, 1, xbf_s, nullptr, nullptr, Asc, C, C, C, NpS,
      xbf_t, 1, xbf_t, nullptr, nullptr, Atc, C, C, C, NpT,
      128, 4, 4);

  // 9. channel softmax over Atc||Asc (contiguous)
  softmax_rows_kernel<<<dim3(2 * Bn * C), blk, 0, stream>>>(Atc, C, -1.f);

  // 10. fused mcomb
  mcomb_fused_kernel<<<dim3((2 * Bn * C * C + 255) / 256), blk, 0, stream>>>(
      Atc, Asc, w_t_ch, w_s2t, w_s_ch, w_t2s, Mc_t, Mc_s, Bn * C * C);

  // 11. merged PV + chan GEMM -> xsT (no fp32 xsum)
  pv_chan_fused_kernel<<<dim3(640), blk, 0, stream>>>(
      v_sbf, S_s, Mc_s, xT_s, s_in, s_g, xsT_s, NS, NpS, NRS,
      v_tbf, S_t, Mc_t, xT_t, t_in, t_g, xsT_t, NT, NpT, NRT);

  // 12. fused offconv
  offconv_fused_kernel<<<dim3(320), blk, 0, stream>>>(
      xsT_s, owb_s, s_off_b, om_s, HS, WS2, NS, NRS,
      xsT_t, owb_t, t_off_b, om_t, HT, WT, NT, NRT);

  // 13. fused gather-table prep
  prep_offsets_fused_kernel<<<dim3((Bn * 9 * NS + Bn * 9 * NT + 255) / 256), blk, 0, stream>>>(
      om_s, prep_s, HS, WS2, Bn * 9 * NS, om_t, prep_t, HT, WT, Bn * 9 * NT);

  // 14. fused DCN (B-gather prefetch pipeline)
  float* out_t = (float*)d_out;
  float* out_s = out_t + (size_t)Bn * C * NT;
  dcn_fused_kernel<<<dim3(640), dim3(512), 0, stream>>>(
      xsT_s, prep_s, Awb_s, s_dcn_b, out_s, NS, WS2, NRS,
      xsT_t, prep_t, Awb_t, t_dcn_b, out_t, NT, WT, NRT);
}